// Round 7
// baseline (807.614 us; speedup 1.0000x reference)
//
#include <hip/hip_runtime.h>

// SubjBasisGenerator fused pipeline. B=4 NQ=416 NC=257 D=768 H=6 DH=128 G=104 R=4 LORA=64
// R17: ONE persistent mega-kernel with a hand-rolled device-scope atomic grid
//      barrier (plain <<<>>> launch — R15 proved hipLaunchCooperativeKernel
//      silently no-ops under the harness's capture; the phase dataflow itself
//      was audited there and the fused-Y-stats body shipped in R16 at 263us).
//      Co-residency by construction: grid = occupancy-query nb x CUs with
//      __launch_bounds__(256,2). Barrier: threadfence -> atomicAdd arrival ->
//      last-arriver RELEASE flag -> spinners AGENT-ACQUIRE spin + s_sleep
//      backoff + bounded bail (mismatch, not hang). Flags zeroed per launch
//      via capture-safe hipMemsetAsync. Replaces 9 dispatch boundaries
//      (~7-15us each, R14/R16 evidence) with ~2-3us barriers.
// R16: stats2 fused into Y-gemm epilogue (fp32 Y in LDS, yfull deleted).
// R14: dispatch 16->11 (prep/mg4/ysim/ct merges).
// R13/R12: merged q/k/mid gemm128s (B-panel-major), merged LNs/transposes,
//      ctx^T btrans fast path, K padded 257->264, 264-row-padded midi.
// R11: oc_k fusion (O-gemm+combine), Wconv bf16 pre-convert.
// R10: gemm128 — 128x128 tile, 4x4 MFMA acc/wave, global_load_lds width-16.
//
// Algebra: the grouped-conv+LN v-path decomposes exactly:
//   sum_j A_j v_j = gv2*( (sum_j A_j inv_j mid_j)@Wconv[g] - sum_j A_j inv_j mu_j )
//                   + bv2 + (A @ ctx)
//   q2[b,g,j] = mid^T M[g] mid = mid . (M[g] @ mid),  M[g] = Wconv[g]Wconv[g]^T/768

typedef unsigned short u16;
typedef unsigned int   u32;
typedef __attribute__((ext_vector_type(4))) float f32x4;
typedef __attribute__((ext_vector_type(4))) u32   u32x4;
typedef __attribute__((ext_vector_type(8))) short bf16x8;

__device__ __forceinline__ float bf2f(u16 v) { return __uint_as_float(((u32)v) << 16); }
__device__ __forceinline__ u16 f2bf(float f) {
  u32 u = __float_as_uint(f);
  u32 r = u + 0x7fffu + ((u >> 16) & 1u);  // RNE
  return (u16)(r >> 16);
}
__device__ __forceinline__ float gld(const void* p, long idx, int f32) {
  return f32 ? ((const float*)p)[idx] : bf2f(((const u16*)p)[idx]);
}

typedef const __attribute__((address_space(1))) u32 gas_u32;
typedef __attribute__((address_space(3))) u32 las_u32;

// async 16B/lane global->LDS; LDS dest = wave-uniform base + lane*16 (m97).
__device__ __forceinline__ void stage16(const u16* g, u16* lbase, int lane) {
#if __has_builtin(__builtin_amdgcn_global_load_lds)
  (void)lane;
  __builtin_amdgcn_global_load_lds((gas_u32*)g, (las_u32*)lbase, 16, 0, 0);
#else
  *(u32x4*)(lbase + lane * 8) = *(const u32x4*)g;
#endif
}

// ------------------------------------------------------------ diag fill -----
__global__ __launch_bounds__(256) void fill_k(u16* p, float v, int n) {
  int i = blockIdx.x * 256 + threadIdx.x;
  if (i < n) p[i] = f2bf(v);
}

// --------------------------------------------------------------- args -------
struct MegaArgs {
  const void *x, *ctx, *Wq, *gq, *bq, *Wk, *gk, *bk, *Wv, *gv1, *bv1;
  const void *Wcv, *gv2, *bv2, *Wo, *go, *bo;
  u16 *xb, *cbuf, *wcvb, *midi;
  u16 *wqt, *wkt, *wot, *wvt, *ctxT;
  float *wbar;
  u16 *qbf, *kbf, *midbf, *Gb;
  float *simf, *pim;
  u16 *Abf, *A2bf;
  float *s_sh, *c_buf;
  u16 *Tb16, *opbf;
  void *outp;
};

// ---------------------------------------------------- grid barrier (atomic) -
// one-shot per site; flags zeroed by hipMemsetAsync before each launch.
__device__ __forceinline__ void gbar(int* bar, int site) {
  __syncthreads();
  if (threadIdx.x == 0) {
    __threadfence();                       // write-back this block's stores
    int* cnt = bar + site * 2;
    int* flg = cnt + 1;
    int prev = atomicAdd(cnt, 1);          // device-scope RMW (coherent point)
    if (prev == (int)gridDim.x - 1) {
      __hip_atomic_store(flg, 1, __ATOMIC_RELEASE, __HIP_MEMORY_SCOPE_AGENT);
    } else {
      long t = 0;
      while (__hip_atomic_load(flg, __ATOMIC_ACQUIRE, __HIP_MEMORY_SCOPE_AGENT) == 0) {
        __builtin_amdgcn_s_sleep(8);       // backoff
        if (++t > (1L << 24)) break;       // bounded bail: mismatch, not hang
      }
    }
    __threadfence();                       // invalidate stale L1/L2 lines
  }
  __syncthreads();
}

// ------------------------------------------------------------ dtype probe ---
// per-block: reads first 4096 words of x (L2-broadcast), returns flag register.
__device__ int probe_flag(const u32* xw) {
  __shared__ int r[4];
  int tid = threadIdx.x, c = 0;
  for (int i = tid; i < 4096; i += 256) {
    u16 lo = (u16)(xw[i] & 0xffffu);
    float a = fabsf(bf2f(lo));
    if (lo == 0 || (a >= 1e-3f && a <= 32.f)) ++c;
  }
#pragma unroll
  for (int o = 32; o; o >>= 1) c += __shfl_xor(c, o, 64);
  if ((tid & 63) == 0) r[tid >> 6] = c;
  __syncthreads();
  int tot = r[0] + r[1] + r[2] + r[3];
  __syncthreads();
  return (tot >= 2048) ? 0 : 1;  // 1 = fp32
}

// --------------------------------------------------------------- prep -------
// vb [0,3597): ext->bf16 copies (x, ctx, Wconv) + midi pad-row zeroing
// vb [3597,11181): transposes Wq/Wk/Wo (768^2), Wv (768x6656), ctx^T
// vb [11181,12845): wbar row means (reads RAW Wcv)
__device__ void prep_body(int bid, int f, const MegaArgs& a) {
  if (bid < 3597) {
    const long n0_ = 1277952, n1_ = 789504, n2_ = 5111808, n3_ = 186368;
    long i = ((long)bid * 256 + threadIdx.x) * 8;
    const long t0 = n0_, t1 = t0 + n1_, t2 = t1 + n2_, t3 = t2 + n3_;
    if (i >= t3) return;
    if (i >= t2) {
      long e = i - t2;                 // zero 7 pad rows per midi z-block
      long z = e / 448, off = e - z * 448;
      u32x4 zz = {0u, 0u, 0u, 0u};
      *(u32x4*)(a.midi + z * 16896 + 16448 + off) = zz;
      return;
    }
    const void* in; u16* out;
    if (i < t0)      { in = a.x;   out = a.xb; }
    else if (i < t1) { in = a.ctx; out = a.cbuf; i -= t0; }
    else             { in = a.Wcv; out = a.wcvb; i -= t1; }
    if (f) {
      const float* ip = (const float*)in + i;
      f32x4 u = *(const f32x4*)ip, v = *(const f32x4*)(ip + 4);
      u32x4 q = { (u32)f2bf(u.x) | ((u32)f2bf(u.y) << 16),
                  (u32)f2bf(u.z) | ((u32)f2bf(u.w) << 16),
                  (u32)f2bf(v.x) | ((u32)f2bf(v.y) << 16),
                  (u32)f2bf(v.z) | ((u32)f2bf(v.w) << 16) };
      *(u32x4*)(out + i) = q;
    } else {
      *(u32x4*)(out + i) = *(const u32x4*)((const u16*)in + i);
    }
  } else if (bid < 11181) {
    __shared__ float s[32][33];
    int t = bid - 3597;
    const void* in; u16* out;
    int inK, inN, ldo, outK, nx;
    long inBase = 0, outBase = 0;
    if (t < 1728) {                    // 3 x 768x768 weights: 576 tiles each
      int w = t / 576; t -= w * 576;
      in  = w == 0 ? a.Wq : w == 1 ? a.Wk : a.Wo;
      out = w == 0 ? a.wqt : w == 1 ? a.wkt : a.wot;
      inK = 768; inN = 768; ldo = 768; outK = 768; nx = 24;
    } else if (t < 6720) {             // Wv 768x6656: 208 n-tiles x 24 k-tiles
      t -= 1728;
      in = a.Wv; out = a.wvt;
      inK = 768; inN = 6656; ldo = 768; outK = 768; nx = 208;
    } else {                           // ctxT: 4 b x (24 n-tiles x 9 k-tiles)
      t -= 6720;
      int b = t / 216; t -= b * 216;
      in = a.ctx; out = a.ctxT;
      inK = 257; inN = 768; ldo = 264; outK = 264; nx = 24;
      inBase = (long)b * 257 * 768; outBase = (long)b * 768 * 264;
    }
    int n0 = (t % nx) * 32, k0 = (t / nx) * 32;
    int tx = threadIdx.x & 31, ty = threadIdx.x >> 5;  // 32 x 8
#pragma unroll
    for (int i = 0; i < 32; i += 8) {
      int k = k0 + ty + i, n = n0 + tx;
      float v = 0.f;
      if (k < inK && n < inN) v = gld(in, inBase + (long)k * inN + n, f);
      s[ty + i][tx] = v;
    }
    __syncthreads();
#pragma unroll
    for (int i = 0; i < 32; i += 8) {
      int n = n0 + ty + i, k = k0 + tx;
      if (n < inN && k < outK) out[outBase + (long)n * ldo + k] = f2bf(s[tx][ty + i]);
    }
    __syncthreads();   // LDS reused next grid-stride iteration
  } else {
    int r = (bid - 11181) * 4 + (threadIdx.x >> 6);
    int lane = threadIdx.x & 63;
    long base = (long)r * 768;
    float sm = 0.f;
    for (int c = lane; c < 768; c += 64) sm += gld(a.Wcv, base + c, f);
#pragma unroll
    for (int o = 32; o; o >>= 1) sm += __shfl_xor(sm, o, 64);
    if (lane == 0) a.wbar[r] = sm * (1.f / 768.f);
  }
}

// ------------------------------------------------------------- gemm128 ------
__device__ __forceinline__ void gemm128_body(
    u16* As, u16* Bs,
    const u16* __restrict__ A, const u16* __restrict__ B, u16* __restrict__ C,
    int M, int N, int K, int lda, int ldb, int ldc, int m0, int n0)
{
  const int tid = threadIdx.x, lane = tid & 63, wave = tid >> 6;
  const int wm = (wave >> 1) * 64, wn = (wave & 1) * 64;
  const int fm = lane & 15, fq = lane >> 4;

  const int srow = lane >> 2, selem = (lane & 3) * 8;
  int ra1 = m0 + wave * 16 + srow;      if (ra1 > M - 1) ra1 = M - 1;
  int ra2 = m0 + 64 + wave * 16 + srow; if (ra2 > M - 1) ra2 = M - 1;
  const int rb1 = n0 + wave * 16 + srow;
  const int rb2 = n0 + 64 + wave * 16 + srow;
  const u16* pa1 = A + (long)ra1 * lda + selem;
  const u16* pa2 = A + (long)ra2 * lda + selem;
  const u16* pb1 = B + (long)rb1 * ldb + selem;
  const u16* pb2 = B + (long)rb2 * ldb + selem;
  u16* la1 = As + wave * 512;
  u16* la2 = As + 2048 + wave * 512;
  u16* lb1 = Bs + wave * 512;
  u16* lb2 = Bs + 2048 + wave * 512;

  f32x4 acc[4][4];
  const f32x4 zero4 = {0.f, 0.f, 0.f, 0.f};
#pragma unroll
  for (int a_ = 0; a_ < 4; ++a_)
#pragma unroll
    for (int b_ = 0; b_ < 4; ++b_) acc[a_][b_] = zero4;

  for (int k0 = 0; k0 < K; k0 += 32) {
    stage16(pa1, la1, lane);
    stage16(pa2, la2, lane);
    stage16(pb1, lb1, lane);
    stage16(pb2, lb2, lane);
    pa1 += 32; pa2 += 32; pb1 += 32; pb2 += 32;
    __syncthreads();
    bf16x8 fa[4], fb[4];
#pragma unroll
    for (int mt = 0; mt < 4; ++mt)
      fa[mt] = *(const bf16x8*)&As[(wm + mt * 16 + fm) * 32 + fq * 8];
#pragma unroll
    for (int nt = 0; nt < 4; ++nt)
      fb[nt] = *(const bf16x8*)&Bs[(wn + nt * 16 + fm) * 32 + fq * 8];
#pragma unroll
    for (int mt = 0; mt < 4; ++mt)
#pragma unroll
      for (int nt = 0; nt < 4; ++nt)
        acc[mt][nt] = __builtin_amdgcn_mfma_f32_16x16x32_bf16(fa[mt], fb[nt], acc[mt][nt], 0, 0, 0);
    __syncthreads();
  }
#pragma unroll
  for (int mt = 0; mt < 4; ++mt)
#pragma unroll
    for (int nt = 0; nt < 4; ++nt)
#pragma unroll
      for (int rr = 0; rr < 4; ++rr) {
        int gm = m0 + wm + mt * 16 + fq * 4 + rr;
        int gn = n0 + wn + nt * 16 + fm;
        if (gm < M) C[(long)gm * ldc + gn] = f2bf(acc[mt][nt][rr]);
      }
}

// ------------------------------------------------- gemm64 body (all-bf16) ---
// 64x64 tile, BK=32, 2x2 acc/wave. If Ylds != nullptr, fp32 tile -> LDS
// (caller epilogue); Ylds may alias As/Bs (dead after K-loop's final barrier).
#define LDS_S 40

__device__ __forceinline__ void gemm64_body(
    u16* As, u16* Bs,
    const u16* __restrict__ A16, const u16* __restrict__ B16,
    float* Cf, u16* Cb, float* Ylds,
    int M, int N, int K, int lda, int ldb, int ldc,
    int btrans, float alpha, int m0, int n0)
{
  const int tid = threadIdx.x;
  const int lane = tid & 63, wave = tid >> 6;
  const int wm = (wave >> 1) * 32, wn = (wave & 1) * 32;
  const int fm = lane & 15, fq = lane >> 4;
  const int ar = tid >> 2, ak = (tid & 3) * 8;
  const int bk = tid >> 3, bn = (tid & 7) * 8;

  f32x4 acc[2][2];
  const f32x4 zero4 = {0.f, 0.f, 0.f, 0.f};
#pragma unroll
  for (int a_ = 0; a_ < 2; ++a_)
#pragma unroll
    for (int b_ = 0; b_ < 2; ++b_) acc[a_][b_] = zero4;

  for (int k0 = 0; k0 < K; k0 += 32) {
    {
      int gm = m0 + ar, gk = k0 + ak;
      long idx = (long)gm * lda + gk;
      if (gm < M && gk + 8 <= K) {
        *(u32x4*)&As[ar * LDS_S + ak] = *(const u32x4*)(A16 + idx);
      } else {
#pragma unroll
        for (int e = 0; e < 8; ++e)
          As[ar * LDS_S + ak + e] = (gm < M && gk + e < K) ? A16[idx + e] : (u16)0;
      }
    }
    if (btrans) {
      int gn = n0 + ar, gk = k0 + ak;
      long idx = (long)gn * ldb + gk;
      if (gn < N && gk + 8 <= K) {
        *(u32x4*)&Bs[ar * LDS_S + ak] = *(const u32x4*)(B16 + idx);
      } else {
#pragma unroll
        for (int e = 0; e < 8; ++e)
          Bs[ar * LDS_S + ak + e] = (gn < N && gk + e < K) ? B16[idx + e] : (u16)0;
      }
    } else {
      int gk = k0 + bk;
      long idx = (long)gk * ldb + n0 + bn;
      u16 tmp[8];
      if (gk < K) {
        u32x4 v = *(const u32x4*)(B16 + idx);
        tmp[0] = (u16)(v.x & 0xffff); tmp[1] = (u16)(v.x >> 16);
        tmp[2] = (u16)(v.y & 0xffff); tmp[3] = (u16)(v.y >> 16);
        tmp[4] = (u16)(v.z & 0xffff); tmp[5] = (u16)(v.z >> 16);
        tmp[6] = (u16)(v.w & 0xffff); tmp[7] = (u16)(v.w >> 16);
      } else {
#pragma unroll
        for (int e = 0; e < 8; ++e) tmp[e] = 0;
      }
      int rot = tid & 7;  // spread LDS bank writes
#pragma unroll
      for (int e = 0; e < 8; ++e) {
        int ee = (e + rot) & 7;
        Bs[(bn + ee) * LDS_S + bk] = tmp[ee];
      }
    }
    __syncthreads();
    {
      bf16x8 fa[2], fb[2];
      fa[0] = *(const bf16x8*)&As[(wm +      fm) * LDS_S + fq * 8];
      fa[1] = *(const bf16x8*)&As[(wm + 16 + fm) * LDS_S + fq * 8];
      fb[0] = *(const bf16x8*)&Bs[(wn +      fm) * LDS_S + fq * 8];
      fb[1] = *(const bf16x8*)&Bs[(wn + 16 + fm) * LDS_S + fq * 8];
#pragma unroll
      for (int mt = 0; mt < 2; ++mt)
#pragma unroll
        for (int nt = 0; nt < 2; ++nt)
          acc[mt][nt] = __builtin_amdgcn_mfma_f32_16x16x32_bf16(fa[mt], fb[nt], acc[mt][nt], 0, 0, 0);
    }
    __syncthreads();
  }
  if (Ylds) {
    // all LDS reads complete past the final barrier; safe to overwrite As/Bs
#pragma unroll
    for (int mt = 0; mt < 2; ++mt)
#pragma unroll
      for (int nt = 0; nt < 2; ++nt)
#pragma unroll
        for (int rr = 0; rr < 4; ++rr)
          Ylds[(wm + mt * 16 + fq * 4 + rr) * 64 + (wn + nt * 16 + fm)] = acc[mt][nt][rr];
  } else {
#pragma unroll
    for (int mt = 0; mt < 2; ++mt)
#pragma unroll
      for (int nt = 0; nt < 2; ++nt)
#pragma unroll
        for (int rr = 0; rr < 4; ++rr) {
          int gm = m0 + wm + mt * 16 + fq * 4 + rr;
          int gn = n0 + wn + nt * 16 + fm;
          if (gm < M && gn < N) {
            float v = alpha * acc[mt][nt][rr];
            if (Cb) Cb[(long)gm * ldc + gn] = f2bf(v);
            else    Cf[(long)gm * ldc + gn] = v;
          }
        }
  }
}

// -------------------------------------- mg4: q/k/mid gemm128s + Gram gemm ---
__device__ void mg4_body(int bid, const MegaArgs& a, char* smem) {
  u16* As = (u16*)smem;
  u16* Bs = (u16*)(smem + 8192);
  if (bid < 600) {
    const u16 *A, *B; u16* C; int M, N, lid, mx;
    if (bid < 78)       { A = a.xb;   B = a.wqt; C = a.qbf;   M = 1664; N = 768;  lid = bid;       mx = 13; }
    else if (bid < 132) { A = a.cbuf; B = a.wkt; C = a.kbf;   M = 1028; N = 768;  lid = bid - 78;  mx = 9;  }
    else                { A = a.cbuf; B = a.wvt; C = a.midbf; M = 1028; N = 6656; lid = bid - 132; mx = 9;  }
    int m0 = (lid % mx) * 128, n0 = (lid / mx) * 128;
    gemm128_body(As, Bs, A, B, C, M, N, 768, 768, 768, N, m0, n0);
  } else {
    int z = bid - 600;   // 0..103: M[g] = Wconv_b[g] @ Wconv_b[g]^T / 768
    gemm64_body(As, Bs, a.wcvb + (long)z * 49152, a.wcvb + (long)z * 49152,
                nullptr, a.Gb + (long)z * 4096, nullptr,
                64, 64, 768, 768, 768, 64, 1, 1.f / 768.f, 0, 0);
  }
}

// ------------------------------ ysim: Y-gemm (+fused stats) + sim-gemm ------
__device__ void ysim_body(int bid, const MegaArgs& a, char* smem) {
  u16* As = (u16*)smem;
  u16* Bs = (u16*)(smem + 8192);
  if (bid < 1768) {
    // Y = mid_g[1028x64] @ M[g]^T -> fp32 tile in LDS, then stats epilogue
    int g = bid / 17, bx = bid % 17;
    int m0 = bx * 64;
    float* Ylds = (float*)smem;   // aliases As/Bs (dead after final barrier)
    gemm64_body(As, Bs, a.midbf + (long)g * 64, a.Gb + (long)g * 4096,
                nullptr, nullptr, Ylds,
                1028, 64, 64, 6656, 64, 64, 1, 1.f, m0, 0);
    __syncthreads();
    int tid = threadIdx.x, lane = tid & 63, wave = tid >> 6;
#pragma unroll
    for (int rr = 0; rr < 16; ++rr) {
      int r = wave * 16 + rr;          // local row
      int gr = m0 + r;                 // global row (wave-uniform)
      if (gr < 1028) {
        float m  = bf2f(a.midbf[(long)gr * 6656 + g * 64 + lane]);
        float y  = Ylds[r * 64 + lane];
        float wb = a.wbar[g * 64 + lane];
        float mup = m * wb, q2p = m * y;
#pragma unroll
        for (int o = 32; o; o >>= 1) { mup += __shfl_xor(mup, o, 64); q2p += __shfl_xor(q2p, o, 64); }
        float var = q2p - mup * mup;
        float inv = rsqrtf(fmaxf(var, 0.f) + 1e-5f);
        int b = gr / 257, j = gr - b * 257;
        long zidx = (long)b * 104 + g;
        a.midi[(zidx * 264 + j) * 64 + lane] = f2bf(inv * m);
        if (lane == 0) a.pim[zidx * 257 + j] = inv * mup;
      }
    }
    __syncthreads();   // Ylds region re-staged next grid-stride iteration
  } else {
    // sim = scale^2 * q @ k^T;  z = b*6+h
    int lid = bid - 1768; int z = lid / 35, r = lid % 35, bx = r % 7, by = r / 7;
    const u16* A = a.qbf + (long)(z / 6) * 319488 + (long)(z % 6) * 128;
    const u16* B = a.kbf + (long)(z / 6) * 197376 + (long)(z % 6) * 128;
    float* Cf = a.simf + (long)z * 106912;
    gemm64_body(As, Bs, A, B, Cf, nullptr, nullptr,
                416, 257, 128, 768, 768, 257, 1, 0.08838834764831845f, bx * 64, by * 64);
  }
}

// --------------------------------------------------- ct: c-gemm + T-gemm ----
__device__ void ct_body(int bid, const MegaArgs& a, char* smem) {
  u16* As = (u16*)smem;
  u16* Bs = (u16*)(smem + 8192);
  if (bid < 336) {
    int z = bid / 14, r = bid % 14, bx = r % 7, by = r / 7;
    const u16* A = a.Abf + (long)z * 109824;
    const u16* B = a.ctxT + (long)(z / 6) * 202752 + (long)(z % 6) * 33792;
    float* Cf = a.c_buf + (long)z * 53248;
    gemm64_body(As, Bs, A, B, Cf, nullptr, nullptr,
                416, 128, 264, 264, 264, 128, 1, 1.f, bx * 64, by * 64);
  } else {
    int z = bid - 336;
    const u16* A = a.A2bf + (long)z * 6336;
    const u16* B = a.midi + (long)z * 16896;
    u16* Cb = a.Tb16 + (long)z * 1536;
    gemm64_body(As, Bs, A, B, nullptr, Cb, nullptr,
                24, 64, 264, 264, 64, 64, 0, 1.f, 0, 0);
  }
}

// ------------------------------------------------------------- row LN -------
__device__ __forceinline__ void ln_row(
    const u16* __restrict__ ip, const void* __restrict__ g, const void* __restrict__ b,
    u16* __restrict__ ob, float* __restrict__ of, int N, int f)
{
  int tid = threadIdx.x, lane = tid & 63, wave = tid >> 6;
  const int nv = N >> 3;
  float s1 = 0.f, s2 = 0.f;
  for (int c8 = tid; c8 < nv; c8 += 256) {
    u32x4 v = *(const u32x4*)(ip + c8 * 8);
    float e0 = bf2f((u16)(v.x & 0xffff)), e1 = bf2f((u16)(v.x >> 16));
    float e2 = bf2f((u16)(v.y & 0xffff)), e3 = bf2f((u16)(v.y >> 16));
    float e4 = bf2f((u16)(v.z & 0xffff)), e5 = bf2f((u16)(v.z >> 16));
    float e6 = bf2f((u16)(v.w & 0xffff)), e7 = bf2f((u16)(v.w >> 16));
    s1 += ((e0 + e1) + (e2 + e3)) + ((e4 + e5) + (e6 + e7));
    s2 += ((e0*e0 + e1*e1) + (e2*e2 + e3*e3)) + ((e4*e4 + e5*e5) + (e6*e6 + e7*e7));
  }
#pragma unroll
  for (int o = 32; o; o >>= 1) { s1 += __shfl_xor(s1, o, 64); s2 += __shfl_xor(s2, o, 64); }
  __shared__ float red[8];
  if (lane == 0) { red[wave] = s1; red[4 + wave] = s2; }
  __syncthreads();
  s1 = red[0] + red[1] + red[2] + red[3];
  s2 = red[4] + red[5] + red[6] + red[7];
  float mean = s1 / N;
  float var = s2 / N - mean * mean;
  float rstd = rsqrtf(fmaxf(var, 0.f) + 1e-5f);
  for (int c8 = tid; c8 < nv; c8 += 256) {
    int c = c8 * 8;
    u32x4 v = *(const u32x4*)(ip + c);
    float e[8];
    e[0] = bf2f((u16)(v.x & 0xffff)); e[1] = bf2f((u16)(v.x >> 16));
    e[2] = bf2f((u16)(v.y & 0xffff)); e[3] = bf2f((u16)(v.y >> 16));
    e[4] = bf2f((u16)(v.z & 0xffff)); e[5] = bf2f((u16)(v.z >> 16));
    e[6] = bf2f((u16)(v.w & 0xffff)); e[7] = bf2f((u16)(v.w >> 16));
    float gg[8], bb[8];
    if (f) {
      const float* gp = (const float*)g + c; const float* bp = (const float*)b + c;
      f32x4 g0 = *(const f32x4*)gp, g1 = *(const f32x4*)(gp + 4);
      f32x4 b0 = *(const f32x4*)bp, b1 = *(const f32x4*)(bp + 4);
      gg[0]=g0.x; gg[1]=g0.y; gg[2]=g0.z; gg[3]=g0.w; gg[4]=g1.x; gg[5]=g1.y; gg[6]=g1.z; gg[7]=g1.w;
      bb[0]=b0.x; bb[1]=b0.y; bb[2]=b0.z; bb[3]=b0.w; bb[4]=b1.x; bb[5]=b1.y; bb[6]=b1.z; bb[7]=b1.w;
    } else {
      u32x4 gv = *(const u32x4*)((const u16*)g + c);
      u32x4 bv = *(const u32x4*)((const u16*)b + c);
      gg[0]=bf2f((u16)(gv.x&0xffff)); gg[1]=bf2f((u16)(gv.x>>16));
      gg[2]=bf2f((u16)(gv.y&0xffff)); gg[3]=bf2f((u16)(gv.y>>16));
      gg[4]=bf2f((u16)(gv.z&0xffff)); gg[5]=bf2f((u16)(gv.z>>16));
      gg[6]=bf2f((u16)(gv.w&0xffff)); gg[7]=bf2f((u16)(gv.w>>16));
      bb[0]=bf2f((u16)(bv.x&0xffff)); bb[1]=bf2f((u16)(bv.x>>16));
      bb[2]=bf2f((u16)(bv.y&0xffff)); bb[3]=bf2f((u16)(bv.y>>16));
      bb[4]=bf2f((u16)(bv.z&0xffff)); bb[5]=bf2f((u16)(bv.z>>16));
      bb[6]=bf2f((u16)(bv.w&0xffff)); bb[7]=bf2f((u16)(bv.w>>16));
    }
    float o_[8];
#pragma unroll
    for (int e2i = 0; e2i < 8; ++e2i) o_[e2i] = (e[e2i] - mean) * rstd * gg[e2i] + bb[e2i];
    if (of) {
      f32x4 o0 = {o_[0], o_[1], o_[2], o_[3]}, o1 = {o_[4], o_[5], o_[6], o_[7]};
      *(f32x4*)(of + c) = o0; *(f32x4*)(of + c + 4) = o1;
    } else {
      u32x4 q = { (u32)f2bf(o_[0]) | ((u32)f2bf(o_[1]) << 16),
                  (u32)f2bf(o_[2]) | ((u32)f2bf(o_[3]) << 16),
                  (u32)f2bf(o_[4]) | ((u32)f2bf(o_[5]) << 16),
                  (u32)f2bf(o_[6]) | ((u32)f2bf(o_[7]) << 16) };
      *(u32x4*)(ob + c) = q;
    }
  }
  __syncthreads();   // red reused next grid-stride iteration
}

__device__ void mln3_body(int row, int f, const MegaArgs& a) {
  u16* ip; const void *g, *b; int N;
  if (row < 1664)      { ip = a.qbf + (long)row * 768; g = a.gq; b = a.bq; N = 768; }
  else if (row < 2692) { ip = a.kbf + (long)(row - 1664) * 768; g = a.gk; b = a.bk; N = 768; }
  else                 { ip = a.midbf + (long)(row - 2692) * 6656; g = a.gv1; b = a.bv1; N = 6656; }
  ln_row(ip, g, b, ip, nullptr, N, f);
}

__device__ void fin_ln_body(int row, int f, const MegaArgs& a) {
  const u16* ip = a.qbf + (long)row * 768;
  float* of = f ? (float*)a.outp + (long)row * 768 : nullptr;
  u16*   ob = f ? nullptr : (u16*)a.outp + (long)row * 768;
  ln_row(ip, a.go, a.bo, ob, of, 768, f);
}

// ------------------------------------------------------------- softmax ------
__device__ void softmax_body(int vb, const MegaArgs& a) {
  int bh = vb % 24, gy = vb / 24;
  int b = bh / 6, h = bh - b * 6;
  int tid = threadIdx.x, lane = tid & 63, wave = tid >> 6;
  int i = gy * 4 + wave;
  int g = i % 104, rq = i / 104;
  const float* sp_ = a.simf + ((long)bh * 416 + i) * 257;
  float s[5];
#pragma unroll
  for (int jc = 0; jc < 5; ++jc) {
    int j = jc * 64 + lane;
    s[jc] = (j < 257) ? sp_[j] : -1e30f;
  }
  float mx = -1e30f;
#pragma unroll
  for (int jc = 0; jc < 5; ++jc) mx = fmaxf(mx, s[jc]);
#pragma unroll
  for (int o = 32; o; o >>= 1) mx = fmaxf(mx, __shfl_xor(mx, o, 64));
  float p[5], sum = 0.f, sp = 0.f;
  long pimb = ((long)b * 104 + g) * 257;
#pragma unroll
  for (int jc = 0; jc < 5; ++jc) {
    int j = jc * 64 + lane;
    float pv = 0.f;
    if (j < 257) { pv = __expf(s[jc] - mx); sp = fmaf(pv, a.pim[pimb + j], sp); }
    p[jc] = pv; sum += pv;
  }
#pragma unroll
  for (int o = 32; o; o >>= 1) { sum += __shfl_xor(sum, o, 64); sp += __shfl_xor(sp, o, 64); }
  float rs = 1.f / sum;
  long arow  = ((long)bh * 416 + i) * 264;
  long a2row = (((long)b * 104 + g) * 24 + h * 4 + rq) * 264;
#pragma unroll
  for (int jc = 0; jc < 5; ++jc) {
    int j = jc * 64 + lane;
    if (j < 257) { u16 pb = f2bf(p[jc] * rs); a.Abf[arow + j] = pb; a.A2bf[a2row + j] = pb; }
    else if (j < 264) { a.Abf[arow + j] = 0; a.A2bf[a2row + j] = 0; }
  }
  if (lane == 0) a.s_sh[(long)bh * 416 + i] = sp * rs;
}

// -------------------------------------------------- fused O-gemm + combine --
__device__ void oc_body(int z, int f, const MegaArgs& a) {
  int b = z / 104, g = z - b * 104;
  int tid = threadIdx.x;
  __shared__ float Ts[24][64];        // 6 KB
  const u16* tp = a.Tb16 + (long)z * 1536;
  for (int idx = tid; idx < 1536; idx += 256) Ts[idx >> 6][idx & 63] = bf2f(tp[idx]);
  __syncthreads();
  const int dh = tid & 127;
  const int hbase = (tid >> 7) * 3;
  const u16* wg = a.wcvb + (long)g * 49152;
#pragma unroll
  for (int hh = 0; hh < 3; ++hh) {
    int h = hbase + hh;
    int d = h * 128 + dh;
    const u16* wp = wg + d;
    float a0 = 0.f, a1 = 0.f, a2 = 0.f, a3 = 0.f;
#pragma unroll 16
    for (int k = 0; k < 64; ++k) {
      float w = bf2f(wp[(long)k * 768]);
      a0 = fmaf(Ts[h * 4 + 0][k], w, a0);
      a1 = fmaf(Ts[h * 4 + 1][k], w, a1);
      a2 = fmaf(Ts[h * 4 + 2][k], w, a2);
      a3 = fmaf(Ts[h * 4 + 3][k], w, a3);
    }
    float acc[4] = {a0, a1, a2, a3};
    float gvd = gld(a.gv2, d, f), bvd = gld(a.bv2, d, f);
#pragma unroll
    for (int rq = 0; rq < 4; ++rq) {
      int i = rq * 104 + g;
      float ssh = a.s_sh[((long)b * 6 + h) * 416 + i];
      float val = gvd * (acc[rq] - ssh) + bvd
                + a.c_buf[(((long)b * 6 + h) * 416 + i) * 128 + dh];
      a.opbf[((long)b * 416 + i) * 768 + d] = f2bf(val);
    }
  }
  __syncthreads();   // Ts reused next grid-stride iteration
}

// ------------------------------------------------------------ mega kernel ---
__global__ __launch_bounds__(256, 2) void mega_k(MegaArgs a, int* bar) {
  __shared__ __attribute__((aligned(16))) char smem[16384];

  const int f = probe_flag((const u32*)a.x);

  for (int vb = blockIdx.x; vb < 12845; vb += gridDim.x) prep_body(vb, f, a);
  gbar(bar, 0);
  for (int vb = blockIdx.x; vb < 704; vb += gridDim.x) mg4_body(vb, a, smem);
  gbar(bar, 1);
  for (int vb = blockIdx.x; vb < 3720; vb += gridDim.x) mln3_body(vb, f, a);
  gbar(bar, 2);
  for (int vb = blockIdx.x; vb < 2608; vb += gridDim.x) ysim_body(vb, a, smem);
  gbar(bar, 3);
  for (int vb = blockIdx.x; vb < 2496; vb += gridDim.x) softmax_body(vb, a);
  gbar(bar, 4);
  for (int vb = blockIdx.x; vb < 752; vb += gridDim.x) ct_body(vb, a, smem);
  gbar(bar, 5);
  for (int vb = blockIdx.x; vb < 416; vb += gridDim.x) oc_body(vb, f, a);
  gbar(bar, 6);
  for (int vb = blockIdx.x; vb < 78; vb += gridDim.x) {
    u16* As = (u16*)smem;
    u16* Bs = (u16*)(smem + 8192);
    gemm128_body(As, Bs, a.opbf, a.wot, a.qbf, 1664, 768, 768, 768, 768, 768,
                 (vb % 13) * 128, (vb / 13) * 128);
  }
  gbar(bar, 7);
  for (int vb = blockIdx.x; vb < 1664; vb += gridDim.x) fin_ln_body(vb, f, a);
}

// ---------------------------------------------------------------- host ------
extern "C" void kernel_launch(void* const* d_in, const int* in_sizes, int n_in,
                              void* d_out, int out_size, void* d_ws, size_t ws_size,
                              hipStream_t stream)
{
  (void)in_sizes; (void)n_in;
  // -------- workspace layout --------
  const size_t SZ_BAR  = 256;        // grid-barrier counters (memset each launch)
  const size_t SZ_QBF  = 2555904;
  const size_t SZ_KBF  = 1579008;
  const size_t SZ_MID  = 13684736;
  const size_t SZ_MM   = 1703936;
  const size_t SZ_WB   = 26624;
  const size_t SZ_MIDI = 14057472;   // 416 * 264 * 64 bf16 (264-row padded)
  const size_t SZ_PIM  = 427648;
  const size_t SZ_ABF  = 5271552;
  const size_t SZ_A2   = 5271552;
  const size_t SZ_SSH  = 39936;
  const size_t SZ_CB   = 1579008;
  const size_t SZ_WCVB = 10223616;   // 104*64*768 bf16
  const size_t SZ_WT   = 1179648;    // 768*768 bf16 (x3)
  const size_t SZ_WVT  = 10223616;   // 6656*768 bf16
  const size_t SZ_CTXT = 1622016;    // 4*768*264 bf16
  const size_t SZ_SIMF = 10263552;   // 24*416*257 fp32
  const size_t REQUIRED = SZ_BAR + SZ_QBF + SZ_KBF + SZ_MID + SZ_MM + SZ_WB +
                          SZ_MIDI + SZ_PIM + SZ_ABF + SZ_A2 + SZ_SSH + SZ_CB +
                          SZ_WCVB + 3 * SZ_WT + SZ_WVT + SZ_CTXT + SZ_SIMF;  // 82,069,376

  if (ws_size < REQUIRED) {
    fill_k<<<(out_size + 255) / 256, 256, 0, stream>>>((u16*)d_out, (float)(ws_size >> 20), out_size);
    return;
  }

  char* p = (char*)d_ws;
  int*   bar   = (int*)  p;                 p += SZ_BAR;
  u16*   qbf   = (u16*)  p;                 p += SZ_QBF;
  u16*   kbf   = (u16*)  p;                 p += SZ_KBF;
  char*  midrg = p;                         p += SZ_MID;
  char*  mmrg  = p;                         p += SZ_MM;
  float* wbar  = (float*)p;                 p += SZ_WB;
  u16*   midi  = (u16*)  p;                 p += SZ_MIDI;
  float* pim   = (float*)p;                 p += SZ_PIM;
  char*  abfrg = p;                         p += SZ_ABF;
  u16*   A2bf  = (u16*)  p;                 p += SZ_A2;
  float* s_sh  = (float*)p;                 p += SZ_SSH;
  u16*   cb    = (u16*)  p;                 p += SZ_CB;
  u16*   wcvb  = (u16*)  p;                 p += SZ_WCVB;
  u16*   wqt2  = (u16*)  p;                 p += SZ_WT;
  u16*   wkt2  = (u16*)  p;                 p += SZ_WT;
  u16*   wot2  = (u16*)  p;                 p += SZ_WT;
  u16*   wvt   = (u16*)  p;                 p += SZ_WVT;
  u16*   ctxT  = (u16*)  p;                 p += SZ_CTXT;
  float* simf  = (float*)p;                 p += SZ_SIMF;

  MegaArgs a;
  a.x = d_in[0];  a.ctx = d_in[1];
  a.Wq = d_in[2]; a.gq = d_in[3]; a.bq = d_in[4];
  a.Wk = d_in[5]; a.gk = d_in[6]; a.bk = d_in[7];
  a.Wv = d_in[8]; a.gv1 = d_in[9]; a.bv1 = d_in[10];
  a.Wcv = d_in[11]; a.gv2 = d_in[12]; a.bv2 = d_in[13];
  a.Wo = d_in[14]; a.go = d_in[15]; a.bo = d_in[16];
  a.xb = (u16*)abfrg;           // xb dead before Abf written
  a.cbuf = cb;
  a.wcvb = wcvb;
  a.midi = midi;
  a.wqt = wqt2; a.wkt = wkt2; a.wot = wot2; a.wvt = wvt; a.ctxT = ctxT;
  a.wbar = wbar;
  a.qbf = qbf; a.kbf = kbf;
  a.midbf = (u16*)midrg;
  a.Gb = (u16*)mmrg;
  a.simf = simf; a.pim = pim;
  a.Abf = (u16*)abfrg; a.A2bf = A2bf;
  a.s_sh = s_sh;
  a.c_buf = (float*)midrg;              // midbf dead after ysim stats
  a.Tb16 = (u16*)(midrg + 5111808);     // after c_buf's 5,111,808 B
  a.opbf = (u16*)abfrg;                 // Abf dead after ct
  a.outp = d_out;

  static int g_grid = 0;
  if (g_grid == 0) {
    int nb = 0;
    hipOccupancyMaxActiveBlocksPerMultiprocessor(&nb, mega_k, 256, 0);
    if (nb < 1) nb = 1;
    if (nb > 4) nb = 4;       // cap atomic-barrier contention
    int ncu = 256;
    hipDeviceProp_t prop;
    int dev = 0;
    if (hipGetDevice(&dev) == hipSuccess &&
        hipGetDeviceProperties(&prop, dev) == hipSuccess &&
        prop.multiProcessorCount > 0)
      ncu = prop.multiProcessorCount;
    g_grid = nb * ncu;        // co-resident by construction
  }

  hipMemsetAsync(bar, 0, SZ_BAR, stream);   // capture-safe (harness uses it)
  mega_k<<<g_grid, 256, 0, stream>>>(a, bar);
}

// Round 9
// 276.324 us; speedup vs baseline: 2.9227x; 2.9227x over previous
//
#include <hip/hip_runtime.h>

// SubjBasisGenerator fused pipeline. B=4 NQ=416 NC=257 D=768 H=6 DH=128 G=104 R=4 LORA=64
// R19 == R18 resubmit (round 8 bench was the same infra failure as round 2:
//      "container failed twice", no kernel verdict; full OOB/race/hang audit
//      found no defect — one lever per bench, no code change).
// R18: R16 skeleton + (1) simsm_k: sim-GEMM + softmax fused per 32-row tile
//      (fp32 scores in 60KB LDS) — removes 20.6MB simf round-trip + softmax
//      dispatch. (2) sp dot (s_sh) moved to ct_k branch (A2bf . pim, fp32).
//      (3) wbar moved to mg4 (bf16 wcvb, overlapped with GEMM tail).
// R16: stats2 fused into Y-gemm epilogue (fp32 Y in LDS, yfull deleted). 263us.
// R14: dispatch 16->11 (prep/mg4/ysim/ct merges).
// R13/R12: merged q/k/mid gemm128s (B-panel-major), merged LNs/transposes,
//      ctx^T btrans fast path, K padded 257->264, 264-row-padded midi.
// R11: oc_k fusion (O-gemm+combine), Wconv bf16 pre-convert.
// R10: gemm128 — 128x128 tile, 4x4 MFMA acc/wave, global_load_lds width-16.
//
// Algebra: the grouped-conv+LN v-path decomposes exactly:
//   sum_j A_j v_j = gv2*( (sum_j A_j inv_j mid_j)@Wconv[g] - sum_j A_j inv_j mu_j )
//                   + bv2 + (A @ ctx)
//   q2[b,g,j] = mid^T M[g] mid = mid . (M[g] @ mid),  M[g] = Wconv[g]Wconv[g]^T/768

typedef unsigned short u16;
typedef unsigned int   u32;
typedef __attribute__((ext_vector_type(4))) float f32x4;
typedef __attribute__((ext_vector_type(4))) u32   u32x4;
typedef __attribute__((ext_vector_type(8))) short bf16x8;

__device__ __forceinline__ float bf2f(u16 v) { return __uint_as_float(((u32)v) << 16); }
__device__ __forceinline__ u16 f2bf(float f) {
  u32 u = __float_as_uint(f);
  u32 r = u + 0x7fffu + ((u >> 16) & 1u);  // RNE
  return (u16)(r >> 16);
}
__device__ __forceinline__ float gld(const void* p, long idx, int f32) {
  return f32 ? ((const float*)p)[idx] : bf2f(((const u16*)p)[idx]);
}

typedef const __attribute__((address_space(1))) u32 gas_u32;
typedef __attribute__((address_space(3))) u32 las_u32;

// async 16B/lane global->LDS; LDS dest = wave-uniform base + lane*16 (m97).
__device__ __forceinline__ void stage16(const u16* g, u16* lbase, int lane) {
#if __has_builtin(__builtin_amdgcn_global_load_lds)
  (void)lane;
  __builtin_amdgcn_global_load_lds((gas_u32*)g, (las_u32*)lbase, 16, 0, 0);
#else
  *(u32x4*)(lbase + lane * 8) = *(const u32x4*)g;
#endif
}

// ------------------------------------------------------------ dtype probe ---
__global__ __launch_bounds__(256) void probe_k(const u32* __restrict__ xw, int* __restrict__ flag) {
  int tid = threadIdx.x, c = 0;
  for (int i = tid; i < 4096; i += 256) {
    u16 lo = (u16)(xw[i] & 0xffffu);
    float a = fabsf(bf2f(lo));
    if (lo == 0 || (a >= 1e-3f && a <= 32.f)) ++c;
  }
#pragma unroll
  for (int o = 32; o; o >>= 1) c += __shfl_xor(c, o, 64);
  __shared__ int r[4];
  if ((tid & 63) == 0) r[tid >> 6] = c;
  __syncthreads();
  if (tid == 0) flag[0] = (r[0] + r[1] + r[2] + r[3] >= 2048) ? 0 : 1;  // 1 = fp32
}

// ------------------------------------------------------------ diag fill -----
__global__ __launch_bounds__(256) void fill_k(u16* p, float v, int n) {
  int i = blockIdx.x * 256 + threadIdx.x;
  if (i < n) p[i] = f2bf(v);
}

// --------------------------------------------------------------- prep_k -----
// blocks [0,3597): ext->bf16 copies (x, ctx, Wconv) + midi pad-row zeroing
// blocks [3597,11181): transposes Wq/Wk/Wo (768^2), Wv (768x6656), ctx^T
__global__ __launch_bounds__(256) void prep_k(
    const void* __restrict__ x,   u16* __restrict__ xb,
    const void* __restrict__ ctx, u16* __restrict__ cbuf,
    const void* __restrict__ Wcv, u16* __restrict__ wcvb,
    u16* __restrict__ midi,
    const void* __restrict__ Wq, const void* __restrict__ Wk,
    const void* __restrict__ Wo, const void* __restrict__ Wv,
    u16* __restrict__ wqt, u16* __restrict__ wkt, u16* __restrict__ wot,
    u16* __restrict__ wvt, u16* __restrict__ ctxT,
    const int* __restrict__ dtf)
{
  const int f = dtf[0];
  int bid = blockIdx.x;
  __shared__ float s[32][33];
  if (bid < 3597) {
    // ---- convb4 ----
    const long n0_ = 1277952, n1_ = 789504, n2_ = 5111808, n3_ = 186368;
    long i = ((long)bid * 256 + threadIdx.x) * 8;
    const long t0 = n0_, t1 = t0 + n1_, t2 = t1 + n2_, t3 = t2 + n3_;
    if (i >= t3) return;
    if (i >= t2) {
      long e = i - t2;                 // zero 7 pad rows per midi z-block
      long z = e / 448, off = e - z * 448;
      u32x4 zz = {0u, 0u, 0u, 0u};
      *(u32x4*)(midi + z * 16896 + 16448 + off) = zz;
      return;
    }
    const void* in; u16* out;
    if (i < t0)      { in = x;    out = xb; }
    else if (i < t1) { in = ctx;  out = cbuf; i -= t0; }
    else             { in = Wcv;  out = wcvb; i -= t1; }
    if (f) {
      const float* ip = (const float*)in + i;
      f32x4 a = *(const f32x4*)ip, b = *(const f32x4*)(ip + 4);
      u32x4 q = { (u32)f2bf(a.x) | ((u32)f2bf(a.y) << 16),
                  (u32)f2bf(a.z) | ((u32)f2bf(a.w) << 16),
                  (u32)f2bf(b.x) | ((u32)f2bf(b.y) << 16),
                  (u32)f2bf(b.z) | ((u32)f2bf(b.w) << 16) };
      *(u32x4*)(out + i) = q;
    } else {
      *(u32x4*)(out + i) = *(const u32x4*)((const u16*)in + i);
    }
  } else {
    // ---- transM ----
    int t = bid - 3597;
    const void* in; u16* out;
    int inK, inN, ldo, outK, nx;
    long inBase = 0, outBase = 0;
    if (t < 1728) {                    // 3 x 768x768 weights: 576 tiles each
      int w = t / 576; t -= w * 576;
      in  = w == 0 ? Wq : w == 1 ? Wk : Wo;
      out = w == 0 ? wqt : w == 1 ? wkt : wot;
      inK = 768; inN = 768; ldo = 768; outK = 768; nx = 24;
    } else if (t < 6720) {             // Wv 768x6656: 208 n-tiles x 24 k-tiles
      t -= 1728;
      in = Wv; out = wvt;
      inK = 768; inN = 6656; ldo = 768; outK = 768; nx = 208;
    } else {                           // ctxT: 4 b x (24 n-tiles x 9 k-tiles)
      t -= 6720;
      int b = t / 216; t -= b * 216;
      in = ctx; out = ctxT;
      inK = 257; inN = 768; ldo = 264; outK = 264; nx = 24;
      inBase = (long)b * 257 * 768; outBase = (long)b * 768 * 264;
    }
    int n0 = (t % nx) * 32, k0 = (t / nx) * 32;
    int tx = threadIdx.x & 31, ty = threadIdx.x >> 5;  // 32 x 8
#pragma unroll
    for (int i = 0; i < 32; i += 8) {
      int k = k0 + ty + i, n = n0 + tx;
      float v = 0.f;
      if (k < inK && n < inN) v = gld(in, inBase + (long)k * inN + n, f);
      s[ty + i][tx] = v;
    }
    __syncthreads();
#pragma unroll
    for (int i = 0; i < 32; i += 8) {
      int n = n0 + ty + i, k = k0 + tx;
      if (n < inN && k < outK) out[outBase + (long)n * ldo + k] = f2bf(s[tx][ty + i]);
    }
  }
}

// ------------------------------------------------------------- gemm128 ------
// C_bf16 = A_bf16[M,K] @ B_bf16[N,K]^T. Requires N%128==0, K%32==0; M-tail via
// row-clamped staging + guarded writes. 128x128 tile, BK=32, 4 waves each 64x64.
__device__ __forceinline__ void gemm128_body(
    const u16* __restrict__ A, const u16* __restrict__ B, u16* __restrict__ C,
    int M, int N, int K, int lda, int ldb, int ldc, int m0, int n0)
{
  __shared__ __attribute__((aligned(16))) u16 As[128 * 32];
  __shared__ __attribute__((aligned(16))) u16 Bs[128 * 32];
  const int tid = threadIdx.x, lane = tid & 63, wave = tid >> 6;
  const int wm = (wave >> 1) * 64, wn = (wave & 1) * 64;
  const int fm = lane & 15, fq = lane >> 4;

  const int srow = lane >> 2, selem = (lane & 3) * 8;
  int ra1 = m0 + wave * 16 + srow;      if (ra1 > M - 1) ra1 = M - 1;
  int ra2 = m0 + 64 + wave * 16 + srow; if (ra2 > M - 1) ra2 = M - 1;
  const int rb1 = n0 + wave * 16 + srow;
  const int rb2 = n0 + 64 + wave * 16 + srow;
  const u16* pa1 = A + (long)ra1 * lda + selem;
  const u16* pa2 = A + (long)ra2 * lda + selem;
  const u16* pb1 = B + (long)rb1 * ldb + selem;
  const u16* pb2 = B + (long)rb2 * ldb + selem;
  u16* la1 = As + wave * 512;
  u16* la2 = As + 2048 + wave * 512;
  u16* lb1 = Bs + wave * 512;
  u16* lb2 = Bs + 2048 + wave * 512;

  f32x4 acc[4][4];
  const f32x4 zero4 = {0.f, 0.f, 0.f, 0.f};
#pragma unroll
  for (int a_ = 0; a_ < 4; ++a_)
#pragma unroll
    for (int b_ = 0; b_ < 4; ++b_) acc[a_][b_] = zero4;

  for (int k0 = 0; k0 < K; k0 += 32) {
    stage16(pa1, la1, lane);
    stage16(pa2, la2, lane);
    stage16(pb1, lb1, lane);
    stage16(pb2, lb2, lane);
    pa1 += 32; pa2 += 32; pb1 += 32; pb2 += 32;
    __syncthreads();
    bf16x8 fa[4], fb[4];
#pragma unroll
    for (int mt = 0; mt < 4; ++mt)
      fa[mt] = *(const bf16x8*)&As[(wm + mt * 16 + fm) * 32 + fq * 8];
#pragma unroll
    for (int nt = 0; nt < 4; ++nt)
      fb[nt] = *(const bf16x8*)&Bs[(wn + nt * 16 + fm) * 32 + fq * 8];
#pragma unroll
    for (int mt = 0; mt < 4; ++mt)
#pragma unroll
      for (int nt = 0; nt < 4; ++nt)
        acc[mt][nt] = __builtin_amdgcn_mfma_f32_16x16x32_bf16(fa[mt], fb[nt], acc[mt][nt], 0, 0, 0);
    __syncthreads();
  }
#pragma unroll
  for (int mt = 0; mt < 4; ++mt)
#pragma unroll
    for (int nt = 0; nt < 4; ++nt)
#pragma unroll
      for (int rr = 0; rr < 4; ++rr) {
        int gm = m0 + wm + mt * 16 + fq * 4 + rr;
        int gn = n0 + wn + nt * 16 + fm;
        if (gm < M) C[(long)gm * ldc + gn] = f2bf(acc[mt][nt][rr]);
      }
}

__global__ __launch_bounds__(256) void gemm128(
    const u16* __restrict__ A, const u16* __restrict__ B, u16* __restrict__ C,
    int M, int N, int K, int lda, int ldb, int ldc)
{
  gemm128_body(A, B, C, M, N, K, lda, ldb, ldc, blockIdx.x * 128, blockIdx.y * 128);
}

// ------------------------------------------------- gemm64 body (all-bf16) ---
// 64x64 tile, BK=32, 2x2 acc/wave. Pointers pre-offset by caller (batch z).
// If Ylds != nullptr: fp32 tile -> LDS (caller epilogue); Ylds may alias As/Bs.
#define LDS_S 40

__device__ __forceinline__ void gemm64_body(
    u16* As, u16* Bs,
    const u16* __restrict__ A16, const u16* __restrict__ B16,
    float* Cf, u16* Cb, float* Ylds,
    int M, int N, int K, int lda, int ldb, int ldc,
    int btrans, float alpha, int m0, int n0)
{
  const int tid = threadIdx.x;
  const int lane = tid & 63, wave = tid >> 6;
  const int wm = (wave >> 1) * 32, wn = (wave & 1) * 32;
  const int fm = lane & 15, fq = lane >> 4;
  const int ar = tid >> 2, ak = (tid & 3) * 8;
  const int bk = tid >> 3, bn = (tid & 7) * 8;

  f32x4 acc[2][2];
  const f32x4 zero4 = {0.f, 0.f, 0.f, 0.f};
#pragma unroll
  for (int a_ = 0; a_ < 2; ++a_)
#pragma unroll
    for (int b_ = 0; b_ < 2; ++b_) acc[a_][b_] = zero4;

  for (int k0 = 0; k0 < K; k0 += 32) {
    {
      int gm = m0 + ar, gk = k0 + ak;
      long idx = (long)gm * lda + gk;
      if (gm < M && gk + 8 <= K) {
        *(u32x4*)&As[ar * LDS_S + ak] = *(const u32x4*)(A16 + idx);
      } else {
#pragma unroll
        for (int e = 0; e < 8; ++e)
          As[ar * LDS_S + ak + e] = (gm < M && gk + e < K) ? A16[idx + e] : (u16)0;
      }
    }
    if (btrans) {
      int gn = n0 + ar, gk = k0 + ak;
      long idx = (long)gn * ldb + gk;
      if (gn < N && gk + 8 <= K) {
        *(u32x4*)&Bs[ar * LDS_S + ak] = *(const u32x4*)(B16 + idx);
      } else {
#pragma unroll
        for (int e = 0; e < 8; ++e)
          Bs[ar * LDS_S + ak + e] = (gn < N && gk + e < K) ? B16[idx + e] : (u16)0;
      }
    } else {
      int gk = k0 + bk;
      long idx = (long)gk * ldb + n0 + bn;
      u16 tmp[8];
      if (gk < K) {
        u32x4 v = *(const u32x4*)(B16 + idx);
        tmp[0] = (u16)(v.x & 0xffff); tmp[1] = (u16)(v.x >> 16);
        tmp[2] = (u16)(v.y & 0xffff); tmp[3] = (u16)(v.y >> 16);
        tmp[4] = (u16)(v.z & 0xffff); tmp[5] = (u16)(v.z >> 16);
        tmp[6] = (u16)(v.w & 0xffff); tmp[7] = (u16)(v.w >> 16);
      } else {
#pragma unroll
        for (int e = 0; e < 8; ++e) tmp[e] = 0;
      }
      int rot = tid & 7;  // spread LDS bank writes
#pragma unroll
      for (int e = 0; e < 8; ++e) {
        int ee = (e + rot) & 7;
        Bs[(bn + ee) * LDS_S + bk] = tmp[ee];
      }
    }
    __syncthreads();
    {
      bf16x8 fa[2], fb[2];
      fa[0] = *(const bf16x8*)&As[(wm +      fm) * LDS_S + fq * 8];
      fa[1] = *(const bf16x8*)&As[(wm + 16 + fm) * LDS_S + fq * 8];
      fb[0] = *(const bf16x8*)&Bs[(wn +      fm) * LDS_S + fq * 8];
      fb[1] = *(const bf16x8*)&Bs[(wn + 16 + fm) * LDS_S + fq * 8];
#pragma unroll
      for (int mt = 0; mt < 2; ++mt)
#pragma unroll
        for (int nt = 0; nt < 2; ++nt)
          acc[mt][nt] = __builtin_amdgcn_mfma_f32_16x16x32_bf16(fa[mt], fb[nt], acc[mt][nt], 0, 0, 0);
    }
    __syncthreads();
  }
  if (Ylds) {
    // all LDS reads complete past the final barrier; safe to overwrite As/Bs
#pragma unroll
    for (int mt = 0; mt < 2; ++mt)
#pragma unroll
      for (int nt = 0; nt < 2; ++nt)
#pragma unroll
        for (int rr = 0; rr < 4; ++rr)
          Ylds[(wm + mt * 16 + fq * 4 + rr) * 64 + (wn + nt * 16 + fm)] = acc[mt][nt][rr];
  } else {
#pragma unroll
    for (int mt = 0; mt < 2; ++mt)
#pragma unroll
      for (int nt = 0; nt < 2; ++nt)
#pragma unroll
        for (int rr = 0; rr < 4; ++rr) {
          int gm = m0 + wm + mt * 16 + fq * 4 + rr;
          int gn = n0 + wn + nt * 16 + fm;
          if (gm < M && gn < N) {
            float v = alpha * acc[mt][nt][rr];
            if (Cb) Cb[(long)gm * ldc + gn] = f2bf(v);
            else    Cf[(long)gm * ldc + gn] = v;
          }
        }
  }
}

// ------------------- mg4: q/k/mid gemm128s + Gram gemm + wbar (bf16) --------
__global__ __launch_bounds__(256) void mg4_k(
    const u16* __restrict__ xb, const u16* __restrict__ wqt, u16* __restrict__ qbf,
    const u16* __restrict__ cbuf, const u16* __restrict__ wkt, u16* __restrict__ kbf,
    const u16* __restrict__ wvt, u16* __restrict__ midbf,
    const u16* __restrict__ wcvb, u16* __restrict__ Gb, float* __restrict__ wbar)
{
  int bid = blockIdx.x;
  if (bid < 600) {
    const u16 *A, *B; u16* C; int M, N, lid, mx;
    if (bid < 78)       { A = xb;   B = wqt; C = qbf;   M = 1664; N = 768;  lid = bid;       mx = 13; }
    else if (bid < 132) { A = cbuf; B = wkt; C = kbf;   M = 1028; N = 768;  lid = bid - 78;  mx = 9;  }
    else                { A = cbuf; B = wvt; C = midbf; M = 1028; N = 6656; lid = bid - 132; mx = 9;  }
    int m0 = (lid % mx) * 128, n0 = (lid / mx) * 128;
    gemm128_body(A, B, C, M, N, 768, 768, 768, N, m0, n0);
  } else if (bid < 704) {
    __shared__ __attribute__((aligned(16))) u16 As[64 * LDS_S];
    __shared__ __attribute__((aligned(16))) u16 Bs[64 * LDS_S];
    int z = bid - 600;   // 0..103: M[g] = Wconv_b[g] @ Wconv_b[g]^T / 768
    gemm64_body(As, Bs, wcvb + (long)z * 49152, wcvb + (long)z * 49152,
                nullptr, Gb + (long)z * 4096, nullptr,
                64, 64, 768, 768, 768, 64, 1, 1.f / 768.f, 0, 0);
  } else {
    // wbar: row means of bf16 Wconv copy, r = g*64+l over 768 cols
    int r = (bid - 704) * 4 + (threadIdx.x >> 6);
    int lane = threadIdx.x & 63;
    const u16* prow = wcvb + (long)r * 768;
    float sm = 0.f;
    for (int c = lane; c < 768; c += 64) sm += bf2f(prow[c]);
#pragma unroll
    for (int o = 32; o; o >>= 1) sm += __shfl_xor(sm, o, 64);
    if (lane == 0) wbar[r] = sm * (1.f / 768.f);
  }
}

// --------------------- ysim: Y-gemm with fused stats epilogue ---------------
__global__ __launch_bounds__(256) void ysim_k(
    const u16* __restrict__ midbf, const u16* __restrict__ Gb,
    const float* __restrict__ wbar, u16* __restrict__ midi, float* __restrict__ pim)
{
  __shared__ __attribute__((aligned(16))) char smem[16384];
  u16* As = (u16*)smem;
  u16* Bs = (u16*)(smem + 8192);
  int bid = blockIdx.x;
  // Y = mid_g[1028x64] @ M[g]^T -> fp32 tile in LDS, then stats epilogue
  int g = bid / 17, bx = bid % 17;
  int m0 = bx * 64;
  float* Ylds = (float*)smem;   // aliases As/Bs (dead after final barrier)
  gemm64_body(As, Bs, midbf + (long)g * 64, Gb + (long)g * 4096,
              nullptr, nullptr, Ylds,
              1028, 64, 64, 6656, 64, 64, 1, 1.f, m0, 0);
  __syncthreads();
  int tid = threadIdx.x, lane = tid & 63, wave = tid >> 6;
#pragma unroll
  for (int rr = 0; rr < 16; ++rr) {
    int r = wave * 16 + rr;          // local row
    int gr = m0 + r;                 // global row (wave-uniform)
    if (gr < 1028) {
      float m  = bf2f(midbf[(long)gr * 6656 + g * 64 + lane]);
      float y  = Ylds[r * 64 + lane];
      float wb = wbar[g * 64 + lane];
      float mup = m * wb, q2p = m * y;
#pragma unroll
      for (int o = 32; o; o >>= 1) { mup += __shfl_xor(mup, o, 64); q2p += __shfl_xor(q2p, o, 64); }
      float var = q2p - mup * mup;
      float inv = rsqrtf(fmaxf(var, 0.f) + 1e-5f);
      int b = gr / 257, j = gr - b * 257;
      long zidx = (long)b * 104 + g;
      midi[(zidx * 264 + j) * 64 + lane] = f2bf(inv * m);
      if (lane == 0) pim[zidx * 257 + j] = inv * mup;
    }
  }
}

// ------------------------- simsm: fused sim-GEMM + softmax ------------------
// Grid 312 = 24 z x 13 m-tiles. Block computes a 32x264 score tile (MFMA,
// fp32 in LDS) then row-softmax in-block. No sp here (moved to ct spdot).
#define SS 136

__global__ __launch_bounds__(256) void simsm_k(
    const u16* __restrict__ qbf, const u16* __restrict__ kbf,
    u16* __restrict__ Abf, u16* __restrict__ A2bf)
{
  __shared__ __attribute__((aligned(16))) u16 Aq[32 * SS];   //  8704 B
  __shared__ __attribute__((aligned(16))) u16 Bk[64 * SS];   // 17408 B
  __shared__ float S[32 * 264];                               // 33792 B
  int bid = blockIdx.x;
  int z = bid / 13, mt = bid - z * 13;
  int b = z / 6, h = z - b * 6;
  int m0 = mt * 32;
  int tid = threadIdx.x, lane = tid & 63, wave = tid >> 6;
  const int fm = lane & 15, fq = lane >> 4;
  const int wm = (wave >> 1) * 16, wn = (wave & 1) * 32;
  const float alpha = 0.08838834764831845f;   // DH^-0.5 = scale^2

  // stage A: q rows m0..m0+31, head slice 128 cols
  const u16* qb = qbf + (long)b * 319488 + h * 128;
  for (int ch = tid; ch < 512; ch += 256) {
    int row = ch >> 4, c8 = (ch & 15) * 8;
    *(u32x4*)&Aq[row * SS + c8] = *(const u32x4*)(qb + (long)(m0 + row) * 768 + c8);
  }
  const u16* kb = kbf + (long)b * 197376 + h * 128;

  for (int jt = 0; jt < 5; ++jt) {
    int j0 = jt * 64;
    __syncthreads();                     // Bk reads of prev iter done; Aq ready (jt=0)
    for (int ch = tid; ch < 1024; ch += 256) {
      int row = ch >> 4, c8 = (ch & 15) * 8;
      int j = j0 + row; if (j > 256) j = 256;   // clamp (garbage cols masked later)
      *(u32x4*)&Bk[row * SS + c8] = *(const u32x4*)(kb + (long)j * 768 + c8);
    }
    __syncthreads();
    f32x4 acc[2];
    acc[0] = (f32x4){0.f, 0.f, 0.f, 0.f};
    acc[1] = (f32x4){0.f, 0.f, 0.f, 0.f};
#pragma unroll
    for (int ks = 0; ks < 4; ++ks) {
      bf16x8 fa = *(const bf16x8*)&Aq[(wm + fm) * SS + ks * 32 + fq * 8];
#pragma unroll
      for (int nt = 0; nt < 2; ++nt) {
        bf16x8 fb = *(const bf16x8*)&Bk[(wn + nt * 16 + fm) * SS + ks * 32 + fq * 8];
        acc[nt] = __builtin_amdgcn_mfma_f32_16x16x32_bf16(fa, fb, acc[nt], 0, 0, 0);
      }
    }
    // C/D layout: col=lane&15, row=(lane>>4)*4+reg (m89-verified)
#pragma unroll
    for (int nt = 0; nt < 2; ++nt)
#pragma unroll
      for (int rr = 0; rr < 4; ++rr) {
        int col = j0 + wn + nt * 16 + fm;
        if (col < 264) S[(wm + fq * 4 + rr) * 264 + col] = acc[nt][rr];
      }
  }
  __syncthreads();
  // row softmax: wave handles rows wave*8 .. wave*8+7
  for (int rr = 0; rr < 8; ++rr) {
    int il = wave * 8 + rr;
    int i = m0 + il;
    int g = i % 104, rq = i / 104;
    float s[5];
#pragma unroll
    for (int c = 0; c < 5; ++c) {
      int j = c * 64 + lane;
      s[c] = (j < 257) ? S[il * 264 + j] * alpha : -1e30f;
    }
    float mx = -1e30f;
#pragma unroll
    for (int c = 0; c < 5; ++c) mx = fmaxf(mx, s[c]);
#pragma unroll
    for (int o = 32; o; o >>= 1) mx = fmaxf(mx, __shfl_xor(mx, o, 64));
    float p[5], sum = 0.f;
#pragma unroll
    for (int c = 0; c < 5; ++c) {
      int j = c * 64 + lane;
      p[c] = (j < 257) ? __expf(s[c] - mx) : 0.f;
      sum += p[c];
    }
#pragma unroll
    for (int o = 32; o; o >>= 1) sum += __shfl_xor(sum, o, 64);
    float rs = 1.f / sum;
    long arow  = ((long)z * 416 + i) * 264;
    long a2row = (((long)b * 104 + g) * 24 + h * 4 + rq) * 264;
#pragma unroll
    for (int c = 0; c < 5; ++c) {
      int j = c * 64 + lane;
      if (j < 257) { u16 pb = f2bf(p[c] * rs); Abf[arow + j] = pb; A2bf[a2row + j] = pb; }
      else if (j < 264) { Abf[arow + j] = 0; A2bf[a2row + j] = 0; }
    }
  }
}

// ----------------------- ct: c-gemm + T-gemm + spdot ------------------------
__global__ __launch_bounds__(256) void ct_k(
    const u16* __restrict__ Abf, const u16* __restrict__ ctxT, float* __restrict__ c_buf,
    const u16* __restrict__ A2bf, const u16* __restrict__ midi, u16* __restrict__ Tb16,
    const float* __restrict__ pim, float* __restrict__ s_sh)
{
  int bid = blockIdx.x;
  if (bid < 336) {
    __shared__ __attribute__((aligned(16))) u16 As[64 * LDS_S];
    __shared__ __attribute__((aligned(16))) u16 Bs[64 * LDS_S];
    // c = A @ ctx_head (btrans via ctx^T, K=264); z = b*6+h
    int z = bid / 14, r = bid % 14, bx = r % 7, by = r / 7;
    const u16* A = Abf + (long)z * 109824;
    const u16* B = ctxT + (long)(z / 6) * 202752 + (long)(z % 6) * 33792;
    float* Cf = c_buf + (long)z * 53248;
    gemm64_body(As, Bs, A, B, Cf, nullptr, nullptr,
                416, 128, 264, 264, 264, 128, 1, 1.f, bx * 64, by * 64);
  } else if (bid < 752) {
    __shared__ __attribute__((aligned(16))) u16 As[64 * LDS_S];
    __shared__ __attribute__((aligned(16))) u16 Bs[64 * LDS_S];
    // T = A2 @ midi (non-trans, K=264, 264-row-padded midi); z = b*104+g
    int z = bid - 336;
    const u16* A = A2bf + (long)z * 6336;
    const u16* B = midi + (long)z * 16896;
    u16* Cb = Tb16 + (long)z * 1536;
    gemm64_body(As, Bs, A, B, nullptr, Cb, nullptr,
                24, 64, 264, 264, 64, 64, 0, 1.f, 0, 0);
  } else {
    // spdot: s_sh = A2[z] . pim[z] (fp32 accumulate); z = b*104+g
    int z = bid - 752;
    int b = z / 104, g = z - b * 104;
    int lane = threadIdx.x & 63, wave = threadIdx.x >> 6;
    const u16* a2 = A2bf + (long)z * 6336;
    const float* pz = pim + (long)z * 257;
    for (int r = wave; r < 24; r += 4) {
      float sp = 0.f;
#pragma unroll
      for (int c = 0; c < 5; ++c) {
        int j = c * 64 + lane;
        if (j < 257) sp = fmaf(bf2f(a2[r * 264 + j]), pz[j], sp);
      }
#pragma unroll
      for (int o = 32; o; o >>= 1) sp += __shfl_xor(sp, o, 64);
      if (lane == 0) {
        int h = r >> 2, rq = r & 3;
        s_sh[((long)b * 6 + h) * 416 + rq * 104 + g] = sp;
      }
    }
  }
}

// ------------------------------------------------------------- row LN -------
__device__ __forceinline__ void ln_row(
    const u16* __restrict__ ip, const void* __restrict__ g, const void* __restrict__ b,
    u16* __restrict__ ob, float* __restrict__ of, int N, int f)
{
  int tid = threadIdx.x, lane = tid & 63, wave = tid >> 6;
  const int nv = N >> 3;
  float s1 = 0.f, s2 = 0.f;
  for (int c8 = tid; c8 < nv; c8 += 256) {
    u32x4 v = *(const u32x4*)(ip + c8 * 8);
    float e0 = bf2f((u16)(v.x & 0xffff)), e1 = bf2f((u16)(v.x >> 16));
    float e2 = bf2f((u16)(v.y & 0xffff)), e3 = bf2f((u16)(v.y >> 16));
    float e4 = bf2f((u16)(v.z & 0xffff)), e5 = bf2f((u16)(v.z >> 16));
    float e6 = bf2f((u16)(v.w & 0xffff)), e7 = bf2f((u16)(v.w >> 16));
    s1 += ((e0 + e1) + (e2 + e3)) + ((e4 + e5) + (e6 + e7));
    s2 += ((e0*e0 + e1*e1) + (e2*e2 + e3*e3)) + ((e4*e4 + e5*e5) + (e6*e6 + e7*e7));
  }
#pragma unroll
  for (int o = 32; o; o >>= 1) { s1 += __shfl_xor(s1, o, 64); s2 += __shfl_xor(s2, o, 64); }
  __shared__ float red[8];
  if (lane == 0) { red[wave] = s1; red[4 + wave] = s2; }
  __syncthreads();
  s1 = red[0] + red[1] + red[2] + red[3];
  s2 = red[4] + red[5] + red[6] + red[7];
  float mean = s1 / N;
  float var = s2 / N - mean * mean;
  float rstd = rsqrtf(fmaxf(var, 0.f) + 1e-5f);
  for (int c8 = tid; c8 < nv; c8 += 256) {
    int c = c8 * 8;
    u32x4 v = *(const u32x4*)(ip + c);
    float e[8];
    e[0] = bf2f((u16)(v.x & 0xffff)); e[1] = bf2f((u16)(v.x >> 16));
    e[2] = bf2f((u16)(v.y & 0xffff)); e[3] = bf2f((u16)(v.y >> 16));
    e[4] = bf2f((u16)(v.z & 0xffff)); e[5] = bf2f((u16)(v.z >> 16));
    e[6] = bf2f((u16)(v.w & 0xffff)); e[7] = bf2f((u16)(v.w >> 16));
    float gg[8], bb[8];
    if (f) {
      const float* gp = (const float*)g + c; const float* bp = (const float*)b + c;
      f32x4 g0 = *(const f32x4*)gp, g1 = *(const f32x4*)(gp + 4);
      f32x4 b0 = *(const f32x4*)bp, b1 = *(const f32x4*)(bp + 4);
      gg[0]=g0.x; gg[1]=g0.y; gg[2]=g0.z; gg[3]=g0.w; gg[4]=g1.x; gg[5]=g1.y; gg[6]=g1.z; gg[7]=g1.w;
      bb[0]=b0.x; bb[1]=b0.y; bb[2]=b0.z; bb[3]=b0.w; bb[4]=b1.x; bb[5]=b1.y; bb[6]=b1.z; bb[7]=b1.w;
    } else {
      u32x4 gv = *(const u32x4*)((const u16*)g + c);
      u32x4 bv = *(const u32x4*)((const u16*)b + c);
      gg[0]=bf2f((u16)(gv.x&0xffff)); gg[1]=bf2f((u16)(gv.x>>16));
      gg[2]=bf2f((u16)(gv.y&0xffff)); gg[3]=bf2f((u16)(gv.y>>16));
      gg[4]=bf2f((u16)(gv.z&0xffff)); gg[5]=bf2f((u16)(gv.z>>16));
      gg[6]=bf2f((u16)(gv.w&0xffff)); gg[7]=bf2f((u16)(gv.w>>16));
      bb[0]=bf2f((u16)(bv.x&0xffff)); bb[1]=bf2f((u16)(bv.x>>16));
      bb[2]=bf2f((u16)(bv.y&0xffff)); bb[3]=bf2f((u16)(bv.y>>16));
      bb[4]=bf2f((u16)(bv.z&0xffff)); bb[5]=bf2f((u16)(bv.z>>16));
      bb[6]=bf2f((u16)(bv.w&0xffff)); bb[7]=bf2f((u16)(bv.w>>16));
    }
    float o_[8];
#pragma unroll
    for (int e2i = 0; e2i < 8; ++e2i) o_[e2i] = (e[e2i] - mean) * rstd * gg[e2i] + bb[e2i];
    if (of) {
      f32x4 o0 = {o_[0], o_[1], o_[2], o_[3]}, o1 = {o_[4], o_[5], o_[6], o_[7]};
      *(f32x4*)(of + c) = o0; *(f32x4*)(of + c + 4) = o1;
    } else {
      u32x4 q = { (u32)f2bf(o_[0]) | ((u32)f2bf(o_[1]) << 16),
                  (u32)f2bf(o_[2]) | ((u32)f2bf(o_[3]) << 16),
                  (u32)f2bf(o_[4]) | ((u32)f2bf(o_[5]) << 16),
                  (u32)f2bf(o_[6]) | ((u32)f2bf(o_[7]) << 16) };
      *(u32x4*)(ob + c) = q;
    }
  }
}

__global__ __launch_bounds__(256) void ln_rows(
    const u16* __restrict__ in, const void* __restrict__ g, const void* __restrict__ b,
    void* __restrict__ out, int N, const int* __restrict__ dtf, int isfinal)
{
  const int f = dtf[0];
  long row = blockIdx.x;
  const u16* ip = in + row * N;
  float* of = (isfinal && f) ? (float*)out + row * N : nullptr;
  u16*   ob = of ? nullptr : (u16*)out + row * N;
  ln_row(ip, g, b, ob, of, N, f);
}

// merged LN for q (1664x768), k (1028x768), mid (1028x6656)
__global__ __launch_bounds__(256) void mln3_k(
    u16* __restrict__ qb, const void* __restrict__ gq, const void* __restrict__ bq,
    u16* __restrict__ kb, const void* __restrict__ gk, const void* __restrict__ bk,
    u16* __restrict__ mb, const void* __restrict__ gv, const void* __restrict__ bv,
    const int* __restrict__ dtf)
{
  const int f = dtf[0];
  int row = blockIdx.x;
  u16* ip; const void *g, *b; int N;
  if (row < 1664)      { ip = qb + (long)row * 768; g = gq; b = bq; N = 768; }
  else if (row < 2692) { ip = kb + (long)(row - 1664) * 768; g = gk; b = bk; N = 768; }
  else                 { ip = mb + (long)(row - 2692) * 6656; g = gv; b = bv; N = 6656; }
  ln_row(ip, g, b, ip, nullptr, N, f);
}

// -------------------------------------------------- fused O-gemm + combine --
__global__ __launch_bounds__(256) void oc_k(
    const u16* __restrict__ T, const u16* __restrict__ Wb,
    const float* __restrict__ s_sh, const float* __restrict__ c_buf,
    const void* __restrict__ gv2, const void* __restrict__ bv2,
    u16* __restrict__ opbf, const int* __restrict__ dtf)
{
  const int f = dtf[0];
  int z = blockIdx.x;                 // b*104+g
  int b = z / 104, g = z - b * 104;
  int tid = threadIdx.x;
  __shared__ float Ts[24][64];        // 6 KB
  const u16* tp = T + (long)z * 1536;
  for (int idx = tid; idx < 1536; idx += 256) Ts[idx >> 6][idx & 63] = bf2f(tp[idx]);
  __syncthreads();
  const int dh = tid & 127;
  const int hbase = (tid >> 7) * 3;   // threads 0..127 -> h 0..2, 128..255 -> h 3..5
  const u16* wg = Wb + (long)g * 49152;
#pragma unroll
  for (int hh = 0; hh < 3; ++hh) {
    int h = hbase + hh;
    int d = h * 128 + dh;
    const u16* wp = wg + d;
    float a0 = 0.f, a1 = 0.f, a2 = 0.f, a3 = 0.f;
#pragma unroll 16
    for (int k = 0; k < 64; ++k) {
      float w = bf2f(wp[(long)k * 768]);
      a0 = fmaf(Ts[h * 4 + 0][k], w, a0);
      a1 = fmaf(Ts[h * 4 + 1][k], w, a1);
      a2 = fmaf(Ts[h * 4 + 2][k], w, a2);
      a3 = fmaf(Ts[h * 4 + 3][k], w, a3);
    }
    float acc[4] = {a0, a1, a2, a3};
    float gvd = gld(gv2, d, f), bvd = gld(bv2, d, f);
#pragma unroll
    for (int rq = 0; rq < 4; ++rq) {
      int i = rq * 104 + g;
      float ssh = s_sh[((long)b * 6 + h) * 416 + i];
      float val = gvd * (acc[rq] - ssh) + bvd
                + c_buf[(((long)b * 6 + h) * 416 + i) * 128 + dh];
      opbf[((long)b * 416 + i) * 768 + d] = f2bf(val);
    }
  }
}

// ---------------------------------------------------------------- host ------
extern "C" void kernel_launch(void* const* d_in, const int* in_sizes, int n_in,
                              void* d_out, int out_size, void* d_ws, size_t ws_size,
                              hipStream_t stream)
{
  (void)in_sizes; (void)n_in;
  const void* x   = d_in[0];
  const void* ctx = d_in[1];
  const void* Wq  = d_in[2];
  const void* gq  = d_in[3];
  const void* bq  = d_in[4];
  const void* Wk  = d_in[5];
  const void* gk  = d_in[6];
  const void* bk  = d_in[7];
  const void* Wv  = d_in[8];
  const void* gv1 = d_in[9];
  const void* bv1 = d_in[10];
  const void* Wcv = d_in[11];
  const void* gv2 = d_in[12];
  const void* bv2 = d_in[13];
  const void* Wo  = d_in[14];
  const void* go  = d_in[15];
  const void* bo  = d_in[16];

  // -------- workspace layout --------
  const size_t SZ_FLAG = 256;
  const size_t SZ_QBF  = 2555904;
  const size_t SZ_KBF  = 1579008;
  const size_t SZ_MID  = 13684736;
  const size_t SZ_MM   = 1703936;
  const size_t SZ_WB   = 26624;
  const size_t SZ_MIDI = 14057472;   // 416 * 264 * 64 bf16 (264-row padded)
  const size_t SZ_PIM  = 427648;
  const size_t SZ_ABF  = 5271552;
  const size_t SZ_A2   = 5271552;
  const size_t SZ_SSH  = 39936;
  const size_t SZ_CB   = 1579008;
  const size_t SZ_WCVB = 10223616;   // 104*64*768 bf16
  const size_t SZ_WT   = 1179648;    // 768*768 bf16 (x3: WqT, WkT, WoT)
  const size_t SZ_WVT  = 10223616;   // 6656*768 bf16
  const size_t SZ_CTXT = 1622016;    // 4*768*264 bf16 (ctx^T, zero-padded cols)
  const size_t REQUIRED = SZ_FLAG + SZ_QBF + SZ_KBF + SZ_MID + SZ_MM + SZ_WB +
                          SZ_MIDI + SZ_PIM + SZ_ABF + SZ_A2 + SZ_SSH + SZ_CB +
                          SZ_WCVB + 3 * SZ_WT + SZ_WVT + SZ_CTXT;  // 71,805,824

  if (ws_size < REQUIRED) {
    fill_k<<<(out_size + 255) / 256, 256, 0, stream>>>((u16*)d_out, (float)(ws_size >> 20), out_size);
    return;
  }

  char* p = (char*)d_ws;
  int*   dtf   = (int*)  p;                 p += SZ_FLAG;
  u16*   qbf   = (u16*)  p;                 p += SZ_QBF;
  u16*   kbf   = (u16*)  p;                 p += SZ_KBF;
  char*  midrg = p;                         p += SZ_MID;
  char*  mmrg  = p;                         p += SZ_MM;
  float* wbar  = (float*)p;                 p += SZ_WB;
  u16*   midi  = (u16*)  p;                 p += SZ_MIDI;
  float* pim   = (float*)p;                 p += SZ_PIM;
  char*  abfrg = p;                         p += SZ_ABF;
  u16*   A2bf  = (u16*)  p;                 p += SZ_A2;
  float* s_sh  = (float*)p;                 p += SZ_SSH;
  u16*   cb    = (u16*)  p;                 p += SZ_CB;
  u16*   wcvb  = (u16*)  p;                 p += SZ_WCVB;
  u16*   wqt2  = (u16*)  p;                 p += SZ_WT;
  u16*   wkt2  = (u16*)  p;                 p += SZ_WT;
  u16*   wot2  = (u16*)  p;                 p += SZ_WT;
  u16*   wvt   = (u16*)  p;                 p += SZ_WVT;
  u16*   ctxT  = (u16*)  p;                 p += SZ_CTXT;

  u16*   midbf = (u16*)midrg;
  float* c_buf = (float*)midrg;             // midbf dead after ysim stats
  u16*   Tb16  = (u16*)(midrg + 5111808);   // right after c_buf's 5,111,808 B
  u16*   Gb    = (u16*)mmrg;
  u16*   xb    = (u16*)abfrg;
  u16*   Abf   = (u16*)abfrg;
  u16*   opbf  = (u16*)abfrg;               // Abf dead after ct_k

  probe_k<<<1, 256, 0, stream>>>((const u32*)x, dtf);

  // prep: copies + midi pad zero (3597) | transposes (7584)
  prep_k<<<11181, 256, 0, stream>>>(x, xb, ctx, cb, Wcv, wcvb, midi,
                                    Wq, Wk, Wo, Wv, wqt2, wkt2, wot2, wvt, ctxT,
                                    dtf);

  // q/k/mid gemm128s (600) + Gram (104) + wbar (1664, bf16 wcvb)
  mg4_k<<<2368, 256, 0, stream>>>(xb, wqt2, qbf, cb, wkt2, kbf, wvt, midbf,
                                  wcvb, Gb, wbar);

  // q/k/mid LNs
  mln3_k<<<3720, 256, 0, stream>>>(qbf, gq, bq, kbf, gk, bk, midbf, gv1, bv1, dtf);

  // Y = mid_g @ M[g] with fused stats epilogue (writes midi, pim)
  ysim_k<<<1768, 256, 0, stream>>>(midbf, Gb, wbar, midi, pim);

  // fused sim-GEMM + softmax (writes Abf, A2bf; no simf round-trip)
  simsm_k<<<312, 256, 0, stream>>>(qbf, kbf, Abf, A2bf);

  // c = A @ ctx_head (336) + T = A2 @ midi (416) + spdot s_sh (416)
  ct_k<<<1168, 256, 0, stream>>>(Abf, ctxT, c_buf, A2bf, midi, Tb16, pim, s_sh);

  // fused O-gemm + combine
  oc_k<<<416, 256, 0, stream>>>(Tb16, wcvb, s_sh, c_buf, gv2, bv2, opbf, dtf);

  // out = LN(out_pre @ Wo)
  {
    dim3 grid(13, 6, 1);
    gemm128<<<grid, dim3(256), 0, stream>>>(opbf, wot2, qbf, 1664, 768, 768, 768, 768, 768);
  }
  ln_rows<<<1664, 256, 0, stream>>>(qbf, go, bo, d_out, 768, dtf, 1);
}

// Round 10
// 273.522 us; speedup vs baseline: 2.9526x; 1.0102x over previous
//
#include <hip/hip_runtime.h>

// SubjBasisGenerator fused pipeline. B=4 NQ=416 NC=257 D=768 H=6 DH=128 G=104 R=4 LORA=64
// R20: revert R18's simsm fusion (276us vs R16's 263us — 312 blocks x 60KB LDS
//      = 1248 waves chip-wide + 12 barriers/block; traded 3us of HBM traffic
//      for >10us of lost TLP. Lesson: phases here are latency/TLP-bound).
//      Restored R16 ysim(Y+sim)+softmax_k. Kept from R18: (1) wbar in mg4
//      (bf16 wcvb, overlaps GEMM tail; removes 20MB fp32 re-read from prep),
//      (2) host-side dtype from in_sizes[0] bytes (5111808->fp32,
//      2555904->bf16, else probe fallback) — skips probe dispatch.
// R16: stats2 fused into Y-gemm epilogue (fp32 Y in LDS, yfull deleted). 263us.
// R14: dispatch 16->11 (prep/mg4/ysim/ct merges).
// R13/R12: merged q/k/mid gemm128s (B-panel-major), merged LNs/transposes,
//      ctx^T btrans fast path, K padded 257->264, 264-row-padded midi.
// R11: oc_k fusion (O-gemm+combine), Wconv bf16 pre-convert.
// R10: gemm128 — 128x128 tile, 4x4 MFMA acc/wave, global_load_lds width-16.
//
// Algebra: the grouped-conv+LN v-path decomposes exactly:
//   sum_j A_j v_j = gv2*( (sum_j A_j inv_j mid_j)@Wconv[g] - sum_j A_j inv_j mu_j )
//                   + bv2 + (A @ ctx)
//   q2[b,g,j] = mid^T M[g] mid = mid . (M[g] @ mid),  M[g] = Wconv[g]Wconv[g]^T/768

typedef unsigned short u16;
typedef unsigned int   u32;
typedef __attribute__((ext_vector_type(4))) float f32x4;
typedef __attribute__((ext_vector_type(4))) u32   u32x4;
typedef __attribute__((ext_vector_type(8))) short bf16x8;

__device__ __forceinline__ float bf2f(u16 v) { return __uint_as_float(((u32)v) << 16); }
__device__ __forceinline__ u16 f2bf(float f) {
  u32 u = __float_as_uint(f);
  u32 r = u + 0x7fffu + ((u >> 16) & 1u);  // RNE
  return (u16)(r >> 16);
}
__device__ __forceinline__ float gld(const void* p, long idx, int f32) {
  return f32 ? ((const float*)p)[idx] : bf2f(((const u16*)p)[idx]);
}

typedef const __attribute__((address_space(1))) u32 gas_u32;
typedef __attribute__((address_space(3))) u32 las_u32;

// async 16B/lane global->LDS; LDS dest = wave-uniform base + lane*16 (m97).
__device__ __forceinline__ void stage16(const u16* g, u16* lbase, int lane) {
#if __has_builtin(__builtin_amdgcn_global_load_lds)
  (void)lane;
  __builtin_amdgcn_global_load_lds((gas_u32*)g, (las_u32*)lbase, 16, 0, 0);
#else
  *(u32x4*)(lbase + lane * 8) = *(const u32x4*)g;
#endif
}

// ------------------------------------------------------------ dtype probe ---
__global__ __launch_bounds__(256) void probe_k(const u32* __restrict__ xw, int* __restrict__ flag) {
  int tid = threadIdx.x, c = 0;
  for (int i = tid; i < 4096; i += 256) {
    u16 lo = (u16)(xw[i] & 0xffffu);
    float a = fabsf(bf2f(lo));
    if (lo == 0 || (a >= 1e-3f && a <= 32.f)) ++c;
  }
#pragma unroll
  for (int o = 32; o; o >>= 1) c += __shfl_xor(c, o, 64);
  __shared__ int r[4];
  if ((tid & 63) == 0) r[tid >> 6] = c;
  __syncthreads();
  if (tid == 0) flag[0] = (r[0] + r[1] + r[2] + r[3] >= 2048) ? 0 : 1;  // 1 = fp32
}

// ------------------------------------------------------------ diag fill -----
__global__ __launch_bounds__(256) void fill_k(u16* p, float v, int n) {
  int i = blockIdx.x * 256 + threadIdx.x;
  if (i < n) p[i] = f2bf(v);
}

// --------------------------------------------------------------- prep_k -----
// blocks [0,3597): ext->bf16 copies (x, ctx, Wconv) + midi pad-row zeroing
// blocks [3597,11181): transposes Wq/Wk/Wo (768^2), Wv (768x6656), ctx^T
__global__ __launch_bounds__(256) void prep_k(
    const void* __restrict__ x,   u16* __restrict__ xb,
    const void* __restrict__ ctx, u16* __restrict__ cbuf,
    const void* __restrict__ Wcv, u16* __restrict__ wcvb,
    u16* __restrict__ midi,
    const void* __restrict__ Wq, const void* __restrict__ Wk,
    const void* __restrict__ Wo, const void* __restrict__ Wv,
    u16* __restrict__ wqt, u16* __restrict__ wkt, u16* __restrict__ wot,
    u16* __restrict__ wvt, u16* __restrict__ ctxT,
    const int* __restrict__ dtf, int fknown)
{
  const int f = (fknown >= 0) ? fknown : dtf[0];
  int bid = blockIdx.x;
  __shared__ float s[32][33];
  if (bid < 3597) {
    // ---- convb4 ----
    const long n0_ = 1277952, n1_ = 789504, n2_ = 5111808, n3_ = 186368;
    long i = ((long)bid * 256 + threadIdx.x) * 8;
    const long t0 = n0_, t1 = t0 + n1_, t2 = t1 + n2_, t3 = t2 + n3_;
    if (i >= t3) return;
    if (i >= t2) {
      long e = i - t2;                 // zero 7 pad rows per midi z-block
      long z = e / 448, off = e - z * 448;
      u32x4 zz = {0u, 0u, 0u, 0u};
      *(u32x4*)(midi + z * 16896 + 16448 + off) = zz;
      return;
    }
    const void* in; u16* out;
    if (i < t0)      { in = x;    out = xb; }
    else if (i < t1) { in = ctx;  out = cbuf; i -= t0; }
    else             { in = Wcv;  out = wcvb; i -= t1; }
    if (f) {
      const float* ip = (const float*)in + i;
      f32x4 a = *(const f32x4*)ip, b = *(const f32x4*)(ip + 4);
      u32x4 q = { (u32)f2bf(a.x) | ((u32)f2bf(a.y) << 16),
                  (u32)f2bf(a.z) | ((u32)f2bf(a.w) << 16),
                  (u32)f2bf(b.x) | ((u32)f2bf(b.y) << 16),
                  (u32)f2bf(b.z) | ((u32)f2bf(b.w) << 16) };
      *(u32x4*)(out + i) = q;
    } else {
      *(u32x4*)(out + i) = *(const u32x4*)((const u16*)in + i);
    }
  } else {
    // ---- transM ----
    int t = bid - 3597;
    const void* in; u16* out;
    int inK, inN, ldo, outK, nx;
    long inBase = 0, outBase = 0;
    if (t < 1728) {                    // 3 x 768x768 weights: 576 tiles each
      int w = t / 576; t -= w * 576;
      in  = w == 0 ? Wq : w == 1 ? Wk : Wo;
      out = w == 0 ? wqt : w == 1 ? wkt : wot;
      inK = 768; inN = 768; ldo = 768; outK = 768; nx = 24;
    } else if (t < 6720) {             // Wv 768x6656: 208 n-tiles x 24 k-tiles
      t -= 1728;
      in = Wv; out = wvt;
      inK = 768; inN = 6656; ldo = 768; outK = 768; nx = 208;
    } else {                           // ctxT: 4 b x (24 n-tiles x 9 k-tiles)
      t -= 6720;
      int b = t / 216; t -= b * 216;
      in = ctx; out = ctxT;
      inK = 257; inN = 768; ldo = 264; outK = 264; nx = 24;
      inBase = (long)b * 257 * 768; outBase = (long)b * 768 * 264;
    }
    int n0 = (t % nx) * 32, k0 = (t / nx) * 32;
    int tx = threadIdx.x & 31, ty = threadIdx.x >> 5;  // 32 x 8
#pragma unroll
    for (int i = 0; i < 32; i += 8) {
      int k = k0 + ty + i, n = n0 + tx;
      float v = 0.f;
      if (k < inK && n < inN) v = gld(in, inBase + (long)k * inN + n, f);
      s[ty + i][tx] = v;
    }
    __syncthreads();
#pragma unroll
    for (int i = 0; i < 32; i += 8) {
      int n = n0 + ty + i, k = k0 + tx;
      if (n < inN && k < outK) out[outBase + (long)n * ldo + k] = f2bf(s[tx][ty + i]);
    }
  }
}

// ------------------------------------------------------------- gemm128 ------
// C_bf16 = A_bf16[M,K] @ B_bf16[N,K]^T. Requires N%128==0, K%32==0; M-tail via
// row-clamped staging + guarded writes. 128x128 tile, BK=32, 4 waves each 64x64.
__device__ __forceinline__ void gemm128_body(
    const u16* __restrict__ A, const u16* __restrict__ B, u16* __restrict__ C,
    int M, int N, int K, int lda, int ldb, int ldc, int m0, int n0)
{
  __shared__ __attribute__((aligned(16))) u16 As[128 * 32];
  __shared__ __attribute__((aligned(16))) u16 Bs[128 * 32];
  const int tid = threadIdx.x, lane = tid & 63, wave = tid >> 6;
  const int wm = (wave >> 1) * 64, wn = (wave & 1) * 64;
  const int fm = lane & 15, fq = lane >> 4;

  const int srow = lane >> 2, selem = (lane & 3) * 8;
  int ra1 = m0 + wave * 16 + srow;      if (ra1 > M - 1) ra1 = M - 1;
  int ra2 = m0 + 64 + wave * 16 + srow; if (ra2 > M - 1) ra2 = M - 1;
  const int rb1 = n0 + wave * 16 + srow;
  const int rb2 = n0 + 64 + wave * 16 + srow;
  const u16* pa1 = A + (long)ra1 * lda + selem;
  const u16* pa2 = A + (long)ra2 * lda + selem;
  const u16* pb1 = B + (long)rb1 * ldb + selem;
  const u16* pb2 = B + (long)rb2 * ldb + selem;
  u16* la1 = As + wave * 512;
  u16* la2 = As + 2048 + wave * 512;
  u16* lb1 = Bs + wave * 512;
  u16* lb2 = Bs + 2048 + wave * 512;

  f32x4 acc[4][4];
  const f32x4 zero4 = {0.f, 0.f, 0.f, 0.f};
#pragma unroll
  for (int a_ = 0; a_ < 4; ++a_)
#pragma unroll
    for (int b_ = 0; b_ < 4; ++b_) acc[a_][b_] = zero4;

  for (int k0 = 0; k0 < K; k0 += 32) {
    stage16(pa1, la1, lane);
    stage16(pa2, la2, lane);
    stage16(pb1, lb1, lane);
    stage16(pb2, lb2, lane);
    pa1 += 32; pa2 += 32; pb1 += 32; pb2 += 32;
    __syncthreads();
    bf16x8 fa[4], fb[4];
#pragma unroll
    for (int mt = 0; mt < 4; ++mt)
      fa[mt] = *(const bf16x8*)&As[(wm + mt * 16 + fm) * 32 + fq * 8];
#pragma unroll
    for (int nt = 0; nt < 4; ++nt)
      fb[nt] = *(const bf16x8*)&Bs[(wn + nt * 16 + fm) * 32 + fq * 8];
#pragma unroll
    for (int mt = 0; mt < 4; ++mt)
#pragma unroll
      for (int nt = 0; nt < 4; ++nt)
        acc[mt][nt] = __builtin_amdgcn_mfma_f32_16x16x32_bf16(fa[mt], fb[nt], acc[mt][nt], 0, 0, 0);
    __syncthreads();
  }
#pragma unroll
  for (int mt = 0; mt < 4; ++mt)
#pragma unroll
    for (int nt = 0; nt < 4; ++nt)
#pragma unroll
      for (int rr = 0; rr < 4; ++rr) {
        int gm = m0 + wm + mt * 16 + fq * 4 + rr;
        int gn = n0 + wn + nt * 16 + fm;
        if (gm < M) C[(long)gm * ldc + gn] = f2bf(acc[mt][nt][rr]);
      }
}

__global__ __launch_bounds__(256) void gemm128(
    const u16* __restrict__ A, const u16* __restrict__ B, u16* __restrict__ C,
    int M, int N, int K, int lda, int ldb, int ldc)
{
  gemm128_body(A, B, C, M, N, K, lda, ldb, ldc, blockIdx.x * 128, blockIdx.y * 128);
}

// ------------------------------------------------- gemm64 body (all-bf16) ---
// 64x64 tile, BK=32, 2x2 acc/wave. Pointers pre-offset by caller (batch z).
// If Ylds != nullptr: fp32 tile -> LDS (caller epilogue); Ylds may alias As/Bs.
#define LDS_S 40

__device__ __forceinline__ void gemm64_body(
    u16* As, u16* Bs,
    const u16* __restrict__ A16, const u16* __restrict__ B16,
    float* Cf, u16* Cb, float* Ylds,
    int M, int N, int K, int lda, int ldb, int ldc,
    int btrans, float alpha, int m0, int n0)
{
  const int tid = threadIdx.x;
  const int lane = tid & 63, wave = tid >> 6;
  const int wm = (wave >> 1) * 32, wn = (wave & 1) * 32;
  const int fm = lane & 15, fq = lane >> 4;
  const int ar = tid >> 2, ak = (tid & 3) * 8;
  const int bk = tid >> 3, bn = (tid & 7) * 8;

  f32x4 acc[2][2];
  const f32x4 zero4 = {0.f, 0.f, 0.f, 0.f};
#pragma unroll
  for (int a_ = 0; a_ < 2; ++a_)
#pragma unroll
    for (int b_ = 0; b_ < 2; ++b_) acc[a_][b_] = zero4;

  for (int k0 = 0; k0 < K; k0 += 32) {
    {
      int gm = m0 + ar, gk = k0 + ak;
      long idx = (long)gm * lda + gk;
      if (gm < M && gk + 8 <= K) {
        *(u32x4*)&As[ar * LDS_S + ak] = *(const u32x4*)(A16 + idx);
      } else {
#pragma unroll
        for (int e = 0; e < 8; ++e)
          As[ar * LDS_S + ak + e] = (gm < M && gk + e < K) ? A16[idx + e] : (u16)0;
      }
    }
    if (btrans) {
      int gn = n0 + ar, gk = k0 + ak;
      long idx = (long)gn * ldb + gk;
      if (gn < N && gk + 8 <= K) {
        *(u32x4*)&Bs[ar * LDS_S + ak] = *(const u32x4*)(B16 + idx);
      } else {
#pragma unroll
        for (int e = 0; e < 8; ++e)
          Bs[ar * LDS_S + ak + e] = (gn < N && gk + e < K) ? B16[idx + e] : (u16)0;
      }
    } else {
      int gk = k0 + bk;
      long idx = (long)gk * ldb + n0 + bn;
      u16 tmp[8];
      if (gk < K) {
        u32x4 v = *(const u32x4*)(B16 + idx);
        tmp[0] = (u16)(v.x & 0xffff); tmp[1] = (u16)(v.x >> 16);
        tmp[2] = (u16)(v.y & 0xffff); tmp[3] = (u16)(v.y >> 16);
        tmp[4] = (u16)(v.z & 0xffff); tmp[5] = (u16)(v.z >> 16);
        tmp[6] = (u16)(v.w & 0xffff); tmp[7] = (u16)(v.w >> 16);
      } else {
#pragma unroll
        for (int e = 0; e < 8; ++e) tmp[e] = 0;
      }
      int rot = tid & 7;  // spread LDS bank writes
#pragma unroll
      for (int e = 0; e < 8; ++e) {
        int ee = (e + rot) & 7;
        Bs[(bn + ee) * LDS_S + bk] = tmp[ee];
      }
    }
    __syncthreads();
    {
      bf16x8 fa[2], fb[2];
      fa[0] = *(const bf16x8*)&As[(wm +      fm) * LDS_S + fq * 8];
      fa[1] = *(const bf16x8*)&As[(wm + 16 + fm) * LDS_S + fq * 8];
      fb[0] = *(const bf16x8*)&Bs[(wn +      fm) * LDS_S + fq * 8];
      fb[1] = *(const bf16x8*)&Bs[(wn + 16 + fm) * LDS_S + fq * 8];
#pragma unroll
      for (int mt = 0; mt < 2; ++mt)
#pragma unroll
        for (int nt = 0; nt < 2; ++nt)
          acc[mt][nt] = __builtin_amdgcn_mfma_f32_16x16x32_bf16(fa[mt], fb[nt], acc[mt][nt], 0, 0, 0);
    }
    __syncthreads();
  }
  if (Ylds) {
    // all LDS reads complete past the final barrier; safe to overwrite As/Bs
#pragma unroll
    for (int mt = 0; mt < 2; ++mt)
#pragma unroll
      for (int nt = 0; nt < 2; ++nt)
#pragma unroll
        for (int rr = 0; rr < 4; ++rr)
          Ylds[(wm + mt * 16 + fq * 4 + rr) * 64 + (wn + nt * 16 + fm)] = acc[mt][nt][rr];
  } else {
#pragma unroll
    for (int mt = 0; mt < 2; ++mt)
#pragma unroll
      for (int nt = 0; nt < 2; ++nt)
#pragma unroll
        for (int rr = 0; rr < 4; ++rr) {
          int gm = m0 + wm + mt * 16 + fq * 4 + rr;
          int gn = n0 + wn + nt * 16 + fm;
          if (gm < M && gn < N) {
            float v = alpha * acc[mt][nt][rr];
            if (Cb) Cb[(long)gm * ldc + gn] = f2bf(v);
            else    Cf[(long)gm * ldc + gn] = v;
          }
        }
  }
}

// ------------------- mg4: q/k/mid gemm128s + Gram gemm + wbar (bf16) --------
__global__ __launch_bounds__(256) void mg4_k(
    const u16* __restrict__ xb, const u16* __restrict__ wqt, u16* __restrict__ qbf,
    const u16* __restrict__ cbuf, const u16* __restrict__ wkt, u16* __restrict__ kbf,
    const u16* __restrict__ wvt, u16* __restrict__ midbf,
    const u16* __restrict__ wcvb, u16* __restrict__ Gb, float* __restrict__ wbar)
{
  int bid = blockIdx.x;
  if (bid < 600) {
    const u16 *A, *B; u16* C; int M, N, lid, mx;
    if (bid < 78)       { A = xb;   B = wqt; C = qbf;   M = 1664; N = 768;  lid = bid;       mx = 13; }
    else if (bid < 132) { A = cbuf; B = wkt; C = kbf;   M = 1028; N = 768;  lid = bid - 78;  mx = 9;  }
    else                { A = cbuf; B = wvt; C = midbf; M = 1028; N = 6656; lid = bid - 132; mx = 9;  }
    int m0 = (lid % mx) * 128, n0 = (lid / mx) * 128;
    gemm128_body(A, B, C, M, N, 768, 768, 768, N, m0, n0);
  } else if (bid < 704) {
    __shared__ __attribute__((aligned(16))) u16 As[64 * LDS_S];
    __shared__ __attribute__((aligned(16))) u16 Bs[64 * LDS_S];
    int z = bid - 600;   // 0..103: M[g] = Wconv_b[g] @ Wconv_b[g]^T / 768
    gemm64_body(As, Bs, wcvb + (long)z * 49152, wcvb + (long)z * 49152,
                nullptr, Gb + (long)z * 4096, nullptr,
                64, 64, 768, 768, 768, 64, 1, 1.f / 768.f, 0, 0);
  } else {
    // wbar: row means of bf16 Wconv copy, r = g*64+l over 768 cols
    int r = (bid - 704) * 4 + (threadIdx.x >> 6);
    int lane = threadIdx.x & 63;
    const u16* prow = wcvb + (long)r * 768;
    float sm = 0.f;
    for (int c = lane; c < 768; c += 64) sm += bf2f(prow[c]);
#pragma unroll
    for (int o = 32; o; o >>= 1) sm += __shfl_xor(sm, o, 64);
    if (lane == 0) wbar[r] = sm * (1.f / 768.f);
  }
}

// --------------------- ysim: Y-gemm with fused stats epilogue + sim-gemm ----
__global__ __launch_bounds__(256) void ysim_k(
    const u16* __restrict__ midbf, const u16* __restrict__ Gb,
    const float* __restrict__ wbar, u16* __restrict__ midi, float* __restrict__ pim,
    const u16* __restrict__ qbf, const u16* __restrict__ kbf, float* __restrict__ simf)
{
  __shared__ __attribute__((aligned(16))) char smem[16384];
  u16* As = (u16*)smem;
  u16* Bs = (u16*)(smem + 8192);
  int bid = blockIdx.x;
  if (bid < 1768) {
    // Y = mid_g[1028x64] @ M[g]^T -> fp32 tile in LDS, then stats epilogue
    int g = bid / 17, bx = bid % 17;
    int m0 = bx * 64;
    float* Ylds = (float*)smem;   // aliases As/Bs (dead after final barrier)
    gemm64_body(As, Bs, midbf + (long)g * 64, Gb + (long)g * 4096,
                nullptr, nullptr, Ylds,
                1028, 64, 64, 6656, 64, 64, 1, 1.f, m0, 0);
    __syncthreads();
    int tid = threadIdx.x, lane = tid & 63, wave = tid >> 6;
#pragma unroll
    for (int rr = 0; rr < 16; ++rr) {
      int r = wave * 16 + rr;          // local row
      int gr = m0 + r;                 // global row (wave-uniform)
      if (gr < 1028) {
        float m  = bf2f(midbf[(long)gr * 6656 + g * 64 + lane]);
        float y  = Ylds[r * 64 + lane];
        float wb = wbar[g * 64 + lane];
        float mup = m * wb, q2p = m * y;
#pragma unroll
        for (int o = 32; o; o >>= 1) { mup += __shfl_xor(mup, o, 64); q2p += __shfl_xor(q2p, o, 64); }
        float var = q2p - mup * mup;
        float inv = rsqrtf(fmaxf(var, 0.f) + 1e-5f);
        int b = gr / 257, j = gr - b * 257;
        long zidx = (long)b * 104 + g;
        midi[(zidx * 264 + j) * 64 + lane] = f2bf(inv * m);
        if (lane == 0) pim[zidx * 257 + j] = inv * mup;
      }
    }
  } else {
    // sim = scale^2 * q @ k^T;  z = b*6+h
    int lid = bid - 1768; int z = lid / 35, r = lid % 35, bx = r % 7, by = r / 7;
    const u16* A = qbf + (long)(z / 6) * 319488 + (long)(z % 6) * 128;
    const u16* B = kbf + (long)(z / 6) * 197376 + (long)(z % 6) * 128;
    float* Cf = simf + (long)z * 106912;
    gemm64_body(As, Bs, A, B, Cf, nullptr, nullptr,
                416, 257, 128, 768, 768, 257, 1, 0.08838834764831845f, bx * 64, by * 64);
  }
}

// --------------------------------------------------- ct: c-gemm + T-gemm ----
__global__ __launch_bounds__(256) void ct_k(
    const u16* __restrict__ Abf, const u16* __restrict__ ctxT, float* __restrict__ c_buf,
    const u16* __restrict__ A2bf, const u16* __restrict__ midi, u16* __restrict__ Tb16)
{
  __shared__ __attribute__((aligned(16))) u16 As[64 * LDS_S];
  __shared__ __attribute__((aligned(16))) u16 Bs[64 * LDS_S];
  int bid = blockIdx.x;
  if (bid < 336) {
    // c = A @ ctx_head (btrans via ctx^T, K=264); z = b*6+h
    int z = bid / 14, r = bid % 14, bx = r % 7, by = r / 7;
    const u16* A = Abf + (long)z * 109824;
    const u16* B = ctxT + (long)(z / 6) * 202752 + (long)(z % 6) * 33792;
    float* Cf = c_buf + (long)z * 53248;
    gemm64_body(As, Bs, A, B, Cf, nullptr, nullptr,
                416, 128, 264, 264, 264, 128, 1, 1.f, bx * 64, by * 64);
  } else {
    // T = A2 @ midi (non-trans, K=264, 264-row-padded midi); z = b*104+g
    int z = bid - 336;
    const u16* A = A2bf + (long)z * 6336;
    const u16* B = midi + (long)z * 16896;
    u16* Cb = Tb16 + (long)z * 1536;
    gemm64_body(As, Bs, A, B, nullptr, Cb, nullptr,
                24, 64, 264, 264, 64, 64, 0, 1.f, 0, 0);
  }
}

// ------------------------------------------------------------- row LN -------
__device__ __forceinline__ void ln_row(
    const u16* __restrict__ ip, const void* __restrict__ g, const void* __restrict__ b,
    u16* __restrict__ ob, float* __restrict__ of, int N, int f)
{
  int tid = threadIdx.x, lane = tid & 63, wave = tid >> 6;
  const int nv = N >> 3;
  float s1 = 0.f, s2 = 0.f;
  for (int c8 = tid; c8 < nv; c8 += 256) {
    u32x4 v = *(const u32x4*)(ip + c8 * 8);
    float e0 = bf2f((u16)(v.x & 0xffff)), e1 = bf2f((u16)(v.x >> 16));
    float e2 = bf2f((u16)(v.y & 0xffff)), e3 = bf2f((u16)(v.y >> 16));
    float e4 = bf2f((u16)(v.z & 0xffff)), e5 = bf2f((u16)(v.z >> 16));
    float e6 = bf2f((u16)(v.w & 0xffff)), e7 = bf2f((u16)(v.w >> 16));
    s1 += ((e0 + e1) + (e2 + e3)) + ((e4 + e5) + (e6 + e7));
    s2 += ((e0*e0 + e1*e1) + (e2*e2 + e3*e3)) + ((e4*e4 + e5*e5) + (e6*e6 + e7*e7));
  }
#pragma unroll
  for (int o = 32; o; o >>= 1) { s1 += __shfl_xor(s1, o, 64); s2 += __shfl_xor(s2, o, 64); }
  __shared__ float red[8];
  if (lane == 0) { red[wave] = s1; red[4 + wave] = s2; }
  __syncthreads();
  s1 = red[0] + red[1] + red[2] + red[3];
  s2 = red[4] + red[5] + red[6] + red[7];
  float mean = s1 / N;
  float var = s2 / N - mean * mean;
  float rstd = rsqrtf(fmaxf(var, 0.f) + 1e-5f);
  for (int c8 = tid; c8 < nv; c8 += 256) {
    int c = c8 * 8;
    u32x4 v = *(const u32x4*)(ip + c);
    float e[8];
    e[0] = bf2f((u16)(v.x & 0xffff)); e[1] = bf2f((u16)(v.x >> 16));
    e[2] = bf2f((u16)(v.y & 0xffff)); e[3] = bf2f((u16)(v.y >> 16));
    e[4] = bf2f((u16)(v.z & 0xffff)); e[5] = bf2f((u16)(v.z >> 16));
    e[6] = bf2f((u16)(v.w & 0xffff)); e[7] = bf2f((u16)(v.w >> 16));
    float gg[8], bb[8];
    if (f) {
      const float* gp = (const float*)g + c; const float* bp = (const float*)b + c;
      f32x4 g0 = *(const f32x4*)gp, g1 = *(const f32x4*)(gp + 4);
      f32x4 b0 = *(const f32x4*)bp, b1 = *(const f32x4*)(bp + 4);
      gg[0]=g0.x; gg[1]=g0.y; gg[2]=g0.z; gg[3]=g0.w; gg[4]=g1.x; gg[5]=g1.y; gg[6]=g1.z; gg[7]=g1.w;
      bb[0]=b0.x; bb[1]=b0.y; bb[2]=b0.z; bb[3]=b0.w; bb[4]=b1.x; bb[5]=b1.y; bb[6]=b1.z; bb[7]=b1.w;
    } else {
      u32x4 gv = *(const u32x4*)((const u16*)g + c);
      u32x4 bv = *(const u32x4*)((const u16*)b + c);
      gg[0]=bf2f((u16)(gv.x&0xffff)); gg[1]=bf2f((u16)(gv.x>>16));
      gg[2]=bf2f((u16)(gv.y&0xffff)); gg[3]=bf2f((u16)(gv.y>>16));
      gg[4]=bf2f((u16)(gv.z&0xffff)); gg[5]=bf2f((u16)(gv.z>>16));
      gg[6]=bf2f((u16)(gv.w&0xffff)); gg[7]=bf2f((u16)(gv.w>>16));
      bb[0]=bf2f((u16)(bv.x&0xffff)); bb[1]=bf2f((u16)(bv.x>>16));
      bb[2]=bf2f((u16)(bv.y&0xffff)); bb[3]=bf2f((u16)(bv.y>>16));
      bb[4]=bf2f((u16)(bv.z&0xffff)); bb[5]=bf2f((u16)(bv.z>>16));
      bb[6]=bf2f((u16)(bv.w&0xffff)); bb[7]=bf2f((u16)(bv.w>>16));
    }
    float o_[8];
#pragma unroll
    for (int e2i = 0; e2i < 8; ++e2i) o_[e2i] = (e[e2i] - mean) * rstd * gg[e2i] + bb[e2i];
    if (of) {
      f32x4 o0 = {o_[0], o_[1], o_[2], o_[3]}, o1 = {o_[4], o_[5], o_[6], o_[7]};
      *(f32x4*)(of + c) = o0; *(f32x4*)(of + c + 4) = o1;
    } else {
      u32x4 q = { (u32)f2bf(o_[0]) | ((u32)f2bf(o_[1]) << 16),
                  (u32)f2bf(o_[2]) | ((u32)f2bf(o_[3]) << 16),
                  (u32)f2bf(o_[4]) | ((u32)f2bf(o_[5]) << 16),
                  (u32)f2bf(o_[6]) | ((u32)f2bf(o_[7]) << 16) };
      *(u32x4*)(ob + c) = q;
    }
  }
}

__global__ __launch_bounds__(256) void ln_rows(
    const u16* __restrict__ in, const void* __restrict__ g, const void* __restrict__ b,
    void* __restrict__ out, int N, const int* __restrict__ dtf, int isfinal, int fknown)
{
  const int f = (fknown >= 0) ? fknown : dtf[0];
  long row = blockIdx.x;
  const u16* ip = in + row * N;
  float* of = (isfinal && f) ? (float*)out + row * N : nullptr;
  u16*   ob = of ? nullptr : (u16*)out + row * N;
  ln_row(ip, g, b, ob, of, N, f);
}

// merged LN for q (1664x768), k (1028x768), mid (1028x6656)
__global__ __launch_bounds__(256) void mln3_k(
    u16* __restrict__ qb, const void* __restrict__ gq, const void* __restrict__ bq,
    u16* __restrict__ kb, const void* __restrict__ gk, const void* __restrict__ bk,
    u16* __restrict__ mb, const void* __restrict__ gv, const void* __restrict__ bv,
    const int* __restrict__ dtf, int fknown)
{
  const int f = (fknown >= 0) ? fknown : dtf[0];
  int row = blockIdx.x;
  u16* ip; const void *g, *b; int N;
  if (row < 1664)      { ip = qb + (long)row * 768; g = gq; b = bq; N = 768; }
  else if (row < 2692) { ip = kb + (long)(row - 1664) * 768; g = gk; b = bk; N = 768; }
  else                 { ip = mb + (long)(row - 2692) * 6656; g = gv; b = bv; N = 6656; }
  ln_row(ip, g, b, ip, nullptr, N, f);
}

// ------------------------------------------------------------- softmax ------
__global__ __launch_bounds__(256) void softmax_k(
    const float* __restrict__ simf, const float* __restrict__ pim,
    u16* __restrict__ Abf, u16* __restrict__ A2bf, float* __restrict__ s_sh)
{
  int bh = blockIdx.x;
  int b = bh / 6, h = bh - b * 6;
  int tid = threadIdx.x, lane = tid & 63, wave = tid >> 6;
  int i = blockIdx.y * 4 + wave;
  int g = i % 104, rq = i / 104;
  const float* sp_ = simf + ((long)bh * 416 + i) * 257;
  float s[5];
#pragma unroll
  for (int jc = 0; jc < 5; ++jc) {
    int j = jc * 64 + lane;
    s[jc] = (j < 257) ? sp_[j] : -1e30f;
  }
  float mx = -1e30f;
#pragma unroll
  for (int jc = 0; jc < 5; ++jc) mx = fmaxf(mx, s[jc]);
#pragma unroll
  for (int o = 32; o; o >>= 1) mx = fmaxf(mx, __shfl_xor(mx, o, 64));
  float p[5], sum = 0.f, sp = 0.f;
  long pimb = ((long)b * 104 + g) * 257;
#pragma unroll
  for (int jc = 0; jc < 5; ++jc) {
    int j = jc * 64 + lane;
    float pv = 0.f;
    if (j < 257) { pv = __expf(s[jc] - mx); sp = fmaf(pv, pim[pimb + j], sp); }
    p[jc] = pv; sum += pv;
  }
#pragma unroll
  for (int o = 32; o; o >>= 1) { sum += __shfl_xor(sum, o, 64); sp += __shfl_xor(sp, o, 64); }
  float rs = 1.f / sum;
  long arow  = ((long)bh * 416 + i) * 264;
  long a2row = (((long)b * 104 + g) * 24 + h * 4 + rq) * 264;
#pragma unroll
  for (int jc = 0; jc < 5; ++jc) {
    int j = jc * 64 + lane;
    if (j < 257) { u16 pb = f2bf(p[jc] * rs); Abf[arow + j] = pb; A2bf[a2row + j] = pb; }
    else if (j < 264) { Abf[arow + j] = 0; A2bf[a2row + j] = 0; }
  }
  if (lane == 0) s_sh[(long)bh * 416 + i] = sp * rs;
}

// -------------------------------------------------- fused O-gemm + combine --
__global__ __launch_bounds__(256) void oc_k(
    const u16* __restrict__ T, const u16* __restrict__ Wb,
    const float* __restrict__ s_sh, const float* __restrict__ c_buf,
    const void* __restrict__ gv2, const void* __restrict__ bv2,
    u16* __restrict__ opbf, const int* __restrict__ dtf, int fknown)
{
  const int f = (fknown >= 0) ? fknown : dtf[0];
  int z = blockIdx.x;                 // b*104+g
  int b = z / 104, g = z - b * 104;
  int tid = threadIdx.x;
  __shared__ float Ts[24][64];        // 6 KB
  const u16* tp = T + (long)z * 1536;
  for (int idx = tid; idx < 1536; idx += 256) Ts[idx >> 6][idx & 63] = bf2f(tp[idx]);
  __syncthreads();
  const int dh = tid & 127;
  const int hbase = (tid >> 7) * 3;   // threads 0..127 -> h 0..2, 128..255 -> h 3..5
  const u16* wg = Wb + (long)g * 49152;
#pragma unroll
  for (int hh = 0; hh < 3; ++hh) {
    int h = hbase + hh;
    int d = h * 128 + dh;
    const u16* wp = wg + d;
    float a0 = 0.f, a1 = 0.f, a2 = 0.f, a3 = 0.f;
#pragma unroll 16
    for (int k = 0; k < 64; ++k) {
      float w = bf2f(wp[(long)k * 768]);
      a0 = fmaf(Ts[h * 4 + 0][k], w, a0);
      a1 = fmaf(Ts[h * 4 + 1][k], w, a1);
      a2 = fmaf(Ts[h * 4 + 2][k], w, a2);
      a3 = fmaf(Ts[h * 4 + 3][k], w, a3);
    }
    float acc[4] = {a0, a1, a2, a3};
    float gvd = gld(gv2, d, f), bvd = gld(bv2, d, f);
#pragma unroll
    for (int rq = 0; rq < 4; ++rq) {
      int i = rq * 104 + g;
      float ssh = s_sh[((long)b * 6 + h) * 416 + i];
      float val = gvd * (acc[rq] - ssh) + bvd
                + c_buf[(((long)b * 6 + h) * 416 + i) * 128 + dh];
      opbf[((long)b * 416 + i) * 768 + d] = f2bf(val);
    }
  }
}

// ---------------------------------------------------------------- host ------
extern "C" void kernel_launch(void* const* d_in, const int* in_sizes, int n_in,
                              void* d_out, int out_size, void* d_ws, size_t ws_size,
                              hipStream_t stream)
{
  const void* x   = d_in[0];
  const void* ctx = d_in[1];
  const void* Wq  = d_in[2];
  const void* gq  = d_in[3];
  const void* bq  = d_in[4];
  const void* Wk  = d_in[5];
  const void* gk  = d_in[6];
  const void* bk  = d_in[7];
  const void* Wv  = d_in[8];
  const void* gv1 = d_in[9];
  const void* bv1 = d_in[10];
  const void* Wcv = d_in[11];
  const void* gv2 = d_in[12];
  const void* bv2 = d_in[13];
  const void* Wo  = d_in[14];
  const void* go  = d_in[15];
  const void* bo  = d_in[16];

  // -------- workspace layout --------
  const size_t SZ_FLAG = 256;
  const size_t SZ_QBF  = 2555904;
  const size_t SZ_KBF  = 1579008;
  const size_t SZ_MID  = 13684736;
  const size_t SZ_MM   = 1703936;
  const size_t SZ_WB   = 26624;
  const size_t SZ_MIDI = 14057472;   // 416 * 264 * 64 bf16 (264-row padded)
  const size_t SZ_PIM  = 427648;
  const size_t SZ_ABF  = 5271552;
  const size_t SZ_A2   = 5271552;
  const size_t SZ_SSH  = 39936;
  const size_t SZ_CB   = 1579008;
  const size_t SZ_WCVB = 10223616;   // 104*64*768 bf16
  const size_t SZ_WT   = 1179648;    // 768*768 bf16 (x3: WqT, WkT, WoT)
  const size_t SZ_WVT  = 10223616;   // 6656*768 bf16
  const size_t SZ_CTXT = 1622016;    // 4*768*264 bf16 (ctx^T, zero-padded cols)
  const size_t SZ_SIMF = 10263552;   // 24*416*257 fp32
  const size_t REQUIRED = SZ_FLAG + SZ_QBF + SZ_KBF + SZ_MID + SZ_MM + SZ_WB +
                          SZ_MIDI + SZ_PIM + SZ_ABF + SZ_A2 + SZ_SSH + SZ_CB +
                          SZ_WCVB + 3 * SZ_WT + SZ_WVT + SZ_CTXT + SZ_SIMF;  // 82,069,376

  if (ws_size < REQUIRED) {
    fill_k<<<(out_size + 255) / 256, 256, 0, stream>>>((u16*)d_out, (float)(ws_size >> 20), out_size);
    return;
  }

  char* p = (char*)d_ws;
  int*   dtf   = (int*)  p;                 p += SZ_FLAG;
  u16*   qbf   = (u16*)  p;                 p += SZ_QBF;
  u16*   kbf   = (u16*)  p;                 p += SZ_KBF;
  char*  midrg = p;                         p += SZ_MID;
  char*  mmrg  = p;                         p += SZ_MM;
  float* wbar  = (float*)p;                 p += SZ_WB;
  u16*   midi  = (u16*)  p;                 p += SZ_MIDI;
  float* pim   = (float*)p;                 p += SZ_PIM;
  char*  abfrg = p;                         p += SZ_ABF;
  u16*   A2bf  = (u16*)  p;                 p += SZ_A2;
  float* s_sh  = (float*)p;                 p += SZ_SSH;
  u16*   cb    = (u16*)  p;                 p += SZ_CB;
  u16*   wcvb  = (u16*)  p;                 p += SZ_WCVB;
  u16*   wqt2  = (u16*)  p;                 p += SZ_WT;
  u16*   wkt2  = (u16*)  p;                 p += SZ_WT;
  u16*   wot2  = (u16*)  p;                 p += SZ_WT;
  u16*   wvt   = (u16*)  p;                 p += SZ_WVT;
  u16*   ctxT  = (u16*)  p;                 p += SZ_CTXT;
  float* simf  = (float*)p;                 p += SZ_SIMF;

  u16*   midbf = (u16*)midrg;
  float* c_buf = (float*)midrg;             // midbf dead after ysim stats
  u16*   Tb16  = (u16*)(midrg + 5111808);   // right after c_buf's 5,111,808 B
  u16*   Gb    = (u16*)mmrg;
  u16*   xb    = (u16*)abfrg;
  u16*   Abf   = (u16*)abfrg;
  u16*   opbf  = (u16*)abfrg;               // Abf dead after ct_k

  // host-side dtype: in_sizes[0] in bytes distinguishes fp32 (5,111,808) from
  // bf16 (2,555,904); anything else (e.g. element count) -> probe fallback.
  int fknown = -1;
  if (in_sizes && n_in > 0) {
    if (in_sizes[0] == 5111808)      fknown = 1;
    else if (in_sizes[0] == 2555904) fknown = 0;
  }
  if (fknown < 0) probe_k<<<1, 256, 0, stream>>>((const u32*)x, dtf);

  // prep: copies + midi pad zero (3597) | transposes (7584)
  prep_k<<<11181, 256, 0, stream>>>(x, xb, ctx, cb, Wcv, wcvb, midi,
                                    Wq, Wk, Wo, Wv, wqt2, wkt2, wot2, wvt, ctxT,
                                    dtf, fknown);

  // q/k/mid gemm128s (600) + Gram (104) + wbar (1664, bf16 wcvb)
  mg4_k<<<2368, 256, 0, stream>>>(xb, wqt2, qbf, cb, wkt2, kbf, wvt, midbf,
                                  wcvb, Gb, wbar);

  // q/k/mid LNs
  mln3_k<<<3720, 256, 0, stream>>>(qbf, gq, bq, kbf, gk, bk, midbf, gv1, bv1,
                                   dtf, fknown);

  // Y = mid_g @ M[g] with fused stats epilogue (1768) + sim (840)
  ysim_k<<<2608, 256, 0, stream>>>(midbf, Gb, wbar, midi, pim, qbf, kbf, simf);

  softmax_k<<<dim3(24, 104), 256, 0, stream>>>(simf, pim, Abf, A2bf, s_sh);

  // c = A @ ctx_head (336) + T = A2 @ midi (416)
  ct_k<<<752, 256, 0, stream>>>(Abf, ctxT, c_buf, A2bf, midi, Tb16);

  // fused O-gemm + combine
  oc_k<<<416, 256, 0, stream>>>(Tb16, wcvb, s_sh, c_buf, gv2, bv2, opbf, dtf, fknown);

  // out = LN(out_pre @ Wo)
  {
    dim3 grid(13, 6, 1);
    gemm128<<<grid, dim3(256), 0, stream>>>(opbf, wot2, qbf, 1664, 768, 768, 768, 768, 768);
  }
  ln_rows<<<1664, 256, 0, stream>>>(qbf, go, bo, d_out, 768, dtf, 1, fknown);
}

// Round 11
// 262.002 us; speedup vs baseline: 3.0825x; 1.0440x over previous
//
#include <hip/hip_runtime.h>

// SubjBasisGenerator fused pipeline. B=4 NQ=416 NC=257 D=768 H=6 DH=128 G=104 R=4 LORA=64
// R21: counters finally showed mg4_k = 43.6us @ MfmaUtil 12.7%, Occ 25% —
//      grid-starved (600 gemm blocks / 256 CU = 2.3/CU; nothing saturated).
//      Retiled q/k/mid + final Wo GEMM from 128x128 to 64x128 (gemm64128):
//      same BK=32 / staging / accumulation order (bitwise-identical numerics),
//      2x blocks (mid 468->884, q 78->156, k 54->102, final 78->156).
//      mg4 LDS unioned to 16KB (was 26.6KB summed across branches).
// R20: wbar in mg4 (bf16 wcvb); host-side dtype from in_sizes[0] (probe
//      fallback). R19 lesson: phases are latency/TLP-bound; wave count is the
//      currency — fusions must not reduce resident-wave parallelism.
// R16: stats2 fused into Y-gemm epilogue (fp32 Y in LDS, yfull deleted).
// R14: dispatch 16->11 (prep/mg4/ysim/ct merges).
// R13/R12: merged q/k/mid gemms (B-panel-major), merged LNs/transposes,
//      ctx^T btrans fast path, K padded 257->264, 264-row-padded midi.
// R11: oc_k fusion (O-gemm+combine), Wconv bf16 pre-convert.
//
// Algebra: the grouped-conv+LN v-path decomposes exactly:
//   sum_j A_j v_j = gv2*( (sum_j A_j inv_j mid_j)@Wconv[g] - sum_j A_j inv_j mu_j )
//                   + bv2 + (A @ ctx)
//   q2[b,g,j] = mid^T M[g] mid = mid . (M[g] @ mid),  M[g] = Wconv[g]Wconv[g]^T/768

typedef unsigned short u16;
typedef unsigned int   u32;
typedef __attribute__((ext_vector_type(4))) float f32x4;
typedef __attribute__((ext_vector_type(4))) u32   u32x4;
typedef __attribute__((ext_vector_type(8))) short bf16x8;

__device__ __forceinline__ float bf2f(u16 v) { return __uint_as_float(((u32)v) << 16); }
__device__ __forceinline__ u16 f2bf(float f) {
  u32 u = __float_as_uint(f);
  u32 r = u + 0x7fffu + ((u >> 16) & 1u);  // RNE
  return (u16)(r >> 16);
}
__device__ __forceinline__ float gld(const void* p, long idx, int f32) {
  return f32 ? ((const float*)p)[idx] : bf2f(((const u16*)p)[idx]);
}

typedef const __attribute__((address_space(1))) u32 gas_u32;
typedef __attribute__((address_space(3))) u32 las_u32;

// async 16B/lane global->LDS; LDS dest = wave-uniform base + lane*16 (m97).
__device__ __forceinline__ void stage16(const u16* g, u16* lbase, int lane) {
#if __has_builtin(__builtin_amdgcn_global_load_lds)
  (void)lane;
  __builtin_amdgcn_global_load_lds((gas_u32*)g, (las_u32*)lbase, 16, 0, 0);
#else
  *(u32x4*)(lbase + lane * 8) = *(const u32x4*)g;
#endif
}

// ------------------------------------------------------------ dtype probe ---
__global__ __launch_bounds__(256) void probe_k(const u32* __restrict__ xw, int* __restrict__ flag) {
  int tid = threadIdx.x, c = 0;
  for (int i = tid; i < 4096; i += 256) {
    u16 lo = (u16)(xw[i] & 0xffffu);
    float a = fabsf(bf2f(lo));
    if (lo == 0 || (a >= 1e-3f && a <= 32.f)) ++c;
  }
#pragma unroll
  for (int o = 32; o; o >>= 1) c += __shfl_xor(c, o, 64);
  __shared__ int r[4];
  if ((tid & 63) == 0) r[tid >> 6] = c;
  __syncthreads();
  if (tid == 0) flag[0] = (r[0] + r[1] + r[2] + r[3] >= 2048) ? 0 : 1;  // 1 = fp32
}

// ------------------------------------------------------------ diag fill -----
__global__ __launch_bounds__(256) void fill_k(u16* p, float v, int n) {
  int i = blockIdx.x * 256 + threadIdx.x;
  if (i < n) p[i] = f2bf(v);
}

// --------------------------------------------------------------- prep_k -----
// blocks [0,3597): ext->bf16 copies (x, ctx, Wconv) + midi pad-row zeroing
// blocks [3597,11181): transposes Wq/Wk/Wo (768^2), Wv (768x6656), ctx^T
__global__ __launch_bounds__(256) void prep_k(
    const void* __restrict__ x,   u16* __restrict__ xb,
    const void* __restrict__ ctx, u16* __restrict__ cbuf,
    const void* __restrict__ Wcv, u16* __restrict__ wcvb,
    u16* __restrict__ midi,
    const void* __restrict__ Wq, const void* __restrict__ Wk,
    const void* __restrict__ Wo, const void* __restrict__ Wv,
    u16* __restrict__ wqt, u16* __restrict__ wkt, u16* __restrict__ wot,
    u16* __restrict__ wvt, u16* __restrict__ ctxT,
    const int* __restrict__ dtf, int fknown)
{
  const int f = (fknown >= 0) ? fknown : dtf[0];
  int bid = blockIdx.x;
  __shared__ float s[32][33];
  if (bid < 3597) {
    // ---- convb4 ----
    const long n0_ = 1277952, n1_ = 789504, n2_ = 5111808, n3_ = 186368;
    long i = ((long)bid * 256 + threadIdx.x) * 8;
    const long t0 = n0_, t1 = t0 + n1_, t2 = t1 + n2_, t3 = t2 + n3_;
    if (i >= t3) return;
    if (i >= t2) {
      long e = i - t2;                 // zero 7 pad rows per midi z-block
      long z = e / 448, off = e - z * 448;
      u32x4 zz = {0u, 0u, 0u, 0u};
      *(u32x4*)(midi + z * 16896 + 16448 + off) = zz;
      return;
    }
    const void* in; u16* out;
    if (i < t0)      { in = x;    out = xb; }
    else if (i < t1) { in = ctx;  out = cbuf; i -= t0; }
    else             { in = Wcv;  out = wcvb; i -= t1; }
    if (f) {
      const float* ip = (const float*)in + i;
      f32x4 a = *(const f32x4*)ip, b = *(const f32x4*)(ip + 4);
      u32x4 q = { (u32)f2bf(a.x) | ((u32)f2bf(a.y) << 16),
                  (u32)f2bf(a.z) | ((u32)f2bf(a.w) << 16),
                  (u32)f2bf(b.x) | ((u32)f2bf(b.y) << 16),
                  (u32)f2bf(b.z) | ((u32)f2bf(b.w) << 16) };
      *(u32x4*)(out + i) = q;
    } else {
      *(u32x4*)(out + i) = *(const u32x4*)((const u16*)in + i);
    }
  } else {
    // ---- transM ----
    int t = bid - 3597;
    const void* in; u16* out;
    int inK, inN, ldo, outK, nx;
    long inBase = 0, outBase = 0;
    if (t < 1728) {                    // 3 x 768x768 weights: 576 tiles each
      int w = t / 576; t -= w * 576;
      in  = w == 0 ? Wq : w == 1 ? Wk : Wo;
      out = w == 0 ? wqt : w == 1 ? wkt : wot;
      inK = 768; inN = 768; ldo = 768; outK = 768; nx = 24;
    } else if (t < 6720) {             // Wv 768x6656: 208 n-tiles x 24 k-tiles
      t -= 1728;
      in = Wv; out = wvt;
      inK = 768; inN = 6656; ldo = 768; outK = 768; nx = 208;
    } else {                           // ctxT: 4 b x (24 n-tiles x 9 k-tiles)
      t -= 6720;
      int b = t / 216; t -= b * 216;
      in = ctx; out = ctxT;
      inK = 257; inN = 768; ldo = 264; outK = 264; nx = 24;
      inBase = (long)b * 257 * 768; outBase = (long)b * 768 * 264;
    }
    int n0 = (t % nx) * 32, k0 = (t / nx) * 32;
    int tx = threadIdx.x & 31, ty = threadIdx.x >> 5;  // 32 x 8
#pragma unroll
    for (int i = 0; i < 32; i += 8) {
      int k = k0 + ty + i, n = n0 + tx;
      float v = 0.f;
      if (k < inK && n < inN) v = gld(in, inBase + (long)k * inN + n, f);
      s[ty + i][tx] = v;
    }
    __syncthreads();
#pragma unroll
    for (int i = 0; i < 32; i += 8) {
      int n = n0 + ty + i, k = k0 + tx;
      if (n < inN && k < outK) out[outBase + (long)n * ldo + k] = f2bf(s[tx][ty + i]);
    }
  }
}

// ----------------------------------------------------------- gemm64128 ------
// C_bf16 = A[M,K] @ B[N,K]^T, tile 64(M) x 128(N), BK=32, 4 waves in 2x2
// (each 32x64, 2x4 MFMA acc). Same staging/accumulation order as the old
// 128^2 body -> bitwise-identical outputs. As = 64x32 (4KB), Bs = 128x32 (8KB).
__device__ __forceinline__ void gemm64128_body(
    u16* As, u16* Bs,
    const u16* __restrict__ A, const u16* __restrict__ B, u16* __restrict__ C,
    int M, int N, int K, int lda, int ldb, int ldc, int m0, int n0)
{
  const int tid = threadIdx.x, lane = tid & 63, wave = tid >> 6;
  const int wm = (wave >> 1) * 32, wn = (wave & 1) * 64;
  const int fm = lane & 15, fq = lane >> 4;
  const int srow = lane >> 2, selem = (lane & 3) * 8;

  int ra = m0 + wave * 16 + srow;      if (ra > M - 1) ra = M - 1;
  const int rb1 = n0 + wave * 16 + srow;
  const int rb2 = n0 + 64 + wave * 16 + srow;
  const u16* pa  = A + (long)ra * lda + selem;
  const u16* pb1 = B + (long)rb1 * ldb + selem;
  const u16* pb2 = B + (long)rb2 * ldb + selem;
  u16* la  = As + wave * 512;
  u16* lb1 = Bs + wave * 512;
  u16* lb2 = Bs + 2048 + wave * 512;

  f32x4 acc[2][4];
  const f32x4 zero4 = {0.f, 0.f, 0.f, 0.f};
#pragma unroll
  for (int a_ = 0; a_ < 2; ++a_)
#pragma unroll
    for (int b_ = 0; b_ < 4; ++b_) acc[a_][b_] = zero4;

  for (int k0 = 0; k0 < K; k0 += 32) {
    stage16(pa,  la,  lane);
    stage16(pb1, lb1, lane);
    stage16(pb2, lb2, lane);
    pa += 32; pb1 += 32; pb2 += 32;
    __syncthreads();
    bf16x8 fa[2], fb[4];
#pragma unroll
    for (int mt = 0; mt < 2; ++mt)
      fa[mt] = *(const bf16x8*)&As[(wm + mt * 16 + fm) * 32 + fq * 8];
#pragma unroll
    for (int nt = 0; nt < 4; ++nt)
      fb[nt] = *(const bf16x8*)&Bs[(wn + nt * 16 + fm) * 32 + fq * 8];
#pragma unroll
    for (int mt = 0; mt < 2; ++mt)
#pragma unroll
      for (int nt = 0; nt < 4; ++nt)
        acc[mt][nt] = __builtin_amdgcn_mfma_f32_16x16x32_bf16(fa[mt], fb[nt], acc[mt][nt], 0, 0, 0);
    __syncthreads();
  }
  // C/D layout: col=lane&15, row=(lane>>4)*4+reg (m89-verified)
#pragma unroll
  for (int mt = 0; mt < 2; ++mt)
#pragma unroll
    for (int nt = 0; nt < 4; ++nt)
#pragma unroll
      for (int rr = 0; rr < 4; ++rr) {
        int gm = m0 + wm + mt * 16 + fq * 4 + rr;
        int gn = n0 + wn + nt * 16 + fm;
        if (gm < M) C[(long)gm * ldc + gn] = f2bf(acc[mt][nt][rr]);
      }
}

// ------------------------------------------------- gemm64 body (all-bf16) ---
// 64x64 tile, BK=32, 2x2 acc/wave. Pointers pre-offset by caller (batch z).
// If Ylds != nullptr: fp32 tile -> LDS (caller epilogue); Ylds may alias As/Bs.
#define LDS_S 40

__device__ __forceinline__ void gemm64_body(
    u16* As, u16* Bs,
    const u16* __restrict__ A16, const u16* __restrict__ B16,
    float* Cf, u16* Cb, float* Ylds,
    int M, int N, int K, int lda, int ldb, int ldc,
    int btrans, float alpha, int m0, int n0)
{
  const int tid = threadIdx.x;
  const int lane = tid & 63, wave = tid >> 6;
  const int wm = (wave >> 1) * 32, wn = (wave & 1) * 32;
  const int fm = lane & 15, fq = lane >> 4;
  const int ar = tid >> 2, ak = (tid & 3) * 8;
  const int bk = tid >> 3, bn = (tid & 7) * 8;

  f32x4 acc[2][2];
  const f32x4 zero4 = {0.f, 0.f, 0.f, 0.f};
#pragma unroll
  for (int a_ = 0; a_ < 2; ++a_)
#pragma unroll
    for (int b_ = 0; b_ < 2; ++b_) acc[a_][b_] = zero4;

  for (int k0 = 0; k0 < K; k0 += 32) {
    {
      int gm = m0 + ar, gk = k0 + ak;
      long idx = (long)gm * lda + gk;
      if (gm < M && gk + 8 <= K) {
        *(u32x4*)&As[ar * LDS_S + ak] = *(const u32x4*)(A16 + idx);
      } else {
#pragma unroll
        for (int e = 0; e < 8; ++e)
          As[ar * LDS_S + ak + e] = (gm < M && gk + e < K) ? A16[idx + e] : (u16)0;
      }
    }
    if (btrans) {
      int gn = n0 + ar, gk = k0 + ak;
      long idx = (long)gn * ldb + gk;
      if (gn < N && gk + 8 <= K) {
        *(u32x4*)&Bs[ar * LDS_S + ak] = *(const u32x4*)(B16 + idx);
      } else {
#pragma unroll
        for (int e = 0; e < 8; ++e)
          Bs[ar * LDS_S + ak + e] = (gn < N && gk + e < K) ? B16[idx + e] : (u16)0;
      }
    } else {
      int gk = k0 + bk;
      long idx = (long)gk * ldb + n0 + bn;
      u16 tmp[8];
      if (gk < K) {
        u32x4 v = *(const u32x4*)(B16 + idx);
        tmp[0] = (u16)(v.x & 0xffff); tmp[1] = (u16)(v.x >> 16);
        tmp[2] = (u16)(v.y & 0xffff); tmp[3] = (u16)(v.y >> 16);
        tmp[4] = (u16)(v.z & 0xffff); tmp[5] = (u16)(v.z >> 16);
        tmp[6] = (u16)(v.w & 0xffff); tmp[7] = (u16)(v.w >> 16);
      } else {
#pragma unroll
        for (int e = 0; e < 8; ++e) tmp[e] = 0;
      }
      int rot = tid & 7;  // spread LDS bank writes
#pragma unroll
      for (int e = 0; e < 8; ++e) {
        int ee = (e + rot) & 7;
        Bs[(bn + ee) * LDS_S + bk] = tmp[ee];
      }
    }
    __syncthreads();
    {
      bf16x8 fa[2], fb[2];
      fa[0] = *(const bf16x8*)&As[(wm +      fm) * LDS_S + fq * 8];
      fa[1] = *(const bf16x8*)&As[(wm + 16 + fm) * LDS_S + fq * 8];
      fb[0] = *(const bf16x8*)&Bs[(wn +      fm) * LDS_S + fq * 8];
      fb[1] = *(const bf16x8*)&Bs[(wn + 16 + fm) * LDS_S + fq * 8];
#pragma unroll
      for (int mt = 0; mt < 2; ++mt)
#pragma unroll
        for (int nt = 0; nt < 2; ++nt)
          acc[mt][nt] = __builtin_amdgcn_mfma_f32_16x16x32_bf16(fa[mt], fb[nt], acc[mt][nt], 0, 0, 0);
    }
    __syncthreads();
  }
  if (Ylds) {
    // all LDS reads complete past the final barrier; safe to overwrite As/Bs
#pragma unroll
    for (int mt = 0; mt < 2; ++mt)
#pragma unroll
      for (int nt = 0; nt < 2; ++nt)
#pragma unroll
        for (int rr = 0; rr < 4; ++rr)
          Ylds[(wm + mt * 16 + fq * 4 + rr) * 64 + (wn + nt * 16 + fm)] = acc[mt][nt][rr];
  } else {
#pragma unroll
    for (int mt = 0; mt < 2; ++mt)
#pragma unroll
      for (int nt = 0; nt < 2; ++nt)
#pragma unroll
        for (int rr = 0; rr < 4; ++rr) {
          int gm = m0 + wm + mt * 16 + fq * 4 + rr;
          int gn = n0 + wn + nt * 16 + fm;
          if (gm < M && gn < N) {
            float v = alpha * acc[mt][nt][rr];
            if (Cb) Cb[(long)gm * ldc + gn] = f2bf(v);
            else    Cf[(long)gm * ldc + gn] = v;
          }
        }
  }
}

// ---------- mg4: q/k/mid gemm64128s + Gram gemm + wbar (bf16), LDS union ----
__global__ __launch_bounds__(256) void mg4_k(
    const u16* __restrict__ xb, const u16* __restrict__ wqt, u16* __restrict__ qbf,
    const u16* __restrict__ cbuf, const u16* __restrict__ wkt, u16* __restrict__ kbf,
    const u16* __restrict__ wvt, u16* __restrict__ midbf,
    const u16* __restrict__ wcvb, u16* __restrict__ Gb, float* __restrict__ wbar)
{
  __shared__ __attribute__((aligned(16))) char smem[16384];
  int bid = blockIdx.x;
  if (bid < 1142) {
    const u16 *A, *B; u16* C; int M, N, lid, mx;
    if (bid < 156)      { A = xb;   B = wqt; C = qbf;   M = 1664; N = 768;  lid = bid;       mx = 26; }
    else if (bid < 258) { A = cbuf; B = wkt; C = kbf;   M = 1028; N = 768;  lid = bid - 156; mx = 17; }
    else                { A = cbuf; B = wvt; C = midbf; M = 1028; N = 6656; lid = bid - 258; mx = 17; }
    int m0 = (lid % mx) * 64, n0 = (lid / mx) * 128;
    gemm64128_body((u16*)smem, (u16*)(smem + 4096), A, B, C, M, N, 768, 768, 768, N, m0, n0);
  } else if (bid < 1246) {
    int z = bid - 1142;   // 0..103: M[g] = Wconv_b[g] @ Wconv_b[g]^T / 768
    gemm64_body((u16*)smem, (u16*)(smem + 5120),
                wcvb + (long)z * 49152, wcvb + (long)z * 49152,
                nullptr, Gb + (long)z * 4096, nullptr,
                64, 64, 768, 768, 768, 64, 1, 1.f / 768.f, 0, 0);
  } else {
    // wbar: row means of bf16 Wconv copy, r = g*64+l over 768 cols
    int r = (bid - 1246) * 4 + (threadIdx.x >> 6);
    int lane = threadIdx.x & 63;
    const u16* prow = wcvb + (long)r * 768;
    float sm = 0.f;
    for (int c = lane; c < 768; c += 64) sm += bf2f(prow[c]);
#pragma unroll
    for (int o = 32; o; o >>= 1) sm += __shfl_xor(sm, o, 64);
    if (lane == 0) wbar[r] = sm * (1.f / 768.f);
  }
}

// ------------------------------ final: out_pre @ Wo^T (64x128 tiles) --------
__global__ __launch_bounds__(256) void gemmF_k(
    const u16* __restrict__ opbf, const u16* __restrict__ wot, u16* __restrict__ qbf)
{
  __shared__ __attribute__((aligned(16))) char smem[12288];
  int lid = blockIdx.x;   // 156 = 26 m-tiles x 6 n-tiles, m-fastest
  gemm64128_body((u16*)smem, (u16*)(smem + 4096), opbf, wot, qbf,
                 1664, 768, 768, 768, 768, 768, (lid % 26) * 64, (lid / 26) * 128);
}

// --------------------- ysim: Y-gemm with fused stats epilogue + sim-gemm ----
__global__ __launch_bounds__(256) void ysim_k(
    const u16* __restrict__ midbf, const u16* __restrict__ Gb,
    const float* __restrict__ wbar, u16* __restrict__ midi, float* __restrict__ pim,
    const u16* __restrict__ qbf, const u16* __restrict__ kbf, float* __restrict__ simf)
{
  __shared__ __attribute__((aligned(16))) char smem[16384];
  u16* As = (u16*)smem;
  u16* Bs = (u16*)(smem + 8192);
  int bid = blockIdx.x;
  if (bid < 1768) {
    // Y = mid_g[1028x64] @ M[g]^T -> fp32 tile in LDS, then stats epilogue
    int g = bid / 17, bx = bid % 17;
    int m0 = bx * 64;
    float* Ylds = (float*)smem;   // aliases As/Bs (dead after final barrier)
    gemm64_body(As, Bs, midbf + (long)g * 64, Gb + (long)g * 4096,
                nullptr, nullptr, Ylds,
                1028, 64, 64, 6656, 64, 64, 1, 1.f, m0, 0);
    __syncthreads();
    int tid = threadIdx.x, lane = tid & 63, wave = tid >> 6;
#pragma unroll
    for (int rr = 0; rr < 16; ++rr) {
      int r = wave * 16 + rr;          // local row
      int gr = m0 + r;                 // global row (wave-uniform)
      if (gr < 1028) {
        float m  = bf2f(midbf[(long)gr * 6656 + g * 64 + lane]);
        float y  = Ylds[r * 64 + lane];
        float wb = wbar[g * 64 + lane];
        float mup = m * wb, q2p = m * y;
#pragma unroll
        for (int o = 32; o; o >>= 1) { mup += __shfl_xor(mup, o, 64); q2p += __shfl_xor(q2p, o, 64); }
        float var = q2p - mup * mup;
        float inv = rsqrtf(fmaxf(var, 0.f) + 1e-5f);
        int b = gr / 257, j = gr - b * 257;
        long zidx = (long)b * 104 + g;
        midi[(zidx * 264 + j) * 64 + lane] = f2bf(inv * m);
        if (lane == 0) pim[zidx * 257 + j] = inv * mup;
      }
    }
  } else {
    // sim = scale^2 * q @ k^T;  z = b*6+h
    int lid = bid - 1768; int z = lid / 35, r = lid % 35, bx = r % 7, by = r / 7;
    const u16* A = qbf + (long)(z / 6) * 319488 + (long)(z % 6) * 128;
    const u16* B = kbf + (long)(z / 6) * 197376 + (long)(z % 6) * 128;
    float* Cf = simf + (long)z * 106912;
    gemm64_body(As, Bs, A, B, Cf, nullptr, nullptr,
                416, 257, 128, 768, 768, 257, 1, 0.08838834764831845f, bx * 64, by * 64);
  }
}

// --------------------------------------------------- ct: c-gemm + T-gemm ----
__global__ __launch_bounds__(256) void ct_k(
    const u16* __restrict__ Abf, const u16* __restrict__ ctxT, float* __restrict__ c_buf,
    const u16* __restrict__ A2bf, const u16* __restrict__ midi, u16* __restrict__ Tb16)
{
  __shared__ __attribute__((aligned(16))) u16 As[64 * LDS_S];
  __shared__ __attribute__((aligned(16))) u16 Bs[64 * LDS_S];
  int bid = blockIdx.x;
  if (bid < 336) {
    // c = A @ ctx_head (btrans via ctx^T, K=264); z = b*6+h
    int z = bid / 14, r = bid % 14, bx = r % 7, by = r / 7;
    const u16* A = Abf + (long)z * 109824;
    const u16* B = ctxT + (long)(z / 6) * 202752 + (long)(z % 6) * 33792;
    float* Cf = c_buf + (long)z * 53248;
    gemm64_body(As, Bs, A, B, Cf, nullptr, nullptr,
                416, 128, 264, 264, 264, 128, 1, 1.f, bx * 64, by * 64);
  } else {
    // T = A2 @ midi (non-trans, K=264, 264-row-padded midi); z = b*104+g
    int z = bid - 336;
    const u16* A = A2bf + (long)z * 6336;
    const u16* B = midi + (long)z * 16896;
    u16* Cb = Tb16 + (long)z * 1536;
    gemm64_body(As, Bs, A, B, nullptr, Cb, nullptr,
                24, 64, 264, 264, 64, 64, 0, 1.f, 0, 0);
  }
}

// ------------------------------------------------------------- row LN -------
__device__ __forceinline__ void ln_row(
    const u16* __restrict__ ip, const void* __restrict__ g, const void* __restrict__ b,
    u16* __restrict__ ob, float* __restrict__ of, int N, int f)
{
  int tid = threadIdx.x, lane = tid & 63, wave = tid >> 6;
  const int nv = N >> 3;
  float s1 = 0.f, s2 = 0.f;
  for (int c8 = tid; c8 < nv; c8 += 256) {
    u32x4 v = *(const u32x4*)(ip + c8 * 8);
    float e0 = bf2f((u16)(v.x & 0xffff)), e1 = bf2f((u16)(v.x >> 16));
    float e2 = bf2f((u16)(v.y & 0xffff)), e3 = bf2f((u16)(v.y >> 16));
    float e4 = bf2f((u16)(v.z & 0xffff)), e5 = bf2f((u16)(v.z >> 16));
    float e6 = bf2f((u16)(v.w & 0xffff)), e7 = bf2f((u16)(v.w >> 16));
    s1 += ((e0 + e1) + (e2 + e3)) + ((e4 + e5) + (e6 + e7));
    s2 += ((e0*e0 + e1*e1) + (e2*e2 + e3*e3)) + ((e4*e4 + e5*e5) + (e6*e6 + e7*e7));
  }
#pragma unroll
  for (int o = 32; o; o >>= 1) { s1 += __shfl_xor(s1, o, 64); s2 += __shfl_xor(s2, o, 64); }
  __shared__ float red[8];
  if (lane == 0) { red[wave] = s1; red[4 + wave] = s2; }
  __syncthreads();
  s1 = red[0] + red[1] + red[2] + red[3];
  s2 = red[4] + red[5] + red[6] + red[7];
  float mean = s1 / N;
  float var = s2 / N - mean * mean;
  float rstd = rsqrtf(fmaxf(var, 0.f) + 1e-5f);
  for (int c8 = tid; c8 < nv; c8 += 256) {
    int c = c8 * 8;
    u32x4 v = *(const u32x4*)(ip + c);
    float e[8];
    e[0] = bf2f((u16)(v.x & 0xffff)); e[1] = bf2f((u16)(v.x >> 16));
    e[2] = bf2f((u16)(v.y & 0xffff)); e[3] = bf2f((u16)(v.y >> 16));
    e[4] = bf2f((u16)(v.z & 0xffff)); e[5] = bf2f((u16)(v.z >> 16));
    e[6] = bf2f((u16)(v.w & 0xffff)); e[7] = bf2f((u16)(v.w >> 16));
    float gg[8], bb[8];
    if (f) {
      const float* gp = (const float*)g + c; const float* bp = (const float*)b + c;
      f32x4 g0 = *(const f32x4*)gp, g1 = *(const f32x4*)(gp + 4);
      f32x4 b0 = *(const f32x4*)bp, b1 = *(const f32x4*)(bp + 4);
      gg[0]=g0.x; gg[1]=g0.y; gg[2]=g0.z; gg[3]=g0.w; gg[4]=g1.x; gg[5]=g1.y; gg[6]=g1.z; gg[7]=g1.w;
      bb[0]=b0.x; bb[1]=b0.y; bb[2]=b0.z; bb[3]=b0.w; bb[4]=b1.x; bb[5]=b1.y; bb[6]=b1.z; bb[7]=b1.w;
    } else {
      u32x4 gv = *(const u32x4*)((const u16*)g + c);
      u32x4 bv = *(const u32x4*)((const u16*)b + c);
      gg[0]=bf2f((u16)(gv.x&0xffff)); gg[1]=bf2f((u16)(gv.x>>16));
      gg[2]=bf2f((u16)(gv.y&0xffff)); gg[3]=bf2f((u16)(gv.y>>16));
      gg[4]=bf2f((u16)(gv.z&0xffff)); gg[5]=bf2f((u16)(gv.z>>16));
      gg[6]=bf2f((u16)(gv.w&0xffff)); gg[7]=bf2f((u16)(gv.w>>16));
      bb[0]=bf2f((u16)(bv.x&0xffff)); bb[1]=bf2f((u16)(bv.x>>16));
      bb[2]=bf2f((u16)(bv.y&0xffff)); bb[3]=bf2f((u16)(bv.y>>16));
      bb[4]=bf2f((u16)(bv.z&0xffff)); bb[5]=bf2f((u16)(bv.z>>16));
      bb[6]=bf2f((u16)(bv.w&0xffff)); bb[7]=bf2f((u16)(bv.w>>16));
    }
    float o_[8];
#pragma unroll
    for (int e2i = 0; e2i < 8; ++e2i) o_[e2i] = (e[e2i] - mean) * rstd * gg[e2i] + bb[e2i];
    if (of) {
      f32x4 o0 = {o_[0], o_[1], o_[2], o_[3]}, o1 = {o_[4], o_[5], o_[6], o_[7]};
      *(f32x4*)(of + c) = o0; *(f32x4*)(of + c + 4) = o1;
    } else {
      u32x4 q = { (u32)f2bf(o_[0]) | ((u32)f2bf(o_[1]) << 16),
                  (u32)f2bf(o_[2]) | ((u32)f2bf(o_[3]) << 16),
                  (u32)f2bf(o_[4]) | ((u32)f2bf(o_[5]) << 16),
                  (u32)f2bf(o_[6]) | ((u32)f2bf(o_[7]) << 16) };
      *(u32x4*)(ob + c) = q;
    }
  }
}

__global__ __launch_bounds__(256) void ln_rows(
    const u16* __restrict__ in, const void* __restrict__ g, const void* __restrict__ b,
    void* __restrict__ out, int N, const int* __restrict__ dtf, int isfinal, int fknown)
{
  const int f = (fknown >= 0) ? fknown : dtf[0];
  long row = blockIdx.x;
  const u16* ip = in + row * N;
  float* of = (isfinal && f) ? (float*)out + row * N : nullptr;
  u16*   ob = of ? nullptr : (u16*)out + row * N;
  ln_row(ip, g, b, ob, of, N, f);
}

// merged LN for q (1664x768), k (1028x768), mid (1028x6656)
__global__ __launch_bounds__(256) void mln3_k(
    u16* __restrict__ qb, const void* __restrict__ gq, const void* __restrict__ bq,
    u16* __restrict__ kb, const void* __restrict__ gk, const void* __restrict__ bk,
    u16* __restrict__ mb, const void* __restrict__ gv, const void* __restrict__ bv,
    const int* __restrict__ dtf, int fknown)
{
  const int f = (fknown >= 0) ? fknown : dtf[0];
  int row = blockIdx.x;
  u16* ip; const void *g, *b; int N;
  if (row < 1664)      { ip = qb + (long)row * 768; g = gq; b = bq; N = 768; }
  else if (row < 2692) { ip = kb + (long)(row - 1664) * 768; g = gk; b = bk; N = 768; }
  else                 { ip = mb + (long)(row - 2692) * 6656; g = gv; b = bv; N = 6656; }
  ln_row(ip, g, b, ip, nullptr, N, f);
}

// ------------------------------------------------------------- softmax ------
__global__ __launch_bounds__(256) void softmax_k(
    const float* __restrict__ simf, const float* __restrict__ pim,
    u16* __restrict__ Abf, u16* __restrict__ A2bf, float* __restrict__ s_sh)
{
  int bh = blockIdx.x;
  int b = bh / 6, h = bh - b * 6;
  int tid = threadIdx.x, lane = tid & 63, wave = tid >> 6;
  int i = blockIdx.y * 4 + wave;
  int g = i % 104, rq = i / 104;
  const float* sp_ = simf + ((long)bh * 416 + i) * 257;
  float s[5];
#pragma unroll
  for (int jc = 0; jc < 5; ++jc) {
    int j = jc * 64 + lane;
    s[jc] = (j < 257) ? sp_[j] : -1e30f;
  }
  float mx = -1e30f;
#pragma unroll
  for (int jc = 0; jc < 5; ++jc) mx = fmaxf(mx, s[jc]);
#pragma unroll
  for (int o = 32; o; o >>= 1) mx = fmaxf(mx, __shfl_xor(mx, o, 64));
  float p[5], sum = 0.f, sp = 0.f;
  long pimb = ((long)b * 104 + g) * 257;
#pragma unroll
  for (int jc = 0; jc < 5; ++jc) {
    int j = jc * 64 + lane;
    float pv = 0.f;
    if (j < 257) { pv = __expf(s[jc] - mx); sp = fmaf(pv, pim[pimb + j], sp); }
    p[jc] = pv; sum += pv;
  }
#pragma unroll
  for (int o = 32; o; o >>= 1) { sum += __shfl_xor(sum, o, 64); sp += __shfl_xor(sp, o, 64); }
  float rs = 1.f / sum;
  long arow  = ((long)bh * 416 + i) * 264;
  long a2row = (((long)b * 104 + g) * 24 + h * 4 + rq) * 264;
#pragma unroll
  for (int jc = 0; jc < 5; ++jc) {
    int j = jc * 64 + lane;
    if (j < 257) { u16 pb = f2bf(p[jc] * rs); Abf[arow + j] = pb; A2bf[a2row + j] = pb; }
    else if (j < 264) { Abf[arow + j] = 0; A2bf[a2row + j] = 0; }
  }
  if (lane == 0) s_sh[(long)bh * 416 + i] = sp * rs;
}

// -------------------------------------------------- fused O-gemm + combine --
__global__ __launch_bounds__(256) void oc_k(
    const u16* __restrict__ T, const u16* __restrict__ Wb,
    const float* __restrict__ s_sh, const float* __restrict__ c_buf,
    const void* __restrict__ gv2, const void* __restrict__ bv2,
    u16* __restrict__ opbf, const int* __restrict__ dtf, int fknown)
{
  const int f = (fknown >= 0) ? fknown : dtf[0];
  int z = blockIdx.x;                 // b*104+g
  int b = z / 104, g = z - b * 104;
  int tid = threadIdx.x;
  __shared__ float Ts[24][64];        // 6 KB
  const u16* tp = T + (long)z * 1536;
  for (int idx = tid; idx < 1536; idx += 256) Ts[idx >> 6][idx & 63] = bf2f(tp[idx]);
  __syncthreads();
  const int dh = tid & 127;
  const int hbase = (tid >> 7) * 3;   // threads 0..127 -> h 0..2, 128..255 -> h 3..5
  const u16* wg = Wb + (long)g * 49152;
#pragma unroll
  for (int hh = 0; hh < 3; ++hh) {
    int h = hbase + hh;
    int d = h * 128 + dh;
    const u16* wp = wg + d;
    float a0 = 0.f, a1 = 0.f, a2 = 0.f, a3 = 0.f;
#pragma unroll 16
    for (int k = 0; k < 64; ++k) {
      float w = bf2f(wp[(long)k * 768]);
      a0 = fmaf(Ts[h * 4 + 0][k], w, a0);
      a1 = fmaf(Ts[h * 4 + 1][k], w, a1);
      a2 = fmaf(Ts[h * 4 + 2][k], w, a2);
      a3 = fmaf(Ts[h * 4 + 3][k], w, a3);
    }
    float acc[4] = {a0, a1, a2, a3};
    float gvd = gld(gv2, d, f), bvd = gld(bv2, d, f);
#pragma unroll
    for (int rq = 0; rq < 4; ++rq) {
      int i = rq * 104 + g;
      float ssh = s_sh[((long)b * 6 + h) * 416 + i];
      float val = gvd * (acc[rq] - ssh) + bvd
                + c_buf[(((long)b * 6 + h) * 416 + i) * 128 + dh];
      opbf[((long)b * 416 + i) * 768 + d] = f2bf(val);
    }
  }
}

// ---------------------------------------------------------------- host ------
extern "C" void kernel_launch(void* const* d_in, const int* in_sizes, int n_in,
                              void* d_out, int out_size, void* d_ws, size_t ws_size,
                              hipStream_t stream)
{
  const void* x   = d_in[0];
  const void* ctx = d_in[1];
  const void* Wq  = d_in[2];
  const void* gq  = d_in[3];
  const void* bq  = d_in[4];
  const void* Wk  = d_in[5];
  const void* gk  = d_in[6];
  const void* bk  = d_in[7];
  const void* Wv  = d_in[8];
  const void* gv1 = d_in[9];
  const void* bv1 = d_in[10];
  const void* Wcv = d_in[11];
  const void* gv2 = d_in[12];
  const void* bv2 = d_in[13];
  const void* Wo  = d_in[14];
  const void* go  = d_in[15];
  const void* bo  = d_in[16];

  // -------- workspace layout --------
  const size_t SZ_FLAG = 256;
  const size_t SZ_QBF  = 2555904;
  const size_t SZ_KBF  = 1579008;
  const size_t SZ_MID  = 13684736;
  const size_t SZ_MM   = 1703936;
  const size_t SZ_WB   = 26624;
  const size_t SZ_MIDI = 14057472;   // 416 * 264 * 64 bf16 (264-row padded)
  const size_t SZ_PIM  = 427648;
  const size_t SZ_ABF  = 5271552;
  const size_t SZ_A2   = 5271552;
  const size_t SZ_SSH  = 39936;
  const size_t SZ_CB   = 1579008;
  const size_t SZ_WCVB = 10223616;   // 104*64*768 bf16
  const size_t SZ_WT   = 1179648;    // 768*768 bf16 (x3: WqT, WkT, WoT)
  const size_t SZ_WVT  = 10223616;   // 6656*768 bf16
  const size_t SZ_CTXT = 1622016;    // 4*768*264 bf16 (ctx^T, zero-padded cols)
  const size_t SZ_SIMF = 10263552;   // 24*416*257 fp32
  const size_t REQUIRED = SZ_FLAG + SZ_QBF + SZ_KBF + SZ_MID + SZ_MM + SZ_WB +
                          SZ_MIDI + SZ_PIM + SZ_ABF + SZ_A2 + SZ_SSH + SZ_CB +
                          SZ_WCVB + 3 * SZ_WT + SZ_WVT + SZ_CTXT + SZ_SIMF;  // 82,069,376

  if (ws_size < REQUIRED) {
    fill_k<<<(out_size + 255) / 256, 256, 0, stream>>>((u16*)d_out, (float)(ws_size >> 20), out_size);
    return;
  }

  char* p = (char*)d_ws;
  int*   dtf   = (int*)  p;                 p += SZ_FLAG;
  u16*   qbf   = (u16*)  p;                 p += SZ_QBF;
  u16*   kbf   = (u16*)  p;                 p += SZ_KBF;
  char*  midrg = p;                         p += SZ_MID;
  char*  mmrg  = p;                         p += SZ_MM;
  float* wbar  = (float*)p;                 p += SZ_WB;
  u16*   midi  = (u16*)  p;                 p += SZ_MIDI;
  float* pim   = (float*)p;                 p += SZ_PIM;
  char*  abfrg = p;                         p += SZ_ABF;
  u16*   A2bf  = (u16*)  p;                 p += SZ_A2;
  float* s_sh  = (float*)p;                 p += SZ_SSH;
  u16*   cb    = (u16*)  p;                 p += SZ_CB;
  u16*   wcvb  = (u16*)  p;                 p += SZ_WCVB;
  u16*   wqt2  = (u16*)  p;                 p += SZ_WT;
  u16*   wkt2  = (u16*)  p;                 p += SZ_WT;
  u16*   wot2  = (u16*)  p;                 p += SZ_WT;
  u16*   wvt   = (u16*)  p;                 p += SZ_WVT;
  u16*   ctxT  = (u16*)  p;                 p += SZ_CTXT;
  float* simf  = (float*)p;                 p += SZ_SIMF;

  u16*   midbf = (u16*)midrg;
  float* c_buf = (float*)midrg;             // midbf dead after ysim stats
  u16*   Tb16  = (u16*)(midrg + 5111808);   // right after c_buf's 5,111,808 B
  u16*   Gb    = (u16*)mmrg;
  u16*   xb    = (u16*)abfrg;
  u16*   Abf   = (u16*)abfrg;
  u16*   opbf  = (u16*)abfrg;               // Abf dead after ct_k

  // host-side dtype: in_sizes[0] in bytes distinguishes fp32 (5,111,808) from
  // bf16 (2,555,904); anything else (e.g. element count) -> probe fallback.
  int fknown = -1;
  if (in_sizes && n_in > 0) {
    if (in_sizes[0] == 5111808)      fknown = 1;
    else if (in_sizes[0] == 2555904) fknown = 0;
  }
  if (fknown < 0) probe_k<<<1, 256, 0, stream>>>((const u32*)x, dtf);

  // prep: copies + midi pad zero (3597) | transposes (7584)
  prep_k<<<11181, 256, 0, stream>>>(x, xb, ctx, cb, Wcv, wcvb, midi,
                                    Wq, Wk, Wo, Wv, wqt2, wkt2, wot2, wvt, ctxT,
                                    dtf, fknown);

  // q/k/mid gemm64128s (1142) + Gram (104) + wbar (1664, bf16 wcvb)
  mg4_k<<<2910, 256, 0, stream>>>(xb, wqt2, qbf, cb, wkt2, kbf, wvt, midbf,
                                  wcvb, Gb, wbar);

  // q/k/mid LNs
  mln3_k<<<3720, 256, 0, stream>>>(qbf, gq, bq, kbf, gk, bk, midbf, gv1, bv1,
                                   dtf, fknown);

  // Y = mid_g @ M[g] with fused stats epilogue (1768) + sim (840)
  ysim_k<<<2608, 256, 0, stream>>>(midbf, Gb, wbar, midi, pim, qbf, kbf, simf);

  softmax_k<<<dim3(24, 104), 256, 0, stream>>>(simf, pim, Abf, A2bf, s_sh);

  // c = A @ ctx_head (336) + T = A2 @ midi (416)
  ct_k<<<752, 256, 0, stream>>>(Abf, ctxT, c_buf, A2bf, midi, Tb16);

  // fused O-gemm + combine
  oc_k<<<416, 256, 0, stream>>>(Tb16, wcvb, s_sh, c_buf, gv2, bv2, opbf, dtf, fknown);

  // out = LN(out_pre @ Wo): 64x128 tiles (156 blocks; was 78 grid-starved)
  gemmF_k<<<156, 256, 0, stream>>>(opbf, wot2, qbf);
  ln_rows<<<1664, 256, 0, stream>>>(qbf, go, bo, d_out, 768, dtf, 1, fknown);
}

// Round 12
// 261.279 us; speedup vs baseline: 3.0910x; 1.0028x over previous
//
#include <hip/hip_runtime.h>

// SubjBasisGenerator fused pipeline. B=4 NQ=416 NC=257 D=768 H=6 DH=128 G=104 R=4 LORA=64
// R22: T1 XCD-chunked bijective block swizzle in mg4's GEMM range + gemmF.
//      R21 counters: mg4 FETCH 73MB vs ~17MB unique operands (TCC = per-XCD L2
//      fills) — all 8 XCDs re-fill shared panels from L3; K-loop barrier waits
//      on L3 latency. Chunked remap (m204 bijective: 1142=8x142+6) gives each
//      XCD a contiguous tile run -> per-XCD L2 set ~3MB, resident. Same tiles,
//      same math; mapping only.
// R21: gemm64128 retile (64x128) for q/k/mid+final: occupancy 25->44%, 273->262.
// R20: wbar in mg4 (bf16); host-side dtype from in_sizes[0] (probe fallback).
//      Lesson: phases are latency/TLP-bound; wave count is the currency.
// R16: stats2 fused into Y-gemm epilogue (fp32 Y in LDS, yfull deleted).
// R14: dispatch 16->11. R13/R12: merged q/k/mid gemms, merged LNs/transposes,
//      ctx^T btrans fast path, K padded 257->264. R11: oc_k fusion, Wconv bf16.
//
// Algebra: the grouped-conv+LN v-path decomposes exactly:
//   sum_j A_j v_j = gv2*( (sum_j A_j inv_j mid_j)@Wconv[g] - sum_j A_j inv_j mu_j )
//                   + bv2 + (A @ ctx)
//   q2[b,g,j] = mid^T M[g] mid = mid . (M[g] @ mid),  M[g] = Wconv[g]Wconv[g]^T/768

typedef unsigned short u16;
typedef unsigned int   u32;
typedef __attribute__((ext_vector_type(4))) float f32x4;
typedef __attribute__((ext_vector_type(4))) u32   u32x4;
typedef __attribute__((ext_vector_type(8))) short bf16x8;

__device__ __forceinline__ float bf2f(u16 v) { return __uint_as_float(((u32)v) << 16); }
__device__ __forceinline__ u16 f2bf(float f) {
  u32 u = __float_as_uint(f);
  u32 r = u + 0x7fffu + ((u >> 16) & 1u);  // RNE
  return (u16)(r >> 16);
}
__device__ __forceinline__ float gld(const void* p, long idx, int f32) {
  return f32 ? ((const float*)p)[idx] : bf2f(((const u16*)p)[idx]);
}

typedef const __attribute__((address_space(1))) u32 gas_u32;
typedef __attribute__((address_space(3))) u32 las_u32;

// async 16B/lane global->LDS; LDS dest = wave-uniform base + lane*16 (m97).
__device__ __forceinline__ void stage16(const u16* g, u16* lbase, int lane) {
#if __has_builtin(__builtin_amdgcn_global_load_lds)
  (void)lane;
  __builtin_amdgcn_global_load_lds((gas_u32*)g, (las_u32*)lbase, 16, 0, 0);
#else
  *(u32x4*)(lbase + lane * 8) = *(const u32x4*)g;
#endif
}

// ------------------------------------------------------------ dtype probe ---
__global__ __launch_bounds__(256) void probe_k(const u32* __restrict__ xw, int* __restrict__ flag) {
  int tid = threadIdx.x, c = 0;
  for (int i = tid; i < 4096; i += 256) {
    u16 lo = (u16)(xw[i] & 0xffffu);
    float a = fabsf(bf2f(lo));
    if (lo == 0 || (a >= 1e-3f && a <= 32.f)) ++c;
  }
#pragma unroll
  for (int o = 32; o; o >>= 1) c += __shfl_xor(c, o, 64);
  __shared__ int r[4];
  if ((tid & 63) == 0) r[tid >> 6] = c;
  __syncthreads();
  if (tid == 0) flag[0] = (r[0] + r[1] + r[2] + r[3] >= 2048) ? 0 : 1;  // 1 = fp32
}

// ------------------------------------------------------------ diag fill -----
__global__ __launch_bounds__(256) void fill_k(u16* p, float v, int n) {
  int i = blockIdx.x * 256 + threadIdx.x;
  if (i < n) p[i] = f2bf(v);
}

// --------------------------------------------------------------- prep_k -----
// blocks [0,3597): ext->bf16 copies (x, ctx, Wconv) + midi pad-row zeroing
// blocks [3597,11181): transposes Wq/Wk/Wo (768^2), Wv (768x6656), ctx^T
__global__ __launch_bounds__(256) void prep_k(
    const void* __restrict__ x,   u16* __restrict__ xb,
    const void* __restrict__ ctx, u16* __restrict__ cbuf,
    const void* __restrict__ Wcv, u16* __restrict__ wcvb,
    u16* __restrict__ midi,
    const void* __restrict__ Wq, const void* __restrict__ Wk,
    const void* __restrict__ Wo, const void* __restrict__ Wv,
    u16* __restrict__ wqt, u16* __restrict__ wkt, u16* __restrict__ wot,
    u16* __restrict__ wvt, u16* __restrict__ ctxT,
    const int* __restrict__ dtf, int fknown)
{
  const int f = (fknown >= 0) ? fknown : dtf[0];
  int bid = blockIdx.x;
  __shared__ float s[32][33];
  if (bid < 3597) {
    // ---- convb4 ----
    const long n0_ = 1277952, n1_ = 789504, n2_ = 5111808, n3_ = 186368;
    long i = ((long)bid * 256 + threadIdx.x) * 8;
    const long t0 = n0_, t1 = t0 + n1_, t2 = t1 + n2_, t3 = t2 + n3_;
    if (i >= t3) return;
    if (i >= t2) {
      long e = i - t2;                 // zero 7 pad rows per midi z-block
      long z = e / 448, off = e - z * 448;
      u32x4 zz = {0u, 0u, 0u, 0u};
      *(u32x4*)(midi + z * 16896 + 16448 + off) = zz;
      return;
    }
    const void* in; u16* out;
    if (i < t0)      { in = x;    out = xb; }
    else if (i < t1) { in = ctx;  out = cbuf; i -= t0; }
    else             { in = Wcv;  out = wcvb; i -= t1; }
    if (f) {
      const float* ip = (const float*)in + i;
      f32x4 a = *(const f32x4*)ip, b = *(const f32x4*)(ip + 4);
      u32x4 q = { (u32)f2bf(a.x) | ((u32)f2bf(a.y) << 16),
                  (u32)f2bf(a.z) | ((u32)f2bf(a.w) << 16),
                  (u32)f2bf(b.x) | ((u32)f2bf(b.y) << 16),
                  (u32)f2bf(b.z) | ((u32)f2bf(b.w) << 16) };
      *(u32x4*)(out + i) = q;
    } else {
      *(u32x4*)(out + i) = *(const u32x4*)((const u16*)in + i);
    }
  } else {
    // ---- transM ----
    int t = bid - 3597;
    const void* in; u16* out;
    int inK, inN, ldo, outK, nx;
    long inBase = 0, outBase = 0;
    if (t < 1728) {                    // 3 x 768x768 weights: 576 tiles each
      int w = t / 576; t -= w * 576;
      in  = w == 0 ? Wq : w == 1 ? Wk : Wo;
      out = w == 0 ? wqt : w == 1 ? wkt : wot;
      inK = 768; inN = 768; ldo = 768; outK = 768; nx = 24;
    } else if (t < 6720) {             // Wv 768x6656: 208 n-tiles x 24 k-tiles
      t -= 1728;
      in = Wv; out = wvt;
      inK = 768; inN = 6656; ldo = 768; outK = 768; nx = 208;
    } else {                           // ctxT: 4 b x (24 n-tiles x 9 k-tiles)
      t -= 6720;
      int b = t / 216; t -= b * 216;
      in = ctx; out = ctxT;
      inK = 257; inN = 768; ldo = 264; outK = 264; nx = 24;
      inBase = (long)b * 257 * 768; outBase = (long)b * 768 * 264;
    }
    int n0 = (t % nx) * 32, k0 = (t / nx) * 32;
    int tx = threadIdx.x & 31, ty = threadIdx.x >> 5;  // 32 x 8
#pragma unroll
    for (int i = 0; i < 32; i += 8) {
      int k = k0 + ty + i, n = n0 + tx;
      float v = 0.f;
      if (k < inK && n < inN) v = gld(in, inBase + (long)k * inN + n, f);
      s[ty + i][tx] = v;
    }
    __syncthreads();
#pragma unroll
    for (int i = 0; i < 32; i += 8) {
      int n = n0 + ty + i, k = k0 + tx;
      if (n < inN && k < outK) out[outBase + (long)n * ldo + k] = f2bf(s[tx][ty + i]);
    }
  }
}

// ----------------------------------------------------------- gemm64128 ------
// C_bf16 = A[M,K] @ B[N,K]^T, tile 64(M) x 128(N), BK=32, 4 waves in 2x2
// (each 32x64, 2x4 MFMA acc). Same staging/accumulation order as the old
// 128^2 body -> bitwise-identical outputs. As = 64x32 (4KB), Bs = 128x32 (8KB).
__device__ __forceinline__ void gemm64128_body(
    u16* As, u16* Bs,
    const u16* __restrict__ A, const u16* __restrict__ B, u16* __restrict__ C,
    int M, int N, int K, int lda, int ldb, int ldc, int m0, int n0)
{
  const int tid = threadIdx.x, lane = tid & 63, wave = tid >> 6;
  const int wm = (wave >> 1) * 32, wn = (wave & 1) * 64;
  const int fm = lane & 15, fq = lane >> 4;
  const int srow = lane >> 2, selem = (lane & 3) * 8;

  int ra = m0 + wave * 16 + srow;      if (ra > M - 1) ra = M - 1;
  const int rb1 = n0 + wave * 16 + srow;
  const int rb2 = n0 + 64 + wave * 16 + srow;
  const u16* pa  = A + (long)ra * lda + selem;
  const u16* pb1 = B + (long)rb1 * ldb + selem;
  const u16* pb2 = B + (long)rb2 * ldb + selem;
  u16* la  = As + wave * 512;
  u16* lb1 = Bs + wave * 512;
  u16* lb2 = Bs + 2048 + wave * 512;

  f32x4 acc[2][4];
  const f32x4 zero4 = {0.f, 0.f, 0.f, 0.f};
#pragma unroll
  for (int a_ = 0; a_ < 2; ++a_)
#pragma unroll
    for (int b_ = 0; b_ < 4; ++b_) acc[a_][b_] = zero4;

  for (int k0 = 0; k0 < K; k0 += 32) {
    stage16(pa,  la,  lane);
    stage16(pb1, lb1, lane);
    stage16(pb2, lb2, lane);
    pa += 32; pb1 += 32; pb2 += 32;
    __syncthreads();
    bf16x8 fa[2], fb[4];
#pragma unroll
    for (int mt = 0; mt < 2; ++mt)
      fa[mt] = *(const bf16x8*)&As[(wm + mt * 16 + fm) * 32 + fq * 8];
#pragma unroll
    for (int nt = 0; nt < 4; ++nt)
      fb[nt] = *(const bf16x8*)&Bs[(wn + nt * 16 + fm) * 32 + fq * 8];
#pragma unroll
    for (int mt = 0; mt < 2; ++mt)
#pragma unroll
      for (int nt = 0; nt < 4; ++nt)
        acc[mt][nt] = __builtin_amdgcn_mfma_f32_16x16x32_bf16(fa[mt], fb[nt], acc[mt][nt], 0, 0, 0);
    __syncthreads();
  }
  // C/D layout: col=lane&15, row=(lane>>4)*4+reg (m89-verified)
#pragma unroll
  for (int mt = 0; mt < 2; ++mt)
#pragma unroll
    for (int nt = 0; nt < 4; ++nt)
#pragma unroll
      for (int rr = 0; rr < 4; ++rr) {
        int gm = m0 + wm + mt * 16 + fq * 4 + rr;
        int gn = n0 + wn + nt * 16 + fm;
        if (gm < M) C[(long)gm * ldc + gn] = f2bf(acc[mt][nt][rr]);
      }
}

// ------------------------------------------------- gemm64 body (all-bf16) ---
// 64x64 tile, BK=32, 2x2 acc/wave. Pointers pre-offset by caller (batch z).
// If Ylds != nullptr: fp32 tile -> LDS (caller epilogue); Ylds may alias As/Bs.
#define LDS_S 40

__device__ __forceinline__ void gemm64_body(
    u16* As, u16* Bs,
    const u16* __restrict__ A16, const u16* __restrict__ B16,
    float* Cf, u16* Cb, float* Ylds,
    int M, int N, int K, int lda, int ldb, int ldc,
    int btrans, float alpha, int m0, int n0)
{
  const int tid = threadIdx.x;
  const int lane = tid & 63, wave = tid >> 6;
  const int wm = (wave >> 1) * 32, wn = (wave & 1) * 32;
  const int fm = lane & 15, fq = lane >> 4;
  const int ar = tid >> 2, ak = (tid & 3) * 8;
  const int bk = tid >> 3, bn = (tid & 7) * 8;

  f32x4 acc[2][2];
  const f32x4 zero4 = {0.f, 0.f, 0.f, 0.f};
#pragma unroll
  for (int a_ = 0; a_ < 2; ++a_)
#pragma unroll
    for (int b_ = 0; b_ < 2; ++b_) acc[a_][b_] = zero4;

  for (int k0 = 0; k0 < K; k0 += 32) {
    {
      int gm = m0 + ar, gk = k0 + ak;
      long idx = (long)gm * lda + gk;
      if (gm < M && gk + 8 <= K) {
        *(u32x4*)&As[ar * LDS_S + ak] = *(const u32x4*)(A16 + idx);
      } else {
#pragma unroll
        for (int e = 0; e < 8; ++e)
          As[ar * LDS_S + ak + e] = (gm < M && gk + e < K) ? A16[idx + e] : (u16)0;
      }
    }
    if (btrans) {
      int gn = n0 + ar, gk = k0 + ak;
      long idx = (long)gn * ldb + gk;
      if (gn < N && gk + 8 <= K) {
        *(u32x4*)&Bs[ar * LDS_S + ak] = *(const u32x4*)(B16 + idx);
      } else {
#pragma unroll
        for (int e = 0; e < 8; ++e)
          Bs[ar * LDS_S + ak + e] = (gn < N && gk + e < K) ? B16[idx + e] : (u16)0;
      }
    } else {
      int gk = k0 + bk;
      long idx = (long)gk * ldb + n0 + bn;
      u16 tmp[8];
      if (gk < K) {
        u32x4 v = *(const u32x4*)(B16 + idx);
        tmp[0] = (u16)(v.x & 0xffff); tmp[1] = (u16)(v.x >> 16);
        tmp[2] = (u16)(v.y & 0xffff); tmp[3] = (u16)(v.y >> 16);
        tmp[4] = (u16)(v.z & 0xffff); tmp[5] = (u16)(v.z >> 16);
        tmp[6] = (u16)(v.w & 0xffff); tmp[7] = (u16)(v.w >> 16);
      } else {
#pragma unroll
        for (int e = 0; e < 8; ++e) tmp[e] = 0;
      }
      int rot = tid & 7;  // spread LDS bank writes
#pragma unroll
      for (int e = 0; e < 8; ++e) {
        int ee = (e + rot) & 7;
        Bs[(bn + ee) * LDS_S + bk] = tmp[ee];
      }
    }
    __syncthreads();
    {
      bf16x8 fa[2], fb[2];
      fa[0] = *(const bf16x8*)&As[(wm +      fm) * LDS_S + fq * 8];
      fa[1] = *(const bf16x8*)&As[(wm + 16 + fm) * LDS_S + fq * 8];
      fb[0] = *(const bf16x8*)&Bs[(wn +      fm) * LDS_S + fq * 8];
      fb[1] = *(const bf16x8*)&Bs[(wn + 16 + fm) * LDS_S + fq * 8];
#pragma unroll
      for (int mt = 0; mt < 2; ++mt)
#pragma unroll
        for (int nt = 0; nt < 2; ++nt)
          acc[mt][nt] = __builtin_amdgcn_mfma_f32_16x16x32_bf16(fa[mt], fb[nt], acc[mt][nt], 0, 0, 0);
    }
    __syncthreads();
  }
  if (Ylds) {
    // all LDS reads complete past the final barrier; safe to overwrite As/Bs
#pragma unroll
    for (int mt = 0; mt < 2; ++mt)
#pragma unroll
      for (int nt = 0; nt < 2; ++nt)
#pragma unroll
        for (int rr = 0; rr < 4; ++rr)
          Ylds[(wm + mt * 16 + fq * 4 + rr) * 64 + (wn + nt * 16 + fm)] = acc[mt][nt][rr];
  } else {
#pragma unroll
    for (int mt = 0; mt < 2; ++mt)
#pragma unroll
      for (int nt = 0; nt < 2; ++nt)
#pragma unroll
        for (int rr = 0; rr < 4; ++rr) {
          int gm = m0 + wm + mt * 16 + fq * 4 + rr;
          int gn = n0 + wn + nt * 16 + fm;
          if (gm < M && gn < N) {
            float v = alpha * acc[mt][nt][rr];
            if (Cb) Cb[(long)gm * ldc + gn] = f2bf(v);
            else    Cf[(long)gm * ldc + gn] = v;
          }
        }
  }
}

// ---------- mg4: q/k/mid gemm64128s + Gram gemm + wbar (bf16), LDS union ----
// GEMM range [0,1142) is XCD-chunk swizzled (m204 bijective, 1142 = 8*142+6):
// blocks with bid%8==x form XCD x's contiguous tile chunk -> per-XCD L2 keeps
// its B-panel chunk + A resident (R21: FETCH 73MB vs 17MB unique = cross-XCD
// re-fill). Mapping-only change; same tiles, same math.
__global__ __launch_bounds__(256) void mg4_k(
    const u16* __restrict__ xb, const u16* __restrict__ wqt, u16* __restrict__ qbf,
    const u16* __restrict__ cbuf, const u16* __restrict__ wkt, u16* __restrict__ kbf,
    const u16* __restrict__ wvt, u16* __restrict__ midbf,
    const u16* __restrict__ wcvb, u16* __restrict__ Gb, float* __restrict__ wbar)
{
  __shared__ __attribute__((aligned(16))) char smem[16384];
  int bid = blockIdx.x;
  if (bid < 1142) {
    int xcd = bid & 7, idx = bid >> 3;
    int v = (xcd < 6 ? xcd * 143 : 858 + (xcd - 6) * 142) + idx;  // bijective
    const u16 *A, *B; u16* C; int M, N, lid, mx;
    if (v < 156)      { A = xb;   B = wqt; C = qbf;   M = 1664; N = 768;  lid = v;       mx = 26; }
    else if (v < 258) { A = cbuf; B = wkt; C = kbf;   M = 1028; N = 768;  lid = v - 156; mx = 17; }
    else              { A = cbuf; B = wvt; C = midbf; M = 1028; N = 6656; lid = v - 258; mx = 17; }
    int m0 = (lid % mx) * 64, n0 = (lid / mx) * 128;
    gemm64128_body((u16*)smem, (u16*)(smem + 4096), A, B, C, M, N, 768, 768, 768, N, m0, n0);
  } else if (bid < 1246) {
    int z = bid - 1142;   // 0..103: M[g] = Wconv_b[g] @ Wconv_b[g]^T / 768
    gemm64_body((u16*)smem, (u16*)(smem + 5120),
                wcvb + (long)z * 49152, wcvb + (long)z * 49152,
                nullptr, Gb + (long)z * 4096, nullptr,
                64, 64, 768, 768, 768, 64, 1, 1.f / 768.f, 0, 0);
  } else {
    // wbar: row means of bf16 Wconv copy, r = g*64+l over 768 cols
    int r = (bid - 1246) * 4 + (threadIdx.x >> 6);
    int lane = threadIdx.x & 63;
    const u16* prow = wcvb + (long)r * 768;
    float sm = 0.f;
    for (int c = 0 + lane; c < 768; c += 64) sm += bf2f(prow[c]);
#pragma unroll
    for (int o = 32; o; o >>= 1) sm += __shfl_xor(sm, o, 64);
    if (lane == 0) wbar[r] = sm * (1.f / 768.f);
  }
}

// ------------------------------ final: out_pre @ Wo^T (64x128 tiles) --------
// XCD-chunk swizzled (156 = 8*19+4).
__global__ __launch_bounds__(256) void gemmF_k(
    const u16* __restrict__ opbf, const u16* __restrict__ wot, u16* __restrict__ qbf)
{
  __shared__ __attribute__((aligned(16))) char smem[12288];
  int bid = blockIdx.x;
  int xcd = bid & 7, idx = bid >> 3;
  int lid = (xcd < 4 ? xcd * 20 : 80 + (xcd - 4) * 19) + idx;   // bijective
  gemm64128_body((u16*)smem, (u16*)(smem + 4096), opbf, wot, qbf,
                 1664, 768, 768, 768, 768, 768, (lid % 26) * 64, (lid / 26) * 128);
}

// --------------------- ysim: Y-gemm with fused stats epilogue + sim-gemm ----
__global__ __launch_bounds__(256) void ysim_k(
    const u16* __restrict__ midbf, const u16* __restrict__ Gb,
    const float* __restrict__ wbar, u16* __restrict__ midi, float* __restrict__ pim,
    const u16* __restrict__ qbf, const u16* __restrict__ kbf, float* __restrict__ simf)
{
  __shared__ __attribute__((aligned(16))) char smem[16384];
  u16* As = (u16*)smem;
  u16* Bs = (u16*)(smem + 8192);
  int bid = blockIdx.x;
  if (bid < 1768) {
    // Y = mid_g[1028x64] @ M[g]^T -> fp32 tile in LDS, then stats epilogue
    int g = bid / 17, bx = bid % 17;
    int m0 = bx * 64;
    float* Ylds = (float*)smem;   // aliases As/Bs (dead after final barrier)
    gemm64_body(As, Bs, midbf + (long)g * 64, Gb + (long)g * 4096,
                nullptr, nullptr, Ylds,
                1028, 64, 64, 6656, 64, 64, 1, 1.f, m0, 0);
    __syncthreads();
    int tid = threadIdx.x, lane = tid & 63, wave = tid >> 6;
#pragma unroll
    for (int rr = 0; rr < 16; ++rr) {
      int r = wave * 16 + rr;          // local row
      int gr = m0 + r;                 // global row (wave-uniform)
      if (gr < 1028) {
        float m  = bf2f(midbf[(long)gr * 6656 + g * 64 + lane]);
        float y  = Ylds[r * 64 + lane];
        float wb = wbar[g * 64 + lane];
        float mup = m * wb, q2p = m * y;
#pragma unroll
        for (int o = 32; o; o >>= 1) { mup += __shfl_xor(mup, o, 64); q2p += __shfl_xor(q2p, o, 64); }
        float var = q2p - mup * mup;
        float inv = rsqrtf(fmaxf(var, 0.f) + 1e-5f);
        int b = gr / 257, j = gr - b * 257;
        long zidx = (long)b * 104 + g;
        midi[(zidx * 264 + j) * 64 + lane] = f2bf(inv * m);
        if (lane == 0) pim[zidx * 257 + j] = inv * mup;
      }
    }
  } else {
    // sim = scale^2 * q @ k^T;  z = b*6+h
    int lid = bid - 1768; int z = lid / 35, r = lid % 35, bx = r % 7, by = r / 7;
    const u16* A = qbf + (long)(z / 6) * 319488 + (long)(z % 6) * 128;
    const u16* B = kbf + (long)(z / 6) * 197376 + (long)(z % 6) * 128;
    float* Cf = simf + (long)z * 106912;
    gemm64_body(As, Bs, A, B, Cf, nullptr, nullptr,
                416, 257, 128, 768, 768, 257, 1, 0.08838834764831845f, bx * 64, by * 64);
  }
}

// --------------------------------------------------- ct: c-gemm + T-gemm ----
__global__ __launch_bounds__(256) void ct_k(
    const u16* __restrict__ Abf, const u16* __restrict__ ctxT, float* __restrict__ c_buf,
    const u16* __restrict__ A2bf, const u16* __restrict__ midi, u16* __restrict__ Tb16)
{
  __shared__ __attribute__((aligned(16))) u16 As[64 * LDS_S];
  __shared__ __attribute__((aligned(16))) u16 Bs[64 * LDS_S];
  int bid = blockIdx.x;
  if (bid < 336) {
    // c = A @ ctx_head (btrans via ctx^T, K=264); z = b*6+h
    int z = bid / 14, r = bid % 14, bx = r % 7, by = r / 7;
    const u16* A = Abf + (long)z * 109824;
    const u16* B = ctxT + (long)(z / 6) * 202752 + (long)(z % 6) * 33792;
    float* Cf = c_buf + (long)z * 53248;
    gemm64_body(As, Bs, A, B, Cf, nullptr, nullptr,
                416, 128, 264, 264, 264, 128, 1, 1.f, bx * 64, by * 64);
  } else {
    // T = A2 @ midi (non-trans, K=264, 264-row-padded midi); z = b*104+g
    int z = bid - 336;
    const u16* A = A2bf + (long)z * 6336;
    const u16* B = midi + (long)z * 16896;
    u16* Cb = Tb16 + (long)z * 1536;
    gemm64_body(As, Bs, A, B, nullptr, Cb, nullptr,
                24, 64, 264, 264, 64, 64, 0, 1.f, 0, 0);
  }
}

// ------------------------------------------------------------- row LN -------
__device__ __forceinline__ void ln_row(
    const u16* __restrict__ ip, const void* __restrict__ g, const void* __restrict__ b,
    u16* __restrict__ ob, float* __restrict__ of, int N, int f)
{
  int tid = threadIdx.x, lane = tid & 63, wave = tid >> 6;
  const int nv = N >> 3;
  float s1 = 0.f, s2 = 0.f;
  for (int c8 = tid; c8 < nv; c8 += 256) {
    u32x4 v = *(const u32x4*)(ip + c8 * 8);
    float e0 = bf2f((u16)(v.x & 0xffff)), e1 = bf2f((u16)(v.x >> 16));
    float e2 = bf2f((u16)(v.y & 0xffff)), e3 = bf2f((u16)(v.y >> 16));
    float e4 = bf2f((u16)(v.z & 0xffff)), e5 = bf2f((u16)(v.z >> 16));
    float e6 = bf2f((u16)(v.w & 0xffff)), e7 = bf2f((u16)(v.w >> 16));
    s1 += ((e0 + e1) + (e2 + e3)) + ((e4 + e5) + (e6 + e7));
    s2 += ((e0*e0 + e1*e1) + (e2*e2 + e3*e3)) + ((e4*e4 + e5*e5) + (e6*e6 + e7*e7));
  }
#pragma unroll
  for (int o = 32; o; o >>= 1) { s1 += __shfl_xor(s1, o, 64); s2 += __shfl_xor(s2, o, 64); }
  __shared__ float red[8];
  if (lane == 0) { red[wave] = s1; red[4 + wave] = s2; }
  __syncthreads();
  s1 = red[0] + red[1] + red[2] + red[3];
  s2 = red[4] + red[5] + red[6] + red[7];
  float mean = s1 / N;
  float var = s2 / N - mean * mean;
  float rstd = rsqrtf(fmaxf(var, 0.f) + 1e-5f);
  for (int c8 = tid; c8 < nv; c8 += 256) {
    int c = c8 * 8;
    u32x4 v = *(const u32x4*)(ip + c);
    float e[8];
    e[0] = bf2f((u16)(v.x & 0xffff)); e[1] = bf2f((u16)(v.x >> 16));
    e[2] = bf2f((u16)(v.y & 0xffff)); e[3] = bf2f((u16)(v.y >> 16));
    e[4] = bf2f((u16)(v.z & 0xffff)); e[5] = bf2f((u16)(v.z >> 16));
    e[6] = bf2f((u16)(v.w & 0xffff)); e[7] = bf2f((u16)(v.w >> 16));
    float gg[8], bb[8];
    if (f) {
      const float* gp = (const float*)g + c; const float* bp = (const float*)b + c;
      f32x4 g0 = *(const f32x4*)gp, g1 = *(const f32x4*)(gp + 4);
      f32x4 b0 = *(const f32x4*)bp, b1 = *(const f32x4*)(bp + 4);
      gg[0]=g0.x; gg[1]=g0.y; gg[2]=g0.z; gg[3]=g0.w; gg[4]=g1.x; gg[5]=g1.y; gg[6]=g1.z; gg[7]=g1.w;
      bb[0]=b0.x; bb[1]=b0.y; bb[2]=b0.z; bb[3]=b0.w; bb[4]=b1.x; bb[5]=b1.y; bb[6]=b1.z; bb[7]=b1.w;
    } else {
      u32x4 gv = *(const u32x4*)((const u16*)g + c);
      u32x4 bv = *(const u32x4*)((const u16*)b + c);
      gg[0]=bf2f((u16)(gv.x&0xffff)); gg[1]=bf2f((u16)(gv.x>>16));
      gg[2]=bf2f((u16)(gv.y&0xffff)); gg[3]=bf2f((u16)(gv.y>>16));
      gg[4]=bf2f((u16)(gv.z&0xffff)); gg[5]=bf2f((u16)(gv.z>>16));
      gg[6]=bf2f((u16)(gv.w&0xffff)); gg[7]=bf2f((u16)(gv.w>>16));
      bb[0]=bf2f((u16)(bv.x&0xffff)); bb[1]=bf2f((u16)(bv.x>>16));
      bb[2]=bf2f((u16)(bv.y&0xffff)); bb[3]=bf2f((u16)(bv.y>>16));
      bb[4]=bf2f((u16)(bv.z&0xffff)); bb[5]=bf2f((u16)(bv.z>>16));
      bb[6]=bf2f((u16)(bv.w&0xffff)); bb[7]=bf2f((u16)(bv.w>>16));
    }
    float o_[8];
#pragma unroll
    for (int e2i = 0; e2i < 8; ++e2i) o_[e2i] = (e[e2i] - mean) * rstd * gg[e2i] + bb[e2i];
    if (of) {
      f32x4 o0 = {o_[0], o_[1], o_[2], o_[3]}, o1 = {o_[4], o_[5], o_[6], o_[7]};
      *(f32x4*)(of + c) = o0; *(f32x4*)(of + c + 4) = o1;
    } else {
      u32x4 q = { (u32)f2bf(o_[0]) | ((u32)f2bf(o_[1]) << 16),
                  (u32)f2bf(o_[2]) | ((u32)f2bf(o_[3]) << 16),
                  (u32)f2bf(o_[4]) | ((u32)f2bf(o_[5]) << 16),
                  (u32)f2bf(o_[6]) | ((u32)f2bf(o_[7]) << 16) };
      *(u32x4*)(ob + c) = q;
    }
  }
}

__global__ __launch_bounds__(256) void ln_rows(
    const u16* __restrict__ in, const void* __restrict__ g, const void* __restrict__ b,
    void* __restrict__ out, int N, const int* __restrict__ dtf, int isfinal, int fknown)
{
  const int f = (fknown >= 0) ? fknown : dtf[0];
  long row = blockIdx.x;
  const u16* ip = in + row * N;
  float* of = (isfinal && f) ? (float*)out + row * N : nullptr;
  u16*   ob = of ? nullptr : (u16*)out + row * N;
  ln_row(ip, g, b, ob, of, N, f);
}

// merged LN for q (1664x768), k (1028x768), mid (1028x6656)
__global__ __launch_bounds__(256) void mln3_k(
    u16* __restrict__ qb, const void* __restrict__ gq, const void* __restrict__ bq,
    u16* __restrict__ kb, const void* __restrict__ gk, const void* __restrict__ bk,
    u16* __restrict__ mb, const void* __restrict__ gv, const void* __restrict__ bv,
    const int* __restrict__ dtf, int fknown)
{
  const int f = (fknown >= 0) ? fknown : dtf[0];
  int row = blockIdx.x;
  u16* ip; const void *g, *b; int N;
  if (row < 1664)      { ip = qb + (long)row * 768; g = gq; b = bq; N = 768; }
  else if (row < 2692) { ip = kb + (long)(row - 1664) * 768; g = gk; b = bk; N = 768; }
  else                 { ip = mb + (long)(row - 2692) * 6656; g = gv; b = bv; N = 6656; }
  ln_row(ip, g, b, ip, nullptr, N, f);
}

// ------------------------------------------------------------- softmax ------
__global__ __launch_bounds__(256) void softmax_k(
    const float* __restrict__ simf, const float* __restrict__ pim,
    u16* __restrict__ Abf, u16* __restrict__ A2bf, float* __restrict__ s_sh)
{
  int bh = blockIdx.x;
  int b = bh / 6, h = bh - b * 6;
  int tid = threadIdx.x, lane = tid & 63, wave = tid >> 6;
  int i = blockIdx.y * 4 + wave;
  int g = i % 104, rq = i / 104;
  const float* sp_ = simf + ((long)bh * 416 + i) * 257;
  float s[5];
#pragma unroll
  for (int jc = 0; jc < 5; ++jc) {
    int j = jc * 64 + lane;
    s[jc] = (j < 257) ? sp_[j] : -1e30f;
  }
  float mx = -1e30f;
#pragma unroll
  for (int jc = 0; jc < 5; ++jc) mx = fmaxf(mx, s[jc]);
#pragma unroll
  for (int o = 32; o; o >>= 1) mx = fmaxf(mx, __shfl_xor(mx, o, 64));
  float p[5], sum = 0.f, sp = 0.f;
  long pimb = ((long)b * 104 + g) * 257;
#pragma unroll
  for (int jc = 0; jc < 5; ++jc) {
    int j = jc * 64 + lane;
    float pv = 0.f;
    if (j < 257) { pv = __expf(s[jc] - mx); sp = fmaf(pv, pim[pimb + j], sp); }
    p[jc] = pv; sum += pv;
  }
#pragma unroll
  for (int o = 32; o; o >>= 1) { sum += __shfl_xor(sum, o, 64); sp += __shfl_xor(sp, o, 64); }
  float rs = 1.f / sum;
  long arow  = ((long)bh * 416 + i) * 264;
  long a2row = (((long)b * 104 + g) * 24 + h * 4 + rq) * 264;
#pragma unroll
  for (int jc = 0; jc < 5; ++jc) {
    int j = jc * 64 + lane;
    if (j < 257) { u16 pb = f2bf(p[jc] * rs); Abf[arow + j] = pb; A2bf[a2row + j] = pb; }
    else if (j < 264) { Abf[arow + j] = 0; A2bf[a2row + j] = 0; }
  }
  if (lane == 0) s_sh[(long)bh * 416 + i] = sp * rs;
}

// -------------------------------------------------- fused O-gemm + combine --
__global__ __launch_bounds__(256) void oc_k(
    const u16* __restrict__ T, const u16* __restrict__ Wb,
    const float* __restrict__ s_sh, const float* __restrict__ c_buf,
    const void* __restrict__ gv2, const void* __restrict__ bv2,
    u16* __restrict__ opbf, const int* __restrict__ dtf, int fknown)
{
  const int f = (fknown >= 0) ? fknown : dtf[0];
  int z = blockIdx.x;                 // b*104+g
  int b = z / 104, g = z - b * 104;
  int tid = threadIdx.x;
  __shared__ float Ts[24][64];        // 6 KB
  const u16* tp = T + (long)z * 1536;
  for (int idx = tid; idx < 1536; idx += 256) Ts[idx >> 6][idx & 63] = bf2f(tp[idx]);
  __syncthreads();
  const int dh = tid & 127;
  const int hbase = (tid >> 7) * 3;   // threads 0..127 -> h 0..2, 128..255 -> h 3..5
  const u16* wg = Wb + (long)g * 49152;
#pragma unroll
  for (int hh = 0; hh < 3; ++hh) {
    int h = hbase + hh;
    int d = h * 128 + dh;
    const u16* wp = wg + d;
    float a0 = 0.f, a1 = 0.f, a2 = 0.f, a3 = 0.f;
#pragma unroll 16
    for (int k = 0; k < 64; ++k) {
      float w = bf2f(wp[(long)k * 768]);
      a0 = fmaf(Ts[h * 4 + 0][k], w, a0);
      a1 = fmaf(Ts[h * 4 + 1][k], w, a1);
      a2 = fmaf(Ts[h * 4 + 2][k], w, a2);
      a3 = fmaf(Ts[h * 4 + 3][k], w, a3);
    }
    float acc[4] = {a0, a1, a2, a3};
    float gvd = gld(gv2, d, f), bvd = gld(bv2, d, f);
#pragma unroll
    for (int rq = 0; rq < 4; ++rq) {
      int i = rq * 104 + g;
      float ssh = s_sh[((long)b * 6 + h) * 416 + i];
      float val = gvd * (acc[rq] - ssh) + bvd
                + c_buf[(((long)b * 6 + h) * 416 + i) * 128 + dh];
      opbf[((long)b * 416 + i) * 768 + d] = f2bf(val);
    }
  }
}

// ---------------------------------------------------------------- host ------
extern "C" void kernel_launch(void* const* d_in, const int* in_sizes, int n_in,
                              void* d_out, int out_size, void* d_ws, size_t ws_size,
                              hipStream_t stream)
{
  const void* x   = d_in[0];
  const void* ctx = d_in[1];
  const void* Wq  = d_in[2];
  const void* gq  = d_in[3];
  const void* bq  = d_in[4];
  const void* Wk  = d_in[5];
  const void* gk  = d_in[6];
  const void* bk  = d_in[7];
  const void* Wv  = d_in[8];
  const void* gv1 = d_in[9];
  const void* bv1 = d_in[10];
  const void* Wcv = d_in[11];
  const void* gv2 = d_in[12];
  const void* bv2 = d_in[13];
  const void* Wo  = d_in[14];
  const void* go  = d_in[15];
  const void* bo  = d_in[16];

  // -------- workspace layout --------
  const size_t SZ_FLAG = 256;
  const size_t SZ_QBF  = 2555904;
  const size_t SZ_KBF  = 1579008;
  const size_t SZ_MID  = 13684736;
  const size_t SZ_MM   = 1703936;
  const size_t SZ_WB   = 26624;
  const size_t SZ_MIDI = 14057472;   // 416 * 264 * 64 bf16 (264-row padded)
  const size_t SZ_PIM  = 427648;
  const size_t SZ_ABF  = 5271552;
  const size_t SZ_A2   = 5271552;
  const size_t SZ_SSH  = 39936;
  const size_t SZ_CB   = 1579008;
  const size_t SZ_WCVB = 10223616;   // 104*64*768 bf16
  const size_t SZ_WT   = 1179648;    // 768*768 bf16 (x3: WqT, WkT, WoT)
  const size_t SZ_WVT  = 10223616;   // 6656*768 bf16
  const size_t SZ_CTXT = 1622016;    // 4*768*264 bf16 (ctx^T, zero-padded cols)
  const size_t SZ_SIMF = 10263552;   // 24*416*257 fp32
  const size_t REQUIRED = SZ_FLAG + SZ_QBF + SZ_KBF + SZ_MID + SZ_MM + SZ_WB +
                          SZ_MIDI + SZ_PIM + SZ_ABF + SZ_A2 + SZ_SSH + SZ_CB +
                          SZ_WCVB + 3 * SZ_WT + SZ_WVT + SZ_CTXT + SZ_SIMF;  // 82,069,376

  if (ws_size < REQUIRED) {
    fill_k<<<(out_size + 255) / 256, 256, 0, stream>>>((u16*)d_out, (float)(ws_size >> 20), out_size);
    return;
  }

  char* p = (char*)d_ws;
  int*   dtf   = (int*)  p;                 p += SZ_FLAG;
  u16*   qbf   = (u16*)  p;                 p += SZ_QBF;
  u16*   kbf   = (u16*)  p;                 p += SZ_KBF;
  char*  midrg = p;                         p += SZ_MID;
  char*  mmrg  = p;                         p += SZ_MM;
  float* wbar  = (float*)p;                 p += SZ_WB;
  u16*   midi  = (u16*)  p;                 p += SZ_MIDI;
  float* pim   = (float*)p;                 p += SZ_PIM;
  char*  abfrg = p;                         p += SZ_ABF;
  u16*   A2bf  = (u16*)  p;                 p += SZ_A2;
  float* s_sh  = (float*)p;                 p += SZ_SSH;
  u16*   cb    = (u16*)  p;                 p += SZ_CB;
  u16*   wcvb  = (u16*)  p;                 p += SZ_WCVB;
  u16*   wqt2  = (u16*)  p;                 p += SZ_WT;
  u16*   wkt2  = (u16*)  p;                 p += SZ_WT;
  u16*   wot2  = (u16*)  p;                 p += SZ_WT;
  u16*   wvt   = (u16*)  p;                 p += SZ_WVT;
  u16*   ctxT  = (u16*)  p;                 p += SZ_CTXT;
  float* simf  = (float*)p;                 p += SZ_SIMF;

  u16*   midbf = (u16*)midrg;
  float* c_buf = (float*)midrg;             // midbf dead after ysim stats
  u16*   Tb16  = (u16*)(midrg + 5111808);   // right after c_buf's 5,111,808 B
  u16*   Gb    = (u16*)mmrg;
  u16*   xb    = (u16*)abfrg;
  u16*   Abf   = (u16*)abfrg;
  u16*   opbf  = (u16*)abfrg;               // Abf dead after ct_k

  // host-side dtype: in_sizes[0] in bytes distinguishes fp32 (5,111,808) from
  // bf16 (2,555,904); anything else (e.g. element count) -> probe fallback.
  int fknown = -1;
  if (in_sizes && n_in > 0) {
    if (in_sizes[0] == 5111808)      fknown = 1;
    else if (in_sizes[0] == 2555904) fknown = 0;
  }
  if (fknown < 0) probe_k<<<1, 256, 0, stream>>>((const u32*)x, dtf);

  // prep: copies + midi pad zero (3597) | transposes (7584)
  prep_k<<<11181, 256, 0, stream>>>(x, xb, ctx, cb, Wcv, wcvb, midi,
                                    Wq, Wk, Wo, Wv, wqt2, wkt2, wot2, wvt, ctxT,
                                    dtf, fknown);

  // q/k/mid gemm64128s (1142, XCD-chunk swizzled) + Gram (104) + wbar (1664)
  mg4_k<<<2910, 256, 0, stream>>>(xb, wqt2, qbf, cb, wkt2, kbf, wvt, midbf,
                                  wcvb, Gb, wbar);

  // q/k/mid LNs
  mln3_k<<<3720, 256, 0, stream>>>(qbf, gq, bq, kbf, gk, bk, midbf, gv1, bv1,
                                   dtf, fknown);

  // Y = mid_g @ M[g] with fused stats epilogue (1768) + sim (840)
  ysim_k<<<2608, 256, 0, stream>>>(midbf, Gb, wbar, midi, pim, qbf, kbf, simf);

  softmax_k<<<dim3(24, 104), 256, 0, stream>>>(simf, pim, Abf, A2bf, s_sh);

  // c = A @ ctx_head (336) + T = A2 @ midi (416)
  ct_k<<<752, 256, 0, stream>>>(Abf, ctxT, c_buf, A2bf, midi, Tb16);

  // fused O-gemm + combine
  oc_k<<<416, 256, 0, stream>>>(Tb16, wcvb, s_sh, c_buf, gv2, bv2, opbf, dtf, fknown);

  // out = LN(out_pre @ Wo): 64x128 tiles, XCD-chunk swizzled
  gemmF_k<<<156, 256, 0, stream>>>(opbf, wot2, qbf);
  ln_rows<<<1664, 256, 0, stream>>>(qbf, go, bo, d_out, 768, dtf, 1, fknown);
}

// Round 13
// 260.537 us; speedup vs baseline: 3.0998x; 1.0028x over previous
//
#include <hip/hip_runtime.h>

// SubjBasisGenerator fused pipeline. B=4 NQ=416 NC=257 D=768 H=6 DH=128 G=104 R=4 LORA=64
// R23: BK 32->64 in gemm64128 (dual half-panels): 6 stage16 / one drain /
//      16 MFMA / one barrier per iter, 12 iters instead of 24. R22 proved the
//      limiter is the K-loop barrier-drain count, not locality (FETCH 73->24MB
//      at unchanged 41us). h-loop runs k-halves in increasing-k order -> same
//      MFMA accumulation sequence -> bitwise-identical outputs. LDS 24KB
//      (<=6 blocks/CU at 160KB/CU; grid gives 4.5 -> occupancy unaffected).
// R22: T1 XCD-chunked bijective swizzle in mg4+gemmF (FETCH 73->24MB).
// R21: gemm64128 retile (64x128): occupancy 25->44%, 273->262us.
// R20: wbar in mg4 (bf16); host-side dtype from in_sizes[0] (probe fallback).
// R16: stats2 fused into Y-gemm epilogue. R14: dispatch 16->11.
// R13/R12: merged gemms/LNs/transposes, ctx^T fast path, K padded 264.
// R11: oc_k fusion, Wconv bf16 pre-convert.
//
// Algebra: the grouped-conv+LN v-path decomposes exactly:
//   sum_j A_j v_j = gv2*( (sum_j A_j inv_j mid_j)@Wconv[g] - sum_j A_j inv_j mu_j )
//                   + bv2 + (A @ ctx)
//   q2[b,g,j] = mid^T M[g] mid = mid . (M[g] @ mid),  M[g] = Wconv[g]Wconv[g]^T/768

typedef unsigned short u16;
typedef unsigned int   u32;
typedef __attribute__((ext_vector_type(4))) float f32x4;
typedef __attribute__((ext_vector_type(4))) u32   u32x4;
typedef __attribute__((ext_vector_type(8))) short bf16x8;

__device__ __forceinline__ float bf2f(u16 v) { return __uint_as_float(((u32)v) << 16); }
__device__ __forceinline__ u16 f2bf(float f) {
  u32 u = __float_as_uint(f);
  u32 r = u + 0x7fffu + ((u >> 16) & 1u);  // RNE
  return (u16)(r >> 16);
}
__device__ __forceinline__ float gld(const void* p, long idx, int f32) {
  return f32 ? ((const float*)p)[idx] : bf2f(((const u16*)p)[idx]);
}

typedef const __attribute__((address_space(1))) u32 gas_u32;
typedef __attribute__((address_space(3))) u32 las_u32;

// async 16B/lane global->LDS; LDS dest = wave-uniform base + lane*16 (m97).
__device__ __forceinline__ void stage16(const u16* g, u16* lbase, int lane) {
#if __has_builtin(__builtin_amdgcn_global_load_lds)
  (void)lane;
  __builtin_amdgcn_global_load_lds((gas_u32*)g, (las_u32*)lbase, 16, 0, 0);
#else
  *(u32x4*)(lbase + lane * 8) = *(const u32x4*)g;
#endif
}

// ------------------------------------------------------------ dtype probe ---
__global__ __launch_bounds__(256) void probe_k(const u32* __restrict__ xw, int* __restrict__ flag) {
  int tid = threadIdx.x, c = 0;
  for (int i = tid; i < 4096; i += 256) {
    u16 lo = (u16)(xw[i] & 0xffffu);
    float a = fabsf(bf2f(lo));
    if (lo == 0 || (a >= 1e-3f && a <= 32.f)) ++c;
  }
#pragma unroll
  for (int o = 32; o; o >>= 1) c += __shfl_xor(c, o, 64);
  __shared__ int r[4];
  if ((tid & 63) == 0) r[tid >> 6] = c;
  __syncthreads();
  if (tid == 0) flag[0] = (r[0] + r[1] + r[2] + r[3] >= 2048) ? 0 : 1;  // 1 = fp32
}

// ------------------------------------------------------------ diag fill -----
__global__ __launch_bounds__(256) void fill_k(u16* p, float v, int n) {
  int i = blockIdx.x * 256 + threadIdx.x;
  if (i < n) p[i] = f2bf(v);
}

// --------------------------------------------------------------- prep_k -----
// blocks [0,3597): ext->bf16 copies (x, ctx, Wconv) + midi pad-row zeroing
// blocks [3597,11181): transposes Wq/Wk/Wo (768^2), Wv (768x6656), ctx^T
__global__ __launch_bounds__(256) void prep_k(
    const void* __restrict__ x,   u16* __restrict__ xb,
    const void* __restrict__ ctx, u16* __restrict__ cbuf,
    const void* __restrict__ Wcv, u16* __restrict__ wcvb,
    u16* __restrict__ midi,
    const void* __restrict__ Wq, const void* __restrict__ Wk,
    const void* __restrict__ Wo, const void* __restrict__ Wv,
    u16* __restrict__ wqt, u16* __restrict__ wkt, u16* __restrict__ wot,
    u16* __restrict__ wvt, u16* __restrict__ ctxT,
    const int* __restrict__ dtf, int fknown)
{
  const int f = (fknown >= 0) ? fknown : dtf[0];
  int bid = blockIdx.x;
  __shared__ float s[32][33];
  if (bid < 3597) {
    // ---- convb4 ----
    const long n0_ = 1277952, n1_ = 789504, n2_ = 5111808, n3_ = 186368;
    long i = ((long)bid * 256 + threadIdx.x) * 8;
    const long t0 = n0_, t1 = t0 + n1_, t2 = t1 + n2_, t3 = t2 + n3_;
    if (i >= t3) return;
    if (i >= t2) {
      long e = i - t2;                 // zero 7 pad rows per midi z-block
      long z = e / 448, off = e - z * 448;
      u32x4 zz = {0u, 0u, 0u, 0u};
      *(u32x4*)(midi + z * 16896 + 16448 + off) = zz;
      return;
    }
    const void* in; u16* out;
    if (i < t0)      { in = x;    out = xb; }
    else if (i < t1) { in = ctx;  out = cbuf; i -= t0; }
    else             { in = Wcv;  out = wcvb; i -= t1; }
    if (f) {
      const float* ip = (const float*)in + i;
      f32x4 a = *(const f32x4*)ip, b = *(const f32x4*)(ip + 4);
      u32x4 q = { (u32)f2bf(a.x) | ((u32)f2bf(a.y) << 16),
                  (u32)f2bf(a.z) | ((u32)f2bf(a.w) << 16),
                  (u32)f2bf(b.x) | ((u32)f2bf(b.y) << 16),
                  (u32)f2bf(b.z) | ((u32)f2bf(b.w) << 16) };
      *(u32x4*)(out + i) = q;
    } else {
      *(u32x4*)(out + i) = *(const u32x4*)((const u16*)in + i);
    }
  } else {
    // ---- transM ----
    int t = bid - 3597;
    const void* in; u16* out;
    int inK, inN, ldo, outK, nx;
    long inBase = 0, outBase = 0;
    if (t < 1728) {                    // 3 x 768x768 weights: 576 tiles each
      int w = t / 576; t -= w * 576;
      in  = w == 0 ? Wq : w == 1 ? Wk : Wo;
      out = w == 0 ? wqt : w == 1 ? wkt : wot;
      inK = 768; inN = 768; ldo = 768; outK = 768; nx = 24;
    } else if (t < 6720) {             // Wv 768x6656: 208 n-tiles x 24 k-tiles
      t -= 1728;
      in = Wv; out = wvt;
      inK = 768; inN = 6656; ldo = 768; outK = 768; nx = 208;
    } else {                           // ctxT: 4 b x (24 n-tiles x 9 k-tiles)
      t -= 6720;
      int b = t / 216; t -= b * 216;
      in = ctx; out = ctxT;
      inK = 257; inN = 768; ldo = 264; outK = 264; nx = 24;
      inBase = (long)b * 257 * 768; outBase = (long)b * 768 * 264;
    }
    int n0 = (t % nx) * 32, k0 = (t / nx) * 32;
    int tx = threadIdx.x & 31, ty = threadIdx.x >> 5;  // 32 x 8
#pragma unroll
    for (int i = 0; i < 32; i += 8) {
      int k = k0 + ty + i, n = n0 + tx;
      float v = 0.f;
      if (k < inK && n < inN) v = gld(in, inBase + (long)k * inN + n, f);
      s[ty + i][tx] = v;
    }
    __syncthreads();
#pragma unroll
    for (int i = 0; i < 32; i += 8) {
      int n = n0 + ty + i, k = k0 + tx;
      if (n < inN && k < outK) out[outBase + (long)n * ldo + k] = f2bf(s[tx][ty + i]);
    }
  }
}

// ----------------------------------------------------------- gemm64128 ------
// C_bf16 = A[M,K] @ B[N,K]^T, tile 64(M) x 128(N), BK=64 via dual half-panels
// (As = 2 x [64][32], Bs = 2 x [128][32]): 6 stage16 / one vmcnt drain /
// 16 MFMA / one barrier per iter. h-loop in increasing-k order -> accumulation
// sequence identical to BK=32 -> bitwise-identical outputs. Requires K%64==0.
__device__ __forceinline__ void gemm64128_body(
    u16* As, u16* Bs,
    const u16* __restrict__ A, const u16* __restrict__ B, u16* __restrict__ C,
    int M, int N, int K, int lda, int ldb, int ldc, int m0, int n0)
{
  const int tid = threadIdx.x, lane = tid & 63, wave = tid >> 6;
  const int wm = (wave >> 1) * 32, wn = (wave & 1) * 64;
  const int fm = lane & 15, fq = lane >> 4;
  const int srow = lane >> 2, selem = (lane & 3) * 8;

  int ra = m0 + wave * 16 + srow;      if (ra > M - 1) ra = M - 1;
  const int rb1 = n0 + wave * 16 + srow;
  const int rb2 = n0 + 64 + wave * 16 + srow;
  const u16* pa  = A + (long)ra * lda + selem;
  const u16* pb1 = B + (long)rb1 * ldb + selem;
  const u16* pb2 = B + (long)rb2 * ldb + selem;
  u16* la  = As + wave * 512;          // As half 0; half 1 at +2048
  u16* lb1 = Bs + wave * 512;          // Bs half 0 rows 0-63; half 1 at +4096
  u16* lb2 = Bs + 2048 + wave * 512;   // Bs half 0 rows 64-127

  f32x4 acc[2][4];
  const f32x4 zero4 = {0.f, 0.f, 0.f, 0.f};
#pragma unroll
  for (int a_ = 0; a_ < 2; ++a_)
#pragma unroll
    for (int b_ = 0; b_ < 4; ++b_) acc[a_][b_] = zero4;

  for (int k0 = 0; k0 < K; k0 += 64) {
    stage16(pa,       la,        lane);
    stage16(pb1,      lb1,       lane);
    stage16(pb2,      lb2,       lane);
    stage16(pa  + 32, la + 2048, lane);
    stage16(pb1 + 32, lb1 + 4096, lane);
    stage16(pb2 + 32, lb2 + 4096, lane);
    pa += 64; pb1 += 64; pb2 += 64;
    __syncthreads();
#pragma unroll
    for (int h = 0; h < 2; ++h) {
      const u16* Ah = As + h * 2048;
      const u16* Bh = Bs + h * 4096;
      bf16x8 fa[2], fb[4];
#pragma unroll
      for (int mt = 0; mt < 2; ++mt)
        fa[mt] = *(const bf16x8*)&Ah[(wm + mt * 16 + fm) * 32 + fq * 8];
#pragma unroll
      for (int nt = 0; nt < 4; ++nt)
        fb[nt] = *(const bf16x8*)&Bh[(wn + nt * 16 + fm) * 32 + fq * 8];
#pragma unroll
      for (int mt = 0; mt < 2; ++mt)
#pragma unroll
        for (int nt = 0; nt < 4; ++nt)
          acc[mt][nt] = __builtin_amdgcn_mfma_f32_16x16x32_bf16(fa[mt], fb[nt], acc[mt][nt], 0, 0, 0);
    }
    __syncthreads();
  }
  // C/D layout: col=lane&15, row=(lane>>4)*4+reg (m89-verified)
#pragma unroll
  for (int mt = 0; mt < 2; ++mt)
#pragma unroll
    for (int nt = 0; nt < 4; ++nt)
#pragma unroll
      for (int rr = 0; rr < 4; ++rr) {
        int gm = m0 + wm + mt * 16 + fq * 4 + rr;
        int gn = n0 + wn + nt * 16 + fm;
        if (gm < M) C[(long)gm * ldc + gn] = f2bf(acc[mt][nt][rr]);
      }
}

// ------------------------------------------------- gemm64 body (all-bf16) ---
// 64x64 tile, BK=32, 2x2 acc/wave. Pointers pre-offset by caller (batch z).
// If Ylds != nullptr: fp32 tile -> LDS (caller epilogue); Ylds may alias As/Bs.
#define LDS_S 40

__device__ __forceinline__ void gemm64_body(
    u16* As, u16* Bs,
    const u16* __restrict__ A16, const u16* __restrict__ B16,
    float* Cf, u16* Cb, float* Ylds,
    int M, int N, int K, int lda, int ldb, int ldc,
    int btrans, float alpha, int m0, int n0)
{
  const int tid = threadIdx.x;
  const int lane = tid & 63, wave = tid >> 6;
  const int wm = (wave >> 1) * 32, wn = (wave & 1) * 32;
  const int fm = lane & 15, fq = lane >> 4;
  const int ar = tid >> 2, ak = (tid & 3) * 8;
  const int bk = tid >> 3, bn = (tid & 7) * 8;

  f32x4 acc[2][2];
  const f32x4 zero4 = {0.f, 0.f, 0.f, 0.f};
#pragma unroll
  for (int a_ = 0; a_ < 2; ++a_)
#pragma unroll
    for (int b_ = 0; b_ < 2; ++b_) acc[a_][b_] = zero4;

  for (int k0 = 0; k0 < K; k0 += 32) {
    {
      int gm = m0 + ar, gk = k0 + ak;
      long idx = (long)gm * lda + gk;
      if (gm < M && gk + 8 <= K) {
        *(u32x4*)&As[ar * LDS_S + ak] = *(const u32x4*)(A16 + idx);
      } else {
#pragma unroll
        for (int e = 0; e < 8; ++e)
          As[ar * LDS_S + ak + e] = (gm < M && gk + e < K) ? A16[idx + e] : (u16)0;
      }
    }
    if (btrans) {
      int gn = n0 + ar, gk = k0 + ak;
      long idx = (long)gn * ldb + gk;
      if (gn < N && gk + 8 <= K) {
        *(u32x4*)&Bs[ar * LDS_S + ak] = *(const u32x4*)(B16 + idx);
      } else {
#pragma unroll
        for (int e = 0; e < 8; ++e)
          Bs[ar * LDS_S + ak + e] = (gn < N && gk + e < K) ? B16[idx + e] : (u16)0;
      }
    } else {
      int gk = k0 + bk;
      long idx = (long)gk * ldb + n0 + bn;
      u16 tmp[8];
      if (gk < K) {
        u32x4 v = *(const u32x4*)(B16 + idx);
        tmp[0] = (u16)(v.x & 0xffff); tmp[1] = (u16)(v.x >> 16);
        tmp[2] = (u16)(v.y & 0xffff); tmp[3] = (u16)(v.y >> 16);
        tmp[4] = (u16)(v.z & 0xffff); tmp[5] = (u16)(v.z >> 16);
        tmp[6] = (u16)(v.w & 0xffff); tmp[7] = (u16)(v.w >> 16);
      } else {
#pragma unroll
        for (int e = 0; e < 8; ++e) tmp[e] = 0;
      }
      int rot = tid & 7;  // spread LDS bank writes
#pragma unroll
      for (int e = 0; e < 8; ++e) {
        int ee = (e + rot) & 7;
        Bs[(bn + ee) * LDS_S + bk] = tmp[ee];
      }
    }
    __syncthreads();
    {
      bf16x8 fa[2], fb[2];
      fa[0] = *(const bf16x8*)&As[(wm +      fm) * LDS_S + fq * 8];
      fa[1] = *(const bf16x8*)&As[(wm + 16 + fm) * LDS_S + fq * 8];
      fb[0] = *(const bf16x8*)&Bs[(wn +      fm) * LDS_S + fq * 8];
      fb[1] = *(const bf16x8*)&Bs[(wn + 16 + fm) * LDS_S + fq * 8];
#pragma unroll
      for (int mt = 0; mt < 2; ++mt)
#pragma unroll
        for (int nt = 0; nt < 2; ++nt)
          acc[mt][nt] = __builtin_amdgcn_mfma_f32_16x16x32_bf16(fa[mt], fb[nt], acc[mt][nt], 0, 0, 0);
    }
    __syncthreads();
  }
  if (Ylds) {
    // all LDS reads complete past the final barrier; safe to overwrite As/Bs
#pragma unroll
    for (int mt = 0; mt < 2; ++mt)
#pragma unroll
      for (int nt = 0; nt < 2; ++nt)
#pragma unroll
        for (int rr = 0; rr < 4; ++rr)
          Ylds[(wm + mt * 16 + fq * 4 + rr) * 64 + (wn + nt * 16 + fm)] = acc[mt][nt][rr];
  } else {
#pragma unroll
    for (int mt = 0; mt < 2; ++mt)
#pragma unroll
      for (int nt = 0; nt < 2; ++nt)
#pragma unroll
        for (int rr = 0; rr < 4; ++rr) {
          int gm = m0 + wm + mt * 16 + fq * 4 + rr;
          int gn = n0 + wn + nt * 16 + fm;
          if (gm < M && gn < N) {
            float v = alpha * acc[mt][nt][rr];
            if (Cb) Cb[(long)gm * ldc + gn] = f2bf(v);
            else    Cf[(long)gm * ldc + gn] = v;
          }
        }
  }
}

// ---------- mg4: q/k/mid gemm64128s + Gram gemm + wbar (bf16), LDS union ----
// GEMM range [0,1142) is XCD-chunk swizzled (m204 bijective, 1142 = 8*142+6).
__global__ __launch_bounds__(256) void mg4_k(
    const u16* __restrict__ xb, const u16* __restrict__ wqt, u16* __restrict__ qbf,
    const u16* __restrict__ cbuf, const u16* __restrict__ wkt, u16* __restrict__ kbf,
    const u16* __restrict__ wvt, u16* __restrict__ midbf,
    const u16* __restrict__ wcvb, u16* __restrict__ Gb, float* __restrict__ wbar)
{
  __shared__ __attribute__((aligned(16))) char smem[24576];
  int bid = blockIdx.x;
  if (bid < 1142) {
    int xcd = bid & 7, idx = bid >> 3;
    int v = (xcd < 6 ? xcd * 143 : 858 + (xcd - 6) * 142) + idx;  // bijective
    const u16 *A, *B; u16* C; int M, N, lid, mx;
    if (v < 156)      { A = xb;   B = wqt; C = qbf;   M = 1664; N = 768;  lid = v;       mx = 26; }
    else if (v < 258) { A = cbuf; B = wkt; C = kbf;   M = 1028; N = 768;  lid = v - 156; mx = 17; }
    else              { A = cbuf; B = wvt; C = midbf; M = 1028; N = 6656; lid = v - 258; mx = 17; }
    int m0 = (lid % mx) * 64, n0 = (lid / mx) * 128;
    gemm64128_body((u16*)smem, (u16*)(smem + 8192), A, B, C, M, N, 768, 768, 768, N, m0, n0);
  } else if (bid < 1246) {
    int z = bid - 1142;   // 0..103: M[g] = Wconv_b[g] @ Wconv_b[g]^T / 768
    gemm64_body((u16*)smem, (u16*)(smem + 5120),
                wcvb + (long)z * 49152, wcvb + (long)z * 49152,
                nullptr, Gb + (long)z * 4096, nullptr,
                64, 64, 768, 768, 768, 64, 1, 1.f / 768.f, 0, 0);
  } else {
    // wbar: row means of bf16 Wconv copy, r = g*64+l over 768 cols
    int r = (bid - 1246) * 4 + (threadIdx.x >> 6);
    int lane = threadIdx.x & 63;
    const u16* prow = wcvb + (long)r * 768;
    float sm = 0.f;
    for (int c = lane; c < 768; c += 64) sm += bf2f(prow[c]);
#pragma unroll
    for (int o = 32; o; o >>= 1) sm += __shfl_xor(sm, o, 64);
    if (lane == 0) wbar[r] = sm * (1.f / 768.f);
  }
}

// ------------------------------ final: out_pre @ Wo^T (64x128 tiles) --------
// XCD-chunk swizzled (156 = 8*19+4).
__global__ __launch_bounds__(256) void gemmF_k(
    const u16* __restrict__ opbf, const u16* __restrict__ wot, u16* __restrict__ qbf)
{
  __shared__ __attribute__((aligned(16))) char smem[24576];
  int bid = blockIdx.x;
  int xcd = bid & 7, idx = bid >> 3;
  int lid = (xcd < 4 ? xcd * 20 : 80 + (xcd - 4) * 19) + idx;   // bijective
  gemm64128_body((u16*)smem, (u16*)(smem + 8192), opbf, wot, qbf,
                 1664, 768, 768, 768, 768, 768, (lid % 26) * 64, (lid / 26) * 128);
}

// --------------------- ysim: Y-gemm with fused stats epilogue + sim-gemm ----
__global__ __launch_bounds__(256) void ysim_k(
    const u16* __restrict__ midbf, const u16* __restrict__ Gb,
    const float* __restrict__ wbar, u16* __restrict__ midi, float* __restrict__ pim,
    const u16* __restrict__ qbf, const u16* __restrict__ kbf, float* __restrict__ simf)
{
  __shared__ __attribute__((aligned(16))) char smem[16384];
  u16* As = (u16*)smem;
  u16* Bs = (u16*)(smem + 8192);
  int bid = blockIdx.x;
  if (bid < 1768) {
    // Y = mid_g[1028x64] @ M[g]^T -> fp32 tile in LDS, then stats epilogue
    int g = bid / 17, bx = bid % 17;
    int m0 = bx * 64;
    float* Ylds = (float*)smem;   // aliases As/Bs (dead after final barrier)
    gemm64_body(As, Bs, midbf + (long)g * 64, Gb + (long)g * 4096,
                nullptr, nullptr, Ylds,
                1028, 64, 64, 6656, 64, 64, 1, 1.f, m0, 0);
    __syncthreads();
    int tid = threadIdx.x, lane = tid & 63, wave = tid >> 6;
#pragma unroll
    for (int rr = 0; rr < 16; ++rr) {
      int r = wave * 16 + rr;          // local row
      int gr = m0 + r;                 // global row (wave-uniform)
      if (gr < 1028) {
        float m  = bf2f(midbf[(long)gr * 6656 + g * 64 + lane]);
        float y  = Ylds[r * 64 + lane];
        float wb = wbar[g * 64 + lane];
        float mup = m * wb, q2p = m * y;
#pragma unroll
        for (int o = 32; o; o >>= 1) { mup += __shfl_xor(mup, o, 64); q2p += __shfl_xor(q2p, o, 64); }
        float var = q2p - mup * mup;
        float inv = rsqrtf(fmaxf(var, 0.f) + 1e-5f);
        int b = gr / 257, j = gr - b * 257;
        long zidx = (long)b * 104 + g;
        midi[(zidx * 264 + j) * 64 + lane] = f2bf(inv * m);
        if (lane == 0) pim[zidx * 257 + j] = inv * mup;
      }
    }
  } else {
    // sim = scale^2 * q @ k^T;  z = b*6+h
    int lid = bid - 1768; int z = lid / 35, r = lid % 35, bx = r % 7, by = r / 7;
    const u16* A = qbf + (long)(z / 6) * 319488 + (long)(z % 6) * 128;
    const u16* B = kbf + (long)(z / 6) * 197376 + (long)(z % 6) * 128;
    float* Cf = simf + (long)z * 106912;
    gemm64_body(As, Bs, A, B, Cf, nullptr, nullptr,
                416, 257, 128, 768, 768, 257, 1, 0.08838834764831845f, bx * 64, by * 64);
  }
}

// --------------------------------------------------- ct: c-gemm + T-gemm ----
__global__ __launch_bounds__(256) void ct_k(
    const u16* __restrict__ Abf, const u16* __restrict__ ctxT, float* __restrict__ c_buf,
    const u16* __restrict__ A2bf, const u16* __restrict__ midi, u16* __restrict__ Tb16)
{
  __shared__ __attribute__((aligned(16))) u16 As[64 * LDS_S];
  __shared__ __attribute__((aligned(16))) u16 Bs[64 * LDS_S];
  int bid = blockIdx.x;
  if (bid < 336) {
    // c = A @ ctx_head (btrans via ctx^T, K=264); z = b*6+h
    int z = bid / 14, r = bid % 14, bx = r % 7, by = r / 7;
    const u16* A = Abf + (long)z * 109824;
    const u16* B = ctxT + (long)(z / 6) * 202752 + (long)(z % 6) * 33792;
    float* Cf = c_buf + (long)z * 53248;
    gemm64_body(As, Bs, A, B, Cf, nullptr, nullptr,
                416, 128, 264, 264, 264, 128, 1, 1.f, bx * 64, by * 64);
  } else {
    // T = A2 @ midi (non-trans, K=264, 264-row-padded midi); z = b*104+g
    int z = bid - 336;
    const u16* A = A2bf + (long)z * 6336;
    const u16* B = midi + (long)z * 16896;
    u16* Cb = Tb16 + (long)z * 1536;
    gemm64_body(As, Bs, A, B, nullptr, Cb, nullptr,
                24, 64, 264, 264, 64, 64, 0, 1.f, 0, 0);
  }
}

// ------------------------------------------------------------- row LN -------
__device__ __forceinline__ void ln_row(
    const u16* __restrict__ ip, const void* __restrict__ g, const void* __restrict__ b,
    u16* __restrict__ ob, float* __restrict__ of, int N, int f)
{
  int tid = threadIdx.x, lane = tid & 63, wave = tid >> 6;
  const int nv = N >> 3;
  float s1 = 0.f, s2 = 0.f;
  for (int c8 = tid; c8 < nv; c8 += 256) {
    u32x4 v = *(const u32x4*)(ip + c8 * 8);
    float e0 = bf2f((u16)(v.x & 0xffff)), e1 = bf2f((u16)(v.x >> 16));
    float e2 = bf2f((u16)(v.y & 0xffff)), e3 = bf2f((u16)(v.y >> 16));
    float e4 = bf2f((u16)(v.z & 0xffff)), e5 = bf2f((u16)(v.z >> 16));
    float e6 = bf2f((u16)(v.w & 0xffff)), e7 = bf2f((u16)(v.w >> 16));
    s1 += ((e0 + e1) + (e2 + e3)) + ((e4 + e5) + (e6 + e7));
    s2 += ((e0*e0 + e1*e1) + (e2*e2 + e3*e3)) + ((e4*e4 + e5*e5) + (e6*e6 + e7*e7));
  }
#pragma unroll
  for (int o = 32; o; o >>= 1) { s1 += __shfl_xor(s1, o, 64); s2 += __shfl_xor(s2, o, 64); }
  __shared__ float red[8];
  if (lane == 0) { red[wave] = s1; red[4 + wave] = s2; }
  __syncthreads();
  s1 = red[0] + red[1] + red[2] + red[3];
  s2 = red[4] + red[5] + red[6] + red[7];
  float mean = s1 / N;
  float var = s2 / N - mean * mean;
  float rstd = rsqrtf(fmaxf(var, 0.f) + 1e-5f);
  for (int c8 = tid; c8 < nv; c8 += 256) {
    int c = c8 * 8;
    u32x4 v = *(const u32x4*)(ip + c);
    float e[8];
    e[0] = bf2f((u16)(v.x & 0xffff)); e[1] = bf2f((u16)(v.x >> 16));
    e[2] = bf2f((u16)(v.y & 0xffff)); e[3] = bf2f((u16)(v.y >> 16));
    e[4] = bf2f((u16)(v.z & 0xffff)); e[5] = bf2f((u16)(v.z >> 16));
    e[6] = bf2f((u16)(v.w & 0xffff)); e[7] = bf2f((u16)(v.w >> 16));
    float gg[8], bb[8];
    if (f) {
      const float* gp = (const float*)g + c; const float* bp = (const float*)b + c;
      f32x4 g0 = *(const f32x4*)gp, g1 = *(const f32x4*)(gp + 4);
      f32x4 b0 = *(const f32x4*)bp, b1 = *(const f32x4*)(bp + 4);
      gg[0]=g0.x; gg[1]=g0.y; gg[2]=g0.z; gg[3]=g0.w; gg[4]=g1.x; gg[5]=g1.y; gg[6]=g1.z; gg[7]=g1.w;
      bb[0]=b0.x; bb[1]=b0.y; bb[2]=b0.z; bb[3]=b0.w; bb[4]=b1.x; bb[5]=b1.y; bb[6]=b1.z; bb[7]=b1.w;
    } else {
      u32x4 gv = *(const u32x4*)((const u16*)g + c);
      u32x4 bv = *(const u32x4*)((const u16*)b + c);
      gg[0]=bf2f((u16)(gv.x&0xffff)); gg[1]=bf2f((u16)(gv.x>>16));
      gg[2]=bf2f((u16)(gv.y&0xffff)); gg[3]=bf2f((u16)(gv.y>>16));
      gg[4]=bf2f((u16)(gv.z&0xffff)); gg[5]=bf2f((u16)(gv.z>>16));
      gg[6]=bf2f((u16)(gv.w&0xffff)); gg[7]=bf2f((u16)(gv.w>>16));
      bb[0]=bf2f((u16)(bv.x&0xffff)); bb[1]=bf2f((u16)(bv.x>>16));
      bb[2]=bf2f((u16)(bv.y&0xffff)); bb[3]=bf2f((u16)(bv.y>>16));
      bb[4]=bf2f((u16)(bv.z&0xffff)); bb[5]=bf2f((u16)(bv.z>>16));
      bb[6]=bf2f((u16)(bv.w&0xffff)); bb[7]=bf2f((u16)(bv.w>>16));
    }
    float o_[8];
#pragma unroll
    for (int e2i = 0; e2i < 8; ++e2i) o_[e2i] = (e[e2i] - mean) * rstd * gg[e2i] + bb[e2i];
    if (of) {
      f32x4 o0 = {o_[0], o_[1], o_[2], o_[3]}, o1 = {o_[4], o_[5], o_[6], o_[7]};
      *(f32x4*)(of + c) = o0; *(f32x4*)(of + c + 4) = o1;
    } else {
      u32x4 q = { (u32)f2bf(o_[0]) | ((u32)f2bf(o_[1]) << 16),
                  (u32)f2bf(o_[2]) | ((u32)f2bf(o_[3]) << 16),
                  (u32)f2bf(o_[4]) | ((u32)f2bf(o_[5]) << 16),
                  (u32)f2bf(o_[6]) | ((u32)f2bf(o_[7]) << 16) };
      *(u32x4*)(ob + c) = q;
    }
  }
}

__global__ __launch_bounds__(256) void ln_rows(
    const u16* __restrict__ in, const void* __restrict__ g, const void* __restrict__ b,
    void* __restrict__ out, int N, const int* __restrict__ dtf, int isfinal, int fknown)
{
  const int f = (fknown >= 0) ? fknown : dtf[0];
  long row = blockIdx.x;
  const u16* ip = in + row * N;
  float* of = (isfinal && f) ? (float*)out + row * N : nullptr;
  u16*   ob = of ? nullptr : (u16*)out + row * N;
  ln_row(ip, g, b, ob, of, N, f);
}

// merged LN for q (1664x768), k (1028x768), mid (1028x6656)
__global__ __launch_bounds__(256) void mln3_k(
    u16* __restrict__ qb, const void* __restrict__ gq, const void* __restrict__ bq,
    u16* __restrict__ kb, const void* __restrict__ gk, const void* __restrict__ bk,
    u16* __restrict__ mb, const void* __restrict__ gv, const void* __restrict__ bv,
    const int* __restrict__ dtf, int fknown)
{
  const int f = (fknown >= 0) ? fknown : dtf[0];
  int row = blockIdx.x;
  u16* ip; const void *g, *b; int N;
  if (row < 1664)      { ip = qb + (long)row * 768; g = gq; b = bq; N = 768; }
  else if (row < 2692) { ip = kb + (long)(row - 1664) * 768; g = gk; b = bk; N = 768; }
  else                 { ip = mb + (long)(row - 2692) * 6656; g = gv; b = bv; N = 6656; }
  ln_row(ip, g, b, ip, nullptr, N, f);
}

// ------------------------------------------------------------- softmax ------
__global__ __launch_bounds__(256) void softmax_k(
    const float* __restrict__ simf, const float* __restrict__ pim,
    u16* __restrict__ Abf, u16* __restrict__ A2bf, float* __restrict__ s_sh)
{
  int bh = blockIdx.x;
  int b = bh / 6, h = bh - b * 6;
  int tid = threadIdx.x, lane = tid & 63, wave = tid >> 6;
  int i = blockIdx.y * 4 + wave;
  int g = i % 104, rq = i / 104;
  const float* sp_ = simf + ((long)bh * 416 + i) * 257;
  float s[5];
#pragma unroll
  for (int jc = 0; jc < 5; ++jc) {
    int j = jc * 64 + lane;
    s[jc] = (j < 257) ? sp_[j] : -1e30f;
  }
  float mx = -1e30f;
#pragma unroll
  for (int jc = 0; jc < 5; ++jc) mx = fmaxf(mx, s[jc]);
#pragma unroll
  for (int o = 32; o; o >>= 1) mx = fmaxf(mx, __shfl_xor(mx, o, 64));
  float p[5], sum = 0.f, sp = 0.f;
  long pimb = ((long)b * 104 + g) * 257;
#pragma unroll
  for (int jc = 0; jc < 5; ++jc) {
    int j = jc * 64 + lane;
    float pv = 0.f;
    if (j < 257) { pv = __expf(s[jc] - mx); sp = fmaf(pv, pim[pimb + j], sp); }
    p[jc] = pv; sum += pv;
  }
#pragma unroll
  for (int o = 32; o; o >>= 1) { sum += __shfl_xor(sum, o, 64); sp += __shfl_xor(sp, o, 64); }
  float rs = 1.f / sum;
  long arow  = ((long)bh * 416 + i) * 264;
  long a2row = (((long)b * 104 + g) * 24 + h * 4 + rq) * 264;
#pragma unroll
  for (int jc = 0; jc < 5; ++jc) {
    int j = jc * 64 + lane;
    if (j < 257) { u16 pb = f2bf(p[jc] * rs); Abf[arow + j] = pb; A2bf[a2row + j] = pb; }
    else if (j < 264) { Abf[arow + j] = 0; A2bf[a2row + j] = 0; }
  }
  if (lane == 0) s_sh[(long)bh * 416 + i] = sp * rs;
}

// -------------------------------------------------- fused O-gemm + combine --
__global__ __launch_bounds__(256) void oc_k(
    const u16* __restrict__ T, const u16* __restrict__ Wb,
    const float* __restrict__ s_sh, const float* __restrict__ c_buf,
    const void* __restrict__ gv2, const void* __restrict__ bv2,
    u16* __restrict__ opbf, const int* __restrict__ dtf, int fknown)
{
  const int f = (fknown >= 0) ? fknown : dtf[0];
  int z = blockIdx.x;                 // b*104+g
  int b = z / 104, g = z - b * 104;
  int tid = threadIdx.x;
  __shared__ float Ts[24][64];        // 6 KB
  const u16* tp = T + (long)z * 1536;
  for (int idx = tid; idx < 1536; idx += 256) Ts[idx >> 6][idx & 63] = bf2f(tp[idx]);
  __syncthreads();
  const int dh = tid & 127;
  const int hbase = (tid >> 7) * 3;   // threads 0..127 -> h 0..2, 128..255 -> h 3..5
  const u16* wg = Wb + (long)g * 49152;
#pragma unroll
  for (int hh = 0; hh < 3; ++hh) {
    int h = hbase + hh;
    int d = h * 128 + dh;
    const u16* wp = wg + d;
    float a0 = 0.f, a1 = 0.f, a2 = 0.f, a3 = 0.f;
#pragma unroll 16
    for (int k = 0; k < 64; ++k) {
      float w = bf2f(wp[(long)k * 768]);
      a0 = fmaf(Ts[h * 4 + 0][k], w, a0);
      a1 = fmaf(Ts[h * 4 + 1][k], w, a1);
      a2 = fmaf(Ts[h * 4 + 2][k], w, a2);
      a3 = fmaf(Ts[h * 4 + 3][k], w, a3);
    }
    float acc[4] = {a0, a1, a2, a3};
    float gvd = gld(gv2, d, f), bvd = gld(bv2, d, f);
#pragma unroll
    for (int rq = 0; rq < 4; ++rq) {
      int i = rq * 104 + g;
      float ssh = s_sh[((long)b * 6 + h) * 416 + i];
      float val = gvd * (acc[rq] - ssh) + bvd
                + c_buf[(((long)b * 6 + h) * 416 + i) * 128 + dh];
      opbf[((long)b * 416 + i) * 768 + d] = f2bf(val);
    }
  }
}

// ---------------------------------------------------------------- host ------
extern "C" void kernel_launch(void* const* d_in, const int* in_sizes, int n_in,
                              void* d_out, int out_size, void* d_ws, size_t ws_size,
                              hipStream_t stream)
{
  const void* x   = d_in[0];
  const void* ctx = d_in[1];
  const void* Wq  = d_in[2];
  const void* gq  = d_in[3];
  const void* bq  = d_in[4];
  const void* Wk  = d_in[5];
  const void* gk  = d_in[6];
  const void* bk  = d_in[7];
  const void* Wv  = d_in[8];
  const void* gv1 = d_in[9];
  const void* bv1 = d_in[10];
  const void* Wcv = d_in[11];
  const void* gv2 = d_in[12];
  const void* bv2 = d_in[13];
  const void* Wo  = d_in[14];
  const void* go  = d_in[15];
  const void* bo  = d_in[16];

  // -------- workspace layout --------
  const size_t SZ_FLAG = 256;
  const size_t SZ_QBF  = 2555904;
  const size_t SZ_KBF  = 1579008;
  const size_t SZ_MID  = 13684736;
  const size_t SZ_MM   = 1703936;
  const size_t SZ_WB   = 26624;
  const size_t SZ_MIDI = 14057472;   // 416 * 264 * 64 bf16 (264-row padded)
  const size_t SZ_PIM  = 427648;
  const size_t SZ_ABF  = 5271552;
  const size_t SZ_A2   = 5271552;
  const size_t SZ_SSH  = 39936;
  const size_t SZ_CB   = 1579008;
  const size_t SZ_WCVB = 10223616;   // 104*64*768 bf16
  const size_t SZ_WT   = 1179648;    // 768*768 bf16 (x3: WqT, WkT, WoT)
  const size_t SZ_WVT  = 10223616;   // 6656*768 bf16
  const size_t SZ_CTXT = 1622016;    // 4*768*264 bf16 (ctx^T, zero-padded cols)
  const size_t SZ_SIMF = 10263552;   // 24*416*257 fp32
  const size_t REQUIRED = SZ_FLAG + SZ_QBF + SZ_KBF + SZ_MID + SZ_MM + SZ_WB +
                          SZ_MIDI + SZ_PIM + SZ_ABF + SZ_A2 + SZ_SSH + SZ_CB +
                          SZ_WCVB + 3 * SZ_WT + SZ_WVT + SZ_CTXT + SZ_SIMF;  // 82,069,376

  if (ws_size < REQUIRED) {
    fill_k<<<(out_size + 255) / 256, 256, 0, stream>>>((u16*)d_out, (float)(ws_size >> 20), out_size);
    return;
  }

  char* p = (char*)d_ws;
  int*   dtf   = (int*)  p;                 p += SZ_FLAG;
  u16*   qbf   = (u16*)  p;                 p += SZ_QBF;
  u16*   kbf   = (u16*)  p;                 p += SZ_KBF;
  char*  midrg = p;                         p += SZ_MID;
  char*  mmrg  = p;                         p += SZ_MM;
  float* wbar  = (float*)p;                 p += SZ_WB;
  u16*   midi  = (u16*)  p;                 p += SZ_MIDI;
  float* pim   = (float*)p;                 p += SZ_PIM;
  char*  abfrg = p;                         p += SZ_ABF;
  u16*   A2bf  = (u16*)  p;                 p += SZ_A2;
  float* s_sh  = (float*)p;                 p += SZ_SSH;
  u16*   cb    = (u16*)  p;                 p += SZ_CB;
  u16*   wcvb  = (u16*)  p;                 p += SZ_WCVB;
  u16*   wqt2  = (u16*)  p;                 p += SZ_WT;
  u16*   wkt2  = (u16*)  p;                 p += SZ_WT;
  u16*   wot2  = (u16*)  p;                 p += SZ_WT;
  u16*   wvt   = (u16*)  p;                 p += SZ_WVT;
  u16*   ctxT  = (u16*)  p;                 p += SZ_CTXT;
  float* simf  = (float*)p;                 p += SZ_SIMF;

  u16*   midbf = (u16*)midrg;
  float* c_buf = (float*)midrg;             // midbf dead after ysim stats
  u16*   Tb16  = (u16*)(midrg + 5111808);   // right after c_buf's 5,111,808 B
  u16*   Gb    = (u16*)mmrg;
  u16*   xb    = (u16*)abfrg;
  u16*   Abf   = (u16*)abfrg;
  u16*   opbf  = (u16*)abfrg;               // Abf dead after ct_k

  // host-side dtype: in_sizes[0] in bytes distinguishes fp32 (5,111,808) from
  // bf16 (2,555,904); anything else (e.g. element count) -> probe fallback.
  int fknown = -1;
  if (in_sizes && n_in > 0) {
    if (in_sizes[0] == 5111808)      fknown = 1;
    else if (in_sizes[0] == 2555904) fknown = 0;
  }
  if (fknown < 0) probe_k<<<1, 256, 0, stream>>>((const u32*)x, dtf);

  // prep: copies + midi pad zero (3597) | transposes (7584)
  prep_k<<<11181, 256, 0, stream>>>(x, xb, ctx, cb, Wcv, wcvb, midi,
                                    Wq, Wk, Wo, Wv, wqt2, wkt2, wot2, wvt, ctxT,
                                    dtf, fknown);

  // q/k/mid gemm64128s BK=64 (1142, XCD-chunk swizzled) + Gram (104) + wbar (1664)
  mg4_k<<<2910, 256, 0, stream>>>(xb, wqt2, qbf, cb, wkt2, kbf, wvt, midbf,
                                  wcvb, Gb, wbar);

  // q/k/mid LNs
  mln3_k<<<3720, 256, 0, stream>>>(qbf, gq, bq, kbf, gk, bk, midbf, gv1, bv1,
                                   dtf, fknown);

  // Y = mid_g @ M[g] with fused stats epilogue (1768) + sim (840)
  ysim_k<<<2608, 256, 0, stream>>>(midbf, Gb, wbar, midi, pim, qbf, kbf, simf);

  softmax_k<<<dim3(24, 104), 256, 0, stream>>>(simf, pim, Abf, A2bf, s_sh);

  // c = A @ ctx_head (336) + T = A2 @ midi (416)
  ct_k<<<752, 256, 0, stream>>>(Abf, ctxT, c_buf, A2bf, midi, Tb16);

  // fused O-gemm + combine
  oc_k<<<416, 256, 0, stream>>>(Tb16, wcvb, s_sh, c_buf, gv2, bv2, opbf, dtf, fknown);

  // out = LN(out_pre @ Wo): 64x128 tiles BK=64, XCD-chunk swizzled
  gemmF_k<<<156, 256, 0, stream>>>(opbf, wot2, qbf);
  ln_rows<<<1664, 256, 0, stream>>>(qbf, go, bo, d_out, 768, dtf, 1, fknown);
}

// Round 14
// 258.902 us; speedup vs baseline: 3.1194x; 1.0063x over previous
//
#include <hip/hip_runtime.h>

// SubjBasisGenerator fused pipeline. B=4 NQ=416 NC=257 D=768 H=6 DH=128 G=104 R=4 LORA=64
// R24: prep transposes retiled 32x32 -> 64x64 (blocks 7584->1920, 16 elem/thr,
//      s[64][65] bank-clean). Per-element math/guards identical. R21-R23 showed
//      all phases latency-bound 2-4x above floor; this is the last low-risk
//      block-amortization lever.
// R23: BK 32->64 in gemm64128 (dual half-panels, bitwise-identical).
// R22: T1 XCD-chunked bijective swizzle in mg4+gemmF (FETCH 73->24MB, dur flat
//      -> limiter is K-loop latency, not locality).
// R21: gemm64128 retile (64x128): occupancy 25->44%, 273->262us.
// R20: wbar in mg4 (bf16); host-side dtype from in_sizes[0] (probe fallback).
// R16: stats2 fused into Y-gemm epilogue. R14: dispatch 16->11.
// R13/R12: merged gemms/LNs/transposes, ctx^T fast path, K padded 264.
// R11: oc_k fusion, Wconv bf16 pre-convert.
//
// Algebra: the grouped-conv+LN v-path decomposes exactly:
//   sum_j A_j v_j = gv2*( (sum_j A_j inv_j mid_j)@Wconv[g] - sum_j A_j inv_j mu_j )
//                   + bv2 + (A @ ctx)
//   q2[b,g,j] = mid^T M[g] mid = mid . (M[g] @ mid),  M[g] = Wconv[g]Wconv[g]^T/768

typedef unsigned short u16;
typedef unsigned int   u32;
typedef __attribute__((ext_vector_type(4))) float f32x4;
typedef __attribute__((ext_vector_type(4))) u32   u32x4;
typedef __attribute__((ext_vector_type(8))) short bf16x8;

__device__ __forceinline__ float bf2f(u16 v) { return __uint_as_float(((u32)v) << 16); }
__device__ __forceinline__ u16 f2bf(float f) {
  u32 u = __float_as_uint(f);
  u32 r = u + 0x7fffu + ((u >> 16) & 1u);  // RNE
  return (u16)(r >> 16);
}
__device__ __forceinline__ float gld(const void* p, long idx, int f32) {
  return f32 ? ((const float*)p)[idx] : bf2f(((const u16*)p)[idx]);
}

typedef const __attribute__((address_space(1))) u32 gas_u32;
typedef __attribute__((address_space(3))) u32 las_u32;

// async 16B/lane global->LDS; LDS dest = wave-uniform base + lane*16 (m97).
__device__ __forceinline__ void stage16(const u16* g, u16* lbase, int lane) {
#if __has_builtin(__builtin_amdgcn_global_load_lds)
  (void)lane;
  __builtin_amdgcn_global_load_lds((gas_u32*)g, (las_u32*)lbase, 16, 0, 0);
#else
  *(u32x4*)(lbase + lane * 8) = *(const u32x4*)g;
#endif
}

// ------------------------------------------------------------ dtype probe ---
__global__ __launch_bounds__(256) void probe_k(const u32* __restrict__ xw, int* __restrict__ flag) {
  int tid = threadIdx.x, c = 0;
  for (int i = tid; i < 4096; i += 256) {
    u16 lo = (u16)(xw[i] & 0xffffu);
    float a = fabsf(bf2f(lo));
    if (lo == 0 || (a >= 1e-3f && a <= 32.f)) ++c;
  }
#pragma unroll
  for (int o = 32; o; o >>= 1) c += __shfl_xor(c, o, 64);
  __shared__ int r[4];
  if ((tid & 63) == 0) r[tid >> 6] = c;
  __syncthreads();
  if (tid == 0) flag[0] = (r[0] + r[1] + r[2] + r[3] >= 2048) ? 0 : 1;  // 1 = fp32
}

// ------------------------------------------------------------ diag fill -----
__global__ __launch_bounds__(256) void fill_k(u16* p, float v, int n) {
  int i = blockIdx.x * 256 + threadIdx.x;
  if (i < n) p[i] = f2bf(v);
}

// --------------------------------------------------------------- prep_k -----
// blocks [0,3597): ext->bf16 copies (x, ctx, Wconv) + midi pad-row zeroing
// blocks [3597,5517): 64x64 transposes — Wq/Wk/Wo (432), Wv (1248), ctxT (240)
__global__ __launch_bounds__(256) void prep_k(
    const void* __restrict__ x,   u16* __restrict__ xb,
    const void* __restrict__ ctx, u16* __restrict__ cbuf,
    const void* __restrict__ Wcv, u16* __restrict__ wcvb,
    u16* __restrict__ midi,
    const void* __restrict__ Wq, const void* __restrict__ Wk,
    const void* __restrict__ Wo, const void* __restrict__ Wv,
    u16* __restrict__ wqt, u16* __restrict__ wkt, u16* __restrict__ wot,
    u16* __restrict__ wvt, u16* __restrict__ ctxT,
    const int* __restrict__ dtf, int fknown)
{
  const int f = (fknown >= 0) ? fknown : dtf[0];
  int bid = blockIdx.x;
  if (bid < 3597) {
    // ---- convb4 ----
    const long n0_ = 1277952, n1_ = 789504, n2_ = 5111808, n3_ = 186368;
    long i = ((long)bid * 256 + threadIdx.x) * 8;
    const long t0 = n0_, t1 = t0 + n1_, t2 = t1 + n2_, t3 = t2 + n3_;
    if (i >= t3) return;
    if (i >= t2) {
      long e = i - t2;                 // zero 7 pad rows per midi z-block
      long z = e / 448, off = e - z * 448;
      u32x4 zz = {0u, 0u, 0u, 0u};
      *(u32x4*)(midi + z * 16896 + 16448 + off) = zz;
      return;
    }
    const void* in; u16* out;
    if (i < t0)      { in = x;    out = xb; }
    else if (i < t1) { in = ctx;  out = cbuf; i -= t0; }
    else             { in = Wcv;  out = wcvb; i -= t1; }
    if (f) {
      const float* ip = (const float*)in + i;
      f32x4 a = *(const f32x4*)ip, b = *(const f32x4*)(ip + 4);
      u32x4 q = { (u32)f2bf(a.x) | ((u32)f2bf(a.y) << 16),
                  (u32)f2bf(a.z) | ((u32)f2bf(a.w) << 16),
                  (u32)f2bf(b.x) | ((u32)f2bf(b.y) << 16),
                  (u32)f2bf(b.z) | ((u32)f2bf(b.w) << 16) };
      *(u32x4*)(out + i) = q;
    } else {
      *(u32x4*)(out + i) = *(const u32x4*)((const u16*)in + i);
    }
  } else {
    // ---- transM: 64x64 tiles ----
    __shared__ float s[64][65];        // 16.9 KB; stride-65 reads 2-way (free)
    int t = bid - 3597;
    const void* in; u16* out;
    int inK, inN, ldo, outK, nx;
    long inBase = 0, outBase = 0;
    if (t < 432) {                     // 3 x 768x768 weights: 144 tiles each
      int w = t / 144; t -= w * 144;
      in  = w == 0 ? Wq : w == 1 ? Wk : Wo;
      out = w == 0 ? wqt : w == 1 ? wkt : wot;
      inK = 768; inN = 768; ldo = 768; outK = 768; nx = 12;
    } else if (t < 1680) {             // Wv 768x6656: 104 n-tiles x 12 k-tiles
      t -= 432;
      in = Wv; out = wvt;
      inK = 768; inN = 6656; ldo = 768; outK = 768; nx = 104;
    } else {                           // ctxT: 4 b x (12 n-tiles x 5 k-tiles)
      t -= 1680;
      int b = t / 60; t -= b * 60;
      in = ctx; out = ctxT;
      inK = 257; inN = 768; ldo = 264; outK = 264; nx = 12;
      inBase = (long)b * 257 * 768; outBase = (long)b * 768 * 264;
    }
    int n0 = (t % nx) * 64, k0 = (t / nx) * 64;
    int tx = threadIdx.x & 63, ty = threadIdx.x >> 6;  // 64 x 4
#pragma unroll
    for (int i = 0; i < 64; i += 4) {
      int k = k0 + i + ty, n = n0 + tx;
      float v = 0.f;
      if (k < inK && n < inN) v = gld(in, inBase + (long)k * inN + n, f);
      s[i + ty][tx] = v;
    }
    __syncthreads();
#pragma unroll
    for (int i = 0; i < 64; i += 4) {
      int n = n0 + i + ty, k = k0 + tx;
      if (n < inN && k < outK) out[outBase + (long)n * ldo + k] = f2bf(s[tx][i + ty]);
    }
  }
}

// ----------------------------------------------------------- gemm64128 ------
// C_bf16 = A[M,K] @ B[N,K]^T, tile 64(M) x 128(N), BK=64 via dual half-panels
// (As = 2 x [64][32], Bs = 2 x [128][32]): 6 stage16 / one vmcnt drain /
// 16 MFMA / one barrier per iter. h-loop in increasing-k order -> accumulation
// sequence identical to BK=32 -> bitwise-identical outputs. Requires K%64==0.
__device__ __forceinline__ void gemm64128_body(
    u16* As, u16* Bs,
    const u16* __restrict__ A, const u16* __restrict__ B, u16* __restrict__ C,
    int M, int N, int K, int lda, int ldb, int ldc, int m0, int n0)
{
  const int tid = threadIdx.x, lane = tid & 63, wave = tid >> 6;
  const int wm = (wave >> 1) * 32, wn = (wave & 1) * 64;
  const int fm = lane & 15, fq = lane >> 4;
  const int srow = lane >> 2, selem = (lane & 3) * 8;

  int ra = m0 + wave * 16 + srow;      if (ra > M - 1) ra = M - 1;
  const int rb1 = n0 + wave * 16 + srow;
  const int rb2 = n0 + 64 + wave * 16 + srow;
  const u16* pa  = A + (long)ra * lda + selem;
  const u16* pb1 = B + (long)rb1 * ldb + selem;
  const u16* pb2 = B + (long)rb2 * ldb + selem;
  u16* la  = As + wave * 512;          // As half 0; half 1 at +2048
  u16* lb1 = Bs + wave * 512;          // Bs half 0 rows 0-63; half 1 at +4096
  u16* lb2 = Bs + 2048 + wave * 512;   // Bs half 0 rows 64-127

  f32x4 acc[2][4];
  const f32x4 zero4 = {0.f, 0.f, 0.f, 0.f};
#pragma unroll
  for (int a_ = 0; a_ < 2; ++a_)
#pragma unroll
    for (int b_ = 0; b_ < 4; ++b_) acc[a_][b_] = zero4;

  for (int k0 = 0; k0 < K; k0 += 64) {
    stage16(pa,       la,        lane);
    stage16(pb1,      lb1,       lane);
    stage16(pb2,      lb2,       lane);
    stage16(pa  + 32, la + 2048, lane);
    stage16(pb1 + 32, lb1 + 4096, lane);
    stage16(pb2 + 32, lb2 + 4096, lane);
    pa += 64; pb1 += 64; pb2 += 64;
    __syncthreads();
#pragma unroll
    for (int h = 0; h < 2; ++h) {
      const u16* Ah = As + h * 2048;
      const u16* Bh = Bs + h * 4096;
      bf16x8 fa[2], fb[4];
#pragma unroll
      for (int mt = 0; mt < 2; ++mt)
        fa[mt] = *(const bf16x8*)&Ah[(wm + mt * 16 + fm) * 32 + fq * 8];
#pragma unroll
      for (int nt = 0; nt < 4; ++nt)
        fb[nt] = *(const bf16x8*)&Bh[(wn + nt * 16 + fm) * 32 + fq * 8];
#pragma unroll
      for (int mt = 0; mt < 2; ++mt)
#pragma unroll
        for (int nt = 0; nt < 4; ++nt)
          acc[mt][nt] = __builtin_amdgcn_mfma_f32_16x16x32_bf16(fa[mt], fb[nt], acc[mt][nt], 0, 0, 0);
    }
    __syncthreads();
  }
  // C/D layout: col=lane&15, row=(lane>>4)*4+reg (m89-verified)
#pragma unroll
  for (int mt = 0; mt < 2; ++mt)
#pragma unroll
    for (int nt = 0; nt < 4; ++nt)
#pragma unroll
      for (int rr = 0; rr < 4; ++rr) {
        int gm = m0 + wm + mt * 16 + fq * 4 + rr;
        int gn = n0 + wn + nt * 16 + fm;
        if (gm < M) C[(long)gm * ldc + gn] = f2bf(acc[mt][nt][rr]);
      }
}

// ------------------------------------------------- gemm64 body (all-bf16) ---
// 64x64 tile, BK=32, 2x2 acc/wave. Pointers pre-offset by caller (batch z).
// If Ylds != nullptr: fp32 tile -> LDS (caller epilogue); Ylds may alias As/Bs.
#define LDS_S 40

__device__ __forceinline__ void gemm64_body(
    u16* As, u16* Bs,
    const u16* __restrict__ A16, const u16* __restrict__ B16,
    float* Cf, u16* Cb, float* Ylds,
    int M, int N, int K, int lda, int ldb, int ldc,
    int btrans, float alpha, int m0, int n0)
{
  const int tid = threadIdx.x;
  const int lane = tid & 63, wave = tid >> 6;
  const int wm = (wave >> 1) * 32, wn = (wave & 1) * 32;
  const int fm = lane & 15, fq = lane >> 4;
  const int ar = tid >> 2, ak = (tid & 3) * 8;
  const int bk = tid >> 3, bn = (tid & 7) * 8;

  f32x4 acc[2][2];
  const f32x4 zero4 = {0.f, 0.f, 0.f, 0.f};
#pragma unroll
  for (int a_ = 0; a_ < 2; ++a_)
#pragma unroll
    for (int b_ = 0; b_ < 2; ++b_) acc[a_][b_] = zero4;

  for (int k0 = 0; k0 < K; k0 += 32) {
    {
      int gm = m0 + ar, gk = k0 + ak;
      long idx = (long)gm * lda + gk;
      if (gm < M && gk + 8 <= K) {
        *(u32x4*)&As[ar * LDS_S + ak] = *(const u32x4*)(A16 + idx);
      } else {
#pragma unroll
        for (int e = 0; e < 8; ++e)
          As[ar * LDS_S + ak + e] = (gm < M && gk + e < K) ? A16[idx + e] : (u16)0;
      }
    }
    if (btrans) {
      int gn = n0 + ar, gk = k0 + ak;
      long idx = (long)gn * ldb + gk;
      if (gn < N && gk + 8 <= K) {
        *(u32x4*)&Bs[ar * LDS_S + ak] = *(const u32x4*)(B16 + idx);
      } else {
#pragma unroll
        for (int e = 0; e < 8; ++e)
          Bs[ar * LDS_S + ak + e] = (gn < N && gk + e < K) ? B16[idx + e] : (u16)0;
      }
    } else {
      int gk = k0 + bk;
      long idx = (long)gk * ldb + n0 + bn;
      u16 tmp[8];
      if (gk < K) {
        u32x4 v = *(const u32x4*)(B16 + idx);
        tmp[0] = (u16)(v.x & 0xffff); tmp[1] = (u16)(v.x >> 16);
        tmp[2] = (u16)(v.y & 0xffff); tmp[3] = (u16)(v.y >> 16);
        tmp[4] = (u16)(v.z & 0xffff); tmp[5] = (u16)(v.z >> 16);
        tmp[6] = (u16)(v.w & 0xffff); tmp[7] = (u16)(v.w >> 16);
      } else {
#pragma unroll
        for (int e = 0; e < 8; ++e) tmp[e] = 0;
      }
      int rot = tid & 7;  // spread LDS bank writes
#pragma unroll
      for (int e = 0; e < 8; ++e) {
        int ee = (e + rot) & 7;
        Bs[(bn + ee) * LDS_S + bk] = tmp[ee];
      }
    }
    __syncthreads();
    {
      bf16x8 fa[2], fb[2];
      fa[0] = *(const bf16x8*)&As[(wm +      fm) * LDS_S + fq * 8];
      fa[1] = *(const bf16x8*)&As[(wm + 16 + fm) * LDS_S + fq * 8];
      fb[0] = *(const bf16x8*)&Bs[(wn +      fm) * LDS_S + fq * 8];
      fb[1] = *(const bf16x8*)&Bs[(wn + 16 + fm) * LDS_S + fq * 8];
#pragma unroll
      for (int mt = 0; mt < 2; ++mt)
#pragma unroll
        for (int nt = 0; nt < 2; ++nt)
          acc[mt][nt] = __builtin_amdgcn_mfma_f32_16x16x32_bf16(fa[mt], fb[nt], acc[mt][nt], 0, 0, 0);
    }
    __syncthreads();
  }
  if (Ylds) {
    // all LDS reads complete past the final barrier; safe to overwrite As/Bs
#pragma unroll
    for (int mt = 0; mt < 2; ++mt)
#pragma unroll
      for (int nt = 0; nt < 2; ++nt)
#pragma unroll
        for (int rr = 0; rr < 4; ++rr)
          Ylds[(wm + mt * 16 + fq * 4 + rr) * 64 + (wn + nt * 16 + fm)] = acc[mt][nt][rr];
  } else {
#pragma unroll
    for (int mt = 0; mt < 2; ++mt)
#pragma unroll
      for (int nt = 0; nt < 2; ++nt)
#pragma unroll
        for (int rr = 0; rr < 4; ++rr) {
          int gm = m0 + wm + mt * 16 + fq * 4 + rr;
          int gn = n0 + wn + nt * 16 + fm;
          if (gm < M && gn < N) {
            float v = alpha * acc[mt][nt][rr];
            if (Cb) Cb[(long)gm * ldc + gn] = f2bf(v);
            else    Cf[(long)gm * ldc + gn] = v;
          }
        }
  }
}

// ---------- mg4: q/k/mid gemm64128s + Gram gemm + wbar (bf16), LDS union ----
// GEMM range [0,1142) is XCD-chunk swizzled (m204 bijective, 1142 = 8*142+6).
__global__ __launch_bounds__(256) void mg4_k(
    const u16* __restrict__ xb, const u16* __restrict__ wqt, u16* __restrict__ qbf,
    const u16* __restrict__ cbuf, const u16* __restrict__ wkt, u16* __restrict__ kbf,
    const u16* __restrict__ wvt, u16* __restrict__ midbf,
    const u16* __restrict__ wcvb, u16* __restrict__ Gb, float* __restrict__ wbar)
{
  __shared__ __attribute__((aligned(16))) char smem[24576];
  int bid = blockIdx.x;
  if (bid < 1142) {
    int xcd = bid & 7, idx = bid >> 3;
    int v = (xcd < 6 ? xcd * 143 : 858 + (xcd - 6) * 142) + idx;  // bijective
    const u16 *A, *B; u16* C; int M, N, lid, mx;
    if (v < 156)      { A = xb;   B = wqt; C = qbf;   M = 1664; N = 768;  lid = v;       mx = 26; }
    else if (v < 258) { A = cbuf; B = wkt; C = kbf;   M = 1028; N = 768;  lid = v - 156; mx = 17; }
    else              { A = cbuf; B = wvt; C = midbf; M = 1028; N = 6656; lid = v - 258; mx = 17; }
    int m0 = (lid % mx) * 64, n0 = (lid / mx) * 128;
    gemm64128_body((u16*)smem, (u16*)(smem + 8192), A, B, C, M, N, 768, 768, 768, N, m0, n0);
  } else if (bid < 1246) {
    int z = bid - 1142;   // 0..103: M[g] = Wconv_b[g] @ Wconv_b[g]^T / 768
    gemm64_body((u16*)smem, (u16*)(smem + 5120),
                wcvb + (long)z * 49152, wcvb + (long)z * 49152,
                nullptr, Gb + (long)z * 4096, nullptr,
                64, 64, 768, 768, 768, 64, 1, 1.f / 768.f, 0, 0);
  } else {
    // wbar: row means of bf16 Wconv copy, r = g*64+l over 768 cols
    int r = (bid - 1246) * 4 + (threadIdx.x >> 6);
    int lane = threadIdx.x & 63;
    const u16* prow = wcvb + (long)r * 768;
    float sm = 0.f;
    for (int c = lane; c < 768; c += 64) sm += bf2f(prow[c]);
#pragma unroll
    for (int o = 32; o; o >>= 1) sm += __shfl_xor(sm, o, 64);
    if (lane == 0) wbar[r] = sm * (1.f / 768.f);
  }
}

// ------------------------------ final: out_pre @ Wo^T (64x128 tiles) --------
// XCD-chunk swizzled (156 = 8*19+4).
__global__ __launch_bounds__(256) void gemmF_k(
    const u16* __restrict__ opbf, const u16* __restrict__ wot, u16* __restrict__ qbf)
{
  __shared__ __attribute__((aligned(16))) char smem[24576];
  int bid = blockIdx.x;
  int xcd = bid & 7, idx = bid >> 3;
  int lid = (xcd < 4 ? xcd * 20 : 80 + (xcd - 4) * 19) + idx;   // bijective
  gemm64128_body((u16*)smem, (u16*)(smem + 8192), opbf, wot, qbf,
                 1664, 768, 768, 768, 768, 768, (lid % 26) * 64, (lid / 26) * 128);
}

// --------------------- ysim: Y-gemm with fused stats epilogue + sim-gemm ----
__global__ __launch_bounds__(256) void ysim_k(
    const u16* __restrict__ midbf, const u16* __restrict__ Gb,
    const float* __restrict__ wbar, u16* __restrict__ midi, float* __restrict__ pim,
    const u16* __restrict__ qbf, const u16* __restrict__ kbf, float* __restrict__ simf)
{
  __shared__ __attribute__((aligned(16))) char smem[16384];
  u16* As = (u16*)smem;
  u16* Bs = (u16*)(smem + 8192);
  int bid = blockIdx.x;
  if (bid < 1768) {
    // Y = mid_g[1028x64] @ M[g]^T -> fp32 tile in LDS, then stats epilogue
    int g = bid / 17, bx = bid % 17;
    int m0 = bx * 64;
    float* Ylds = (float*)smem;   // aliases As/Bs (dead after final barrier)
    gemm64_body(As, Bs, midbf + (long)g * 64, Gb + (long)g * 4096,
                nullptr, nullptr, Ylds,
                1028, 64, 64, 6656, 64, 64, 1, 1.f, m0, 0);
    __syncthreads();
    int tid = threadIdx.x, lane = tid & 63, wave = tid >> 6;
#pragma unroll
    for (int rr = 0; rr < 16; ++rr) {
      int r = wave * 16 + rr;          // local row
      int gr = m0 + r;                 // global row (wave-uniform)
      if (gr < 1028) {
        float m  = bf2f(midbf[(long)gr * 6656 + g * 64 + lane]);
        float y  = Ylds[r * 64 + lane];
        float wb = wbar[g * 64 + lane];
        float mup = m * wb, q2p = m * y;
#pragma unroll
        for (int o = 32; o; o >>= 1) { mup += __shfl_xor(mup, o, 64); q2p += __shfl_xor(q2p, o, 64); }
        float var = q2p - mup * mup;
        float inv = rsqrtf(fmaxf(var, 0.f) + 1e-5f);
        int b = gr / 257, j = gr - b * 257;
        long zidx = (long)b * 104 + g;
        midi[(zidx * 264 + j) * 64 + lane] = f2bf(inv * m);
        if (lane == 0) pim[zidx * 257 + j] = inv * mup;
      }
    }
  } else {
    // sim = scale^2 * q @ k^T;  z = b*6+h
    int lid = bid - 1768; int z = lid / 35, r = lid % 35, bx = r % 7, by = r / 7;
    const u16* A = qbf + (long)(z / 6) * 319488 + (long)(z % 6) * 128;
    const u16* B = kbf + (long)(z / 6) * 197376 + (long)(z % 6) * 128;
    float* Cf = simf + (long)z * 106912;
    gemm64_body(As, Bs, A, B, Cf, nullptr, nullptr,
                416, 257, 128, 768, 768, 257, 1, 0.08838834764831845f, bx * 64, by * 64);
  }
}

// --------------------------------------------------- ct: c-gemm + T-gemm ----
__global__ __launch_bounds__(256) void ct_k(
    const u16* __restrict__ Abf, const u16* __restrict__ ctxT, float* __restrict__ c_buf,
    const u16* __restrict__ A2bf, const u16* __restrict__ midi, u16* __restrict__ Tb16)
{
  __shared__ __attribute__((aligned(16))) u16 As[64 * LDS_S];
  __shared__ __attribute__((aligned(16))) u16 Bs[64 * LDS_S];
  int bid = blockIdx.x;
  if (bid < 336) {
    // c = A @ ctx_head (btrans via ctx^T, K=264); z = b*6+h
    int z = bid / 14, r = bid % 14, bx = r % 7, by = r / 7;
    const u16* A = Abf + (long)z * 109824;
    const u16* B = ctxT + (long)(z / 6) * 202752 + (long)(z % 6) * 33792;
    float* Cf = c_buf + (long)z * 53248;
    gemm64_body(As, Bs, A, B, Cf, nullptr, nullptr,
                416, 128, 264, 264, 264, 128, 1, 1.f, bx * 64, by * 64);
  } else {
    // T = A2 @ midi (non-trans, K=264, 264-row-padded midi); z = b*104+g
    int z = bid - 336;
    const u16* A = A2bf + (long)z * 6336;
    const u16* B = midi + (long)z * 16896;
    u16* Cb = Tb16 + (long)z * 1536;
    gemm64_body(As, Bs, A, B, nullptr, Cb, nullptr,
                24, 64, 264, 264, 64, 64, 0, 1.f, 0, 0);
  }
}

// ------------------------------------------------------------- row LN -------
__device__ __forceinline__ void ln_row(
    const u16* __restrict__ ip, const void* __restrict__ g, const void* __restrict__ b,
    u16* __restrict__ ob, float* __restrict__ of, int N, int f)
{
  int tid = threadIdx.x, lane = tid & 63, wave = tid >> 6;
  const int nv = N >> 3;
  float s1 = 0.f, s2 = 0.f;
  for (int c8 = tid; c8 < nv; c8 += 256) {
    u32x4 v = *(const u32x4*)(ip + c8 * 8);
    float e0 = bf2f((u16)(v.x & 0xffff)), e1 = bf2f((u16)(v.x >> 16));
    float e2 = bf2f((u16)(v.y & 0xffff)), e3 = bf2f((u16)(v.y >> 16));
    float e4 = bf2f((u16)(v.z & 0xffff)), e5 = bf2f((u16)(v.z >> 16));
    float e6 = bf2f((u16)(v.w & 0xffff)), e7 = bf2f((u16)(v.w >> 16));
    s1 += ((e0 + e1) + (e2 + e3)) + ((e4 + e5) + (e6 + e7));
    s2 += ((e0*e0 + e1*e1) + (e2*e2 + e3*e3)) + ((e4*e4 + e5*e5) + (e6*e6 + e7*e7));
  }
#pragma unroll
  for (int o = 32; o; o >>= 1) { s1 += __shfl_xor(s1, o, 64); s2 += __shfl_xor(s2, o, 64); }
  __shared__ float red[8];
  if (lane == 0) { red[wave] = s1; red[4 + wave] = s2; }
  __syncthreads();
  s1 = red[0] + red[1] + red[2] + red[3];
  s2 = red[4] + red[5] + red[6] + red[7];
  float mean = s1 / N;
  float var = s2 / N - mean * mean;
  float rstd = rsqrtf(fmaxf(var, 0.f) + 1e-5f);
  for (int c8 = tid; c8 < nv; c8 += 256) {
    int c = c8 * 8;
    u32x4 v = *(const u32x4*)(ip + c);
    float e[8];
    e[0] = bf2f((u16)(v.x & 0xffff)); e[1] = bf2f((u16)(v.x >> 16));
    e[2] = bf2f((u16)(v.y & 0xffff)); e[3] = bf2f((u16)(v.y >> 16));
    e[4] = bf2f((u16)(v.z & 0xffff)); e[5] = bf2f((u16)(v.z >> 16));
    e[6] = bf2f((u16)(v.w & 0xffff)); e[7] = bf2f((u16)(v.w >> 16));
    float gg[8], bb[8];
    if (f) {
      const float* gp = (const float*)g + c; const float* bp = (const float*)b + c;
      f32x4 g0 = *(const f32x4*)gp, g1 = *(const f32x4*)(gp + 4);
      f32x4 b0 = *(const f32x4*)bp, b1 = *(const f32x4*)(bp + 4);
      gg[0]=g0.x; gg[1]=g0.y; gg[2]=g0.z; gg[3]=g0.w; gg[4]=g1.x; gg[5]=g1.y; gg[6]=g1.z; gg[7]=g1.w;
      bb[0]=b0.x; bb[1]=b0.y; bb[2]=b0.z; bb[3]=b0.w; bb[4]=b1.x; bb[5]=b1.y; bb[6]=b1.z; bb[7]=b1.w;
    } else {
      u32x4 gv = *(const u32x4*)((const u16*)g + c);
      u32x4 bv = *(const u32x4*)((const u16*)b + c);
      gg[0]=bf2f((u16)(gv.x&0xffff)); gg[1]=bf2f((u16)(gv.x>>16));
      gg[2]=bf2f((u16)(gv.y&0xffff)); gg[3]=bf2f((u16)(gv.y>>16));
      gg[4]=bf2f((u16)(gv.z&0xffff)); gg[5]=bf2f((u16)(gv.z>>16));
      gg[6]=bf2f((u16)(gv.w&0xffff)); gg[7]=bf2f((u16)(gv.w>>16));
      bb[0]=bf2f((u16)(bv.x&0xffff)); bb[1]=bf2f((u16)(bv.x>>16));
      bb[2]=bf2f((u16)(bv.y&0xffff)); bb[3]=bf2f((u16)(bv.y>>16));
      bb[4]=bf2f((u16)(bv.z&0xffff)); bb[5]=bf2f((u16)(bv.z>>16));
      bb[6]=bf2f((u16)(bv.w&0xffff)); bb[7]=bf2f((u16)(bv.w>>16));
    }
    float o_[8];
#pragma unroll
    for (int e2i = 0; e2i < 8; ++e2i) o_[e2i] = (e[e2i] - mean) * rstd * gg[e2i] + bb[e2i];
    if (of) {
      f32x4 o0 = {o_[0], o_[1], o_[2], o_[3]}, o1 = {o_[4], o_[5], o_[6], o_[7]};
      *(f32x4*)(of + c) = o0; *(f32x4*)(of + c + 4) = o1;
    } else {
      u32x4 q = { (u32)f2bf(o_[0]) | ((u32)f2bf(o_[1]) << 16),
                  (u32)f2bf(o_[2]) | ((u32)f2bf(o_[3]) << 16),
                  (u32)f2bf(o_[4]) | ((u32)f2bf(o_[5]) << 16),
                  (u32)f2bf(o_[6]) | ((u32)f2bf(o_[7]) << 16) };
      *(u32x4*)(ob + c) = q;
    }
  }
}

__global__ __launch_bounds__(256) void ln_rows(
    const u16* __restrict__ in, const void* __restrict__ g, const void* __restrict__ b,
    void* __restrict__ out, int N, const int* __restrict__ dtf, int isfinal, int fknown)
{
  const int f = (fknown >= 0) ? fknown : dtf[0];
  long row = blockIdx.x;
  const u16* ip = in + row * N;
  float* of = (isfinal && f) ? (float*)out + row * N : nullptr;
  u16*   ob = of ? nullptr : (u16*)out + row * N;
  ln_row(ip, g, b, ob, of, N, f);
}

// merged LN for q (1664x768), k (1028x768), mid (1028x6656)
__global__ __launch_bounds__(256) void mln3_k(
    u16* __restrict__ qb, const void* __restrict__ gq, const void* __restrict__ bq,
    u16* __restrict__ kb, const void* __restrict__ gk, const void* __restrict__ bk,
    u16* __restrict__ mb, const void* __restrict__ gv, const void* __restrict__ bv,
    const int* __restrict__ dtf, int fknown)
{
  const int f = (fknown >= 0) ? fknown : dtf[0];
  int row = blockIdx.x;
  u16* ip; const void *g, *b; int N;
  if (row < 1664)      { ip = qb + (long)row * 768; g = gq; b = bq; N = 768; }
  else if (row < 2692) { ip = kb + (long)(row - 1664) * 768; g = gk; b = bk; N = 768; }
  else                 { ip = mb + (long)(row - 2692) * 6656; g = gv; b = bv; N = 6656; }
  ln_row(ip, g, b, ip, nullptr, N, f);
}

// ------------------------------------------------------------- softmax ------
__global__ __launch_bounds__(256) void softmax_k(
    const float* __restrict__ simf, const float* __restrict__ pim,
    u16* __restrict__ Abf, u16* __restrict__ A2bf, float* __restrict__ s_sh)
{
  int bh = blockIdx.x;
  int b = bh / 6, h = bh - b * 6;
  int tid = threadIdx.x, lane = tid & 63, wave = tid >> 6;
  int i = blockIdx.y * 4 + wave;
  int g = i % 104, rq = i / 104;
  const float* sp_ = simf + ((long)bh * 416 + i) * 257;
  float s[5];
#pragma unroll
  for (int jc = 0; jc < 5; ++jc) {
    int j = jc * 64 + lane;
    s[jc] = (j < 257) ? sp_[j] : -1e30f;
  }
  float mx = -1e30f;
#pragma unroll
  for (int jc = 0; jc < 5; ++jc) mx = fmaxf(mx, s[jc]);
#pragma unroll
  for (int o = 32; o; o >>= 1) mx = fmaxf(mx, __shfl_xor(mx, o, 64));
  float p[5], sum = 0.f, sp = 0.f;
  long pimb = ((long)b * 104 + g) * 257;
#pragma unroll
  for (int jc = 0; jc < 5; ++jc) {
    int j = jc * 64 + lane;
    float pv = 0.f;
    if (j < 257) { pv = __expf(s[jc] - mx); sp = fmaf(pv, pim[pimb + j], sp); }
    p[jc] = pv; sum += pv;
  }
#pragma unroll
  for (int o = 32; o; o >>= 1) { sum += __shfl_xor(sum, o, 64); sp += __shfl_xor(sp, o, 64); }
  float rs = 1.f / sum;
  long arow  = ((long)bh * 416 + i) * 264;
  long a2row = (((long)b * 104 + g) * 24 + h * 4 + rq) * 264;
#pragma unroll
  for (int jc = 0; jc < 5; ++jc) {
    int j = jc * 64 + lane;
    if (j < 257) { u16 pb = f2bf(p[jc] * rs); Abf[arow + j] = pb; A2bf[a2row + j] = pb; }
    else if (j < 264) { Abf[arow + j] = 0; A2bf[a2row + j] = 0; }
  }
  if (lane == 0) s_sh[(long)bh * 416 + i] = sp * rs;
}

// -------------------------------------------------- fused O-gemm + combine --
__global__ __launch_bounds__(256) void oc_k(
    const u16* __restrict__ T, const u16* __restrict__ Wb,
    const float* __restrict__ s_sh, const float* __restrict__ c_buf,
    const void* __restrict__ gv2, const void* __restrict__ bv2,
    u16* __restrict__ opbf, const int* __restrict__ dtf, int fknown)
{
  const int f = (fknown >= 0) ? fknown : dtf[0];
  int z = blockIdx.x;                 // b*104+g
  int b = z / 104, g = z - b * 104;
  int tid = threadIdx.x;
  __shared__ float Ts[24][64];        // 6 KB
  const u16* tp = T + (long)z * 1536;
  for (int idx = tid; idx < 1536; idx += 256) Ts[idx >> 6][idx & 63] = bf2f(tp[idx]);
  __syncthreads();
  const int dh = tid & 127;
  const int hbase = (tid >> 7) * 3;   // threads 0..127 -> h 0..2, 128..255 -> h 3..5
  const u16* wg = Wb + (long)g * 49152;
#pragma unroll
  for (int hh = 0; hh < 3; ++hh) {
    int h = hbase + hh;
    int d = h * 128 + dh;
    const u16* wp = wg + d;
    float a0 = 0.f, a1 = 0.f, a2 = 0.f, a3 = 0.f;
#pragma unroll 16
    for (int k = 0; k < 64; ++k) {
      float w = bf2f(wp[(long)k * 768]);
      a0 = fmaf(Ts[h * 4 + 0][k], w, a0);
      a1 = fmaf(Ts[h * 4 + 1][k], w, a1);
      a2 = fmaf(Ts[h * 4 + 2][k], w, a2);
      a3 = fmaf(Ts[h * 4 + 3][k], w, a3);
    }
    float acc[4] = {a0, a1, a2, a3};
    float gvd = gld(gv2, d, f), bvd = gld(bv2, d, f);
#pragma unroll
    for (int rq = 0; rq < 4; ++rq) {
      int i = rq * 104 + g;
      float ssh = s_sh[((long)b * 6 + h) * 416 + i];
      float val = gvd * (acc[rq] - ssh) + bvd
                + c_buf[(((long)b * 6 + h) * 416 + i) * 128 + dh];
      opbf[((long)b * 416 + i) * 768 + d] = f2bf(val);
    }
  }
}

// ---------------------------------------------------------------- host ------
extern "C" void kernel_launch(void* const* d_in, const int* in_sizes, int n_in,
                              void* d_out, int out_size, void* d_ws, size_t ws_size,
                              hipStream_t stream)
{
  const void* x   = d_in[0];
  const void* ctx = d_in[1];
  const void* Wq  = d_in[2];
  const void* gq  = d_in[3];
  const void* bq  = d_in[4];
  const void* Wk  = d_in[5];
  const void* gk  = d_in[6];
  const void* bk  = d_in[7];
  const void* Wv  = d_in[8];
  const void* gv1 = d_in[9];
  const void* bv1 = d_in[10];
  const void* Wcv = d_in[11];
  const void* gv2 = d_in[12];
  const void* bv2 = d_in[13];
  const void* Wo  = d_in[14];
  const void* go  = d_in[15];
  const void* bo  = d_in[16];

  // -------- workspace layout --------
  const size_t SZ_FLAG = 256;
  const size_t SZ_QBF  = 2555904;
  const size_t SZ_KBF  = 1579008;
  const size_t SZ_MID  = 13684736;
  const size_t SZ_MM   = 1703936;
  const size_t SZ_WB   = 26624;
  const size_t SZ_MIDI = 14057472;   // 416 * 264 * 64 bf16 (264-row padded)
  const size_t SZ_PIM  = 427648;
  const size_t SZ_ABF  = 5271552;
  const size_t SZ_A2   = 5271552;
  const size_t SZ_SSH  = 39936;
  const size_t SZ_CB   = 1579008;
  const size_t SZ_WCVB = 10223616;   // 104*64*768 bf16
  const size_t SZ_WT   = 1179648;    // 768*768 bf16 (x3: WqT, WkT, WoT)
  const size_t SZ_WVT  = 10223616;   // 6656*768 bf16
  const size_t SZ_CTXT = 1622016;    // 4*768*264 bf16 (ctx^T, zero-padded cols)
  const size_t SZ_SIMF = 10263552;   // 24*416*257 fp32
  const size_t REQUIRED = SZ_FLAG + SZ_QBF + SZ_KBF + SZ_MID + SZ_MM + SZ_WB +
                          SZ_MIDI + SZ_PIM + SZ_ABF + SZ_A2 + SZ_SSH + SZ_CB +
                          SZ_WCVB + 3 * SZ_WT + SZ_WVT + SZ_CTXT + SZ_SIMF;  // 82,069,376

  if (ws_size < REQUIRED) {
    fill_k<<<(out_size + 255) / 256, 256, 0, stream>>>((u16*)d_out, (float)(ws_size >> 20), out_size);
    return;
  }

  char* p = (char*)d_ws;
  int*   dtf   = (int*)  p;                 p += SZ_FLAG;
  u16*   qbf   = (u16*)  p;                 p += SZ_QBF;
  u16*   kbf   = (u16*)  p;                 p += SZ_KBF;
  char*  midrg = p;                         p += SZ_MID;
  char*  mmrg  = p;                         p += SZ_MM;
  float* wbar  = (float*)p;                 p += SZ_WB;
  u16*   midi  = (u16*)  p;                 p += SZ_MIDI;
  float* pim   = (float*)p;                 p += SZ_PIM;
  char*  abfrg = p;                         p += SZ_ABF;
  u16*   A2bf  = (u16*)  p;                 p += SZ_A2;
  float* s_sh  = (float*)p;                 p += SZ_SSH;
  u16*   cb    = (u16*)  p;                 p += SZ_CB;
  u16*   wcvb  = (u16*)  p;                 p += SZ_WCVB;
  u16*   wqt2  = (u16*)  p;                 p += SZ_WT;
  u16*   wkt2  = (u16*)  p;                 p += SZ_WT;
  u16*   wot2  = (u16*)  p;                 p += SZ_WT;
  u16*   wvt   = (u16*)  p;                 p += SZ_WVT;
  u16*   ctxT  = (u16*)  p;                 p += SZ_CTXT;
  float* simf  = (float*)p;                 p += SZ_SIMF;

  u16*   midbf = (u16*)midrg;
  float* c_buf = (float*)midrg;             // midbf dead after ysim stats
  u16*   Tb16  = (u16*)(midrg + 5111808);   // right after c_buf's 5,111,808 B
  u16*   Gb    = (u16*)mmrg;
  u16*   xb    = (u16*)abfrg;
  u16*   Abf   = (u16*)abfrg;
  u16*   opbf  = (u16*)abfrg;               // Abf dead after ct_k

  // host-side dtype: in_sizes[0] in bytes distinguishes fp32 (5,111,808) from
  // bf16 (2,555,904); anything else (e.g. element count) -> probe fallback.
  int fknown = -1;
  if (in_sizes && n_in > 0) {
    if (in_sizes[0] == 5111808)      fknown = 1;
    else if (in_sizes[0] == 2555904) fknown = 0;
  }
  if (fknown < 0) probe_k<<<1, 256, 0, stream>>>((const u32*)x, dtf);

  // prep: copies + midi pad zero (3597) | 64x64 transposes (1920)
  prep_k<<<5517, 256, 0, stream>>>(x, xb, ctx, cb, Wcv, wcvb, midi,
                                   Wq, Wk, Wo, Wv, wqt2, wkt2, wot2, wvt, ctxT,
                                   dtf, fknown);

  // q/k/mid gemm64128s BK=64 (1142, XCD-chunk swizzled) + Gram (104) + wbar (1664)
  mg4_k<<<2910, 256, 0, stream>>>(xb, wqt2, qbf, cb, wkt2, kbf, wvt, midbf,
                                  wcvb, Gb, wbar);

  // q/k/mid LNs
  mln3_k<<<3720, 256, 0, stream>>>(qbf, gq, bq, kbf, gk, bk, midbf, gv1, bv1,
                                   dtf, fknown);

  // Y = mid_g @ M[g] with fused stats epilogue (1768) + sim (840)
  ysim_k<<<2608, 256, 0, stream>>>(midbf, Gb, wbar, midi, pim, qbf, kbf, simf);

  softmax_k<<<dim3(24, 104), 256, 0, stream>>>(simf, pim, Abf, A2bf, s_sh);

  // c = A @ ctx_head (336) + T = A2 @ midi (416)
  ct_k<<<752, 256, 0, stream>>>(Abf, ctxT, c_buf, A2bf, midi, Tb16);

  // fused O-gemm + combine
  oc_k<<<416, 256, 0, stream>>>(Tb16, wcvb, s_sh, c_buf, gv2, bv2, opbf, dtf, fknown);

  // out = LN(out_pre @ Wo): 64x128 tiles BK=64, XCD-chunk swizzled
  gemmF_k<<<156, 256, 0, stream>>>(opbf, wot2, qbf);
  ln_rows<<<1664, 256, 0, stream>>>(qbf, go, bo, d_out, 768, dtf, 1, fknown);
}